// Round 8
// baseline (626.083 us; speedup 1.0000x reference)
//
#include <hip/hip_runtime.h>
#include <hip/hip_bf16.h>
#include <math.h>

#define Bn 4
#define Sn 512
#define Dn 512
#define DINn 1024
#define Hn 16
#define Pn 64
#define RNn 128
#define DFFn 1368
#define BSn (Bn*Sn)
#define CH 64
#define NCH (Sn/CH)   // 8
#define PSTR 6144     // fused proj row stride: [z(1024) | u(1024) | B(2048) | C(2048)]
#define FSTR 2736     // fused ffn row stride: [h1(1368) | h3(1368)]

typedef __attribute__((ext_vector_type(8))) short short8;
typedef __attribute__((ext_vector_type(4))) float f32x4;

static __device__ __forceinline__ float bf2f(__hip_bfloat16 v){return __bfloat162float(v);}
static __device__ __forceinline__ __hip_bfloat16 f2bf(float v){return __float2bfloat16(v);}
static __device__ __forceinline__ short f2bfs(float v){ __hip_bfloat16 b=f2bf(v); short s; __builtin_memcpy(&s,&b,2); return s; }
static __device__ __forceinline__ float bfs2f(short s){ __hip_bfloat16 b; __builtin_memcpy(&b,&s,2); return bf2f(b); }

// ---------------- fused 8-way transpose+cast: f32 [Rr x Cc] -> bf16 [CcPad x RrPad] ----------------
struct T8 {
  const float* src[8];
  __hip_bfloat16* dst[8];
  int Rr[8], Cc[8], RrPad[8], CcPad[8], gw[8];
  int start[9];
};

__global__ void transpose8_kernel(T8 d) {
  int bid = blockIdx.x;
  int i = 0;
#pragma unroll
  for (int k = 1; k < 8; ++k) if (bid >= d.start[k]) i = k;
  int rel = bid - d.start[i];
  int gx = rel % d.gw[i], gy = rel / d.gw[i];
  const float* __restrict__ in = d.src[i];
  __hip_bfloat16* __restrict__ out = d.dst[i];
  int Rr = d.Rr[i], Cc = d.Cc[i], RrPad = d.RrPad[i], CcPad = d.CcPad[i];
  __shared__ __hip_bfloat16 tile[32][33];
  int c0 = gx * 32, r0 = gy * 32;
  int tx = threadIdx.x, ty = threadIdx.y;
  for (int k = ty; k < 32; k += 8) {
    int r = r0 + k, cc = c0 + tx;
    tile[k][tx] = (r < Rr && cc < Cc) ? f2bf(in[(size_t)r * Cc + cc]) : f2bf(0.f);
  }
  __syncthreads();
  for (int k = ty; k < 32; k += 8) {
    int r = c0 + k, cc = r0 + tx;
    if (r < CcPad && cc < RrPad) out[(size_t)r * RrPad + cc] = tile[tx][k];
  }
}

// ---------------- rmsnorm1 * mask -> bf16, fused dt/la ----------------
__global__ void rmsnorm1_dt_kernel(const float* __restrict__ x,
                                   const float* __restrict__ w,
                                   const float* __restrict__ mask,
                                   const float* __restrict__ Wdt,
                                   const float* __restrict__ dtb,
                                   const float* __restrict__ Alog,
                                   __hip_bfloat16* __restrict__ outb,
                                   float* __restrict__ dt, float* __restrict__ la) {
  __shared__ float xs[Dn];
  __shared__ float red[4];
  int row = blockIdx.x, t = threadIdx.x;
  const float* xr = x + (size_t)row * Dn;
  float v0 = xr[t], v1 = xr[t + 256];
  float ss = v0 * v0 + v1 * v1;
#pragma unroll
  for (int o = 32; o > 0; o >>= 1) ss += __shfl_down(ss, o);
  if ((t & 63) == 0) red[t >> 6] = ss;
  __syncthreads();
  float tot = red[0] + red[1] + red[2] + red[3];
  float sc = rsqrtf(tot * (1.f / Dn) + 1e-6f) * mask[row];
  float o0 = v0 * sc * w[t], o1v = v1 * sc * w[t + 256];
  outb[(size_t)row * Dn + t] = f2bf(o0);
  outb[(size_t)row * Dn + t + 256] = f2bf(o1v);
  xs[t] = o0;
  xs[t + 256] = o1v;
  __syncthreads();
  int h = t >> 4, j = t & 15;
  float s = 0.f;
  for (int k = j * 32; k < j * 32 + 32; ++k) s = fmaf(xs[k], Wdt[k * Hn + h], s);
#pragma unroll
  for (int o = 8; o > 0; o >>= 1) s += __shfl_down(s, o, 16);
  if (j == 0) {
    float v = s + dtb[h];
    float sp = (v > 20.f) ? v : log1pf(expf(v));
    float Ah = expf(Alog[h]);
    dt[(size_t)row * Hn + h] = sp;
    la[(size_t)row * Hn + h] = -Ah * sp;
  }
}

// ---------------- rmsnorm (f32 in, no mask) -> bf16 ----------------
__global__ void rmsnorm2_kernel(const float* __restrict__ x,
                                const float* __restrict__ w,
                                __hip_bfloat16* __restrict__ out) {
  int row = blockIdx.x, t = threadIdx.x;
  const float* xr = x + (size_t)row * Dn;
  float v0 = xr[t], v1 = xr[t + 256];
  float ss = v0 * v0 + v1 * v1;
#pragma unroll
  for (int o = 32; o > 0; o >>= 1) ss += __shfl_down(ss, o);
  __shared__ float red[4];
  if ((t & 63) == 0) red[t >> 6] = ss;
  __syncthreads();
  float tot = red[0] + red[1] + red[2] + red[3];
  float sc = rsqrtf(tot * (1.f / Dn) + 1e-6f);
  out[(size_t)row * Dn + t] = f2bf(v0 * sc * w[t]);
  out[(size_t)row * Dn + t + 256] = f2bf(v1 * sc * w[t + 256]);
}

// ---------------- GEMM 128x128, BK=32, LDS double-buffer + distance-2 register prefetch ----------------
// kTiles must be >= 3 (K=512 here). C bf16.
__global__ __launch_bounds__(256) void gemm_kernel(
    const __hip_bfloat16* __restrict__ A, const __hip_bfloat16* __restrict__ BT,
    __hip_bfloat16* __restrict__ C, int M, int N, int K) {
  __shared__ short As[2][128][40];
  __shared__ short Bs[2][128][40];
  int m0 = blockIdx.x * 128, n0 = blockIdx.y * 128;
  int t = threadIdx.x;
  int lane = t & 63, wv = t >> 6;
  int wm = (wv & 1) * 64, wn = (wv >> 1) * 64;
  f32x4 acc[4][4];
#pragma unroll
  for (int i = 0; i < 4; ++i)
#pragma unroll
    for (int j = 0; j < 4; ++j) acc[i][j] = (f32x4){0.f, 0.f, 0.f, 0.f};
  const short* Ag = (const short*)A;
  const short* Bg = (const short*)BT;
  int sr = t >> 2;
  int sc = (t & 3) * 8;
  int rb0 = n0 + sr, rb1 = n0 + sr + 64;
  bool bv0 = rb0 < N, bv1 = rb1 < N;
  const short* Ap0 = Ag + (size_t)(m0 + sr) * K + sc;
  const short* Ap1 = Ag + (size_t)(m0 + sr + 64) * K + sc;
  const short* Bp0 = Bg + (size_t)rb0 * K + sc;
  const short* Bp1 = Bg + (size_t)rb1 * K + sc;
  int kTiles = K >> 5;
  short8 a0[2], a1[2], b0[2], b1[2];
  auto loadt = [&](int k0, int s) {
    a0[s] = *(const short8*)(Ap0 + k0);
    a1[s] = *(const short8*)(Ap1 + k0);
    b0[s] = bv0 ? *(const short8*)(Bp0 + k0) : (short8)0;
    b1[s] = bv1 ? *(const short8*)(Bp1 + k0) : (short8)0;
  };
  auto store = [&](int s, int buf) {
    *(short8*)&As[buf][sr][sc] = a0[s];
    *(short8*)&As[buf][sr + 64][sc] = a1[s];
    *(short8*)&Bs[buf][sr][sc] = b0[s];
    *(short8*)&Bs[buf][sr + 64][sc] = b1[s];
  };
  // prologue: tiles 0,1 -> slots 0,1; store tile0; reload slot0 with tile2
  loadt(0, 0);
  loadt(32, 1);
  store(0, 0);
  loadt(64, 0);
  __syncthreads();
  int fr = lane & 15, fq = (lane >> 4) * 8;
  for (int kt = 0; kt < kTiles; ++kt) {
    int buf = kt & 1;
    short8 af[4], bfr[4];
#pragma unroll
    for (int i = 0; i < 4; ++i) af[i] = *(const short8*)&As[buf][wm + i * 16 + fr][fq];
#pragma unroll
    for (int i = 0; i < 4; ++i) bfr[i] = *(const short8*)&Bs[buf][wn + i * 16 + fr][fq];
#pragma unroll
    for (int mi = 0; mi < 4; ++mi)
#pragma unroll
      for (int ni = 0; ni < 4; ++ni)
        acc[mi][ni] = __builtin_amdgcn_mfma_f32_16x16x32_bf16(af[mi], bfr[ni], acc[mi][ni], 0, 0, 0);
    if (kt + 1 < kTiles) store((kt + 1) & 1, 1 - buf);   // tile kt+1 (loaded 2 iters ago)
    if (kt + 3 < kTiles) loadt((kt + 3) << 5, (kt + 1) & 1);  // prefetch distance 2
    __syncthreads();
  }
  int fq4 = (lane >> 4) * 4;
#pragma unroll
  for (int mi = 0; mi < 4; ++mi)
#pragma unroll
    for (int ni = 0; ni < 4; ++ni) {
      int col = n0 + wn + ni * 16 + fr;
      if (col < N) {
        int rowb = m0 + wm + mi * 16 + fq4;
#pragma unroll
        for (int r = 0; r < 4; ++r)
          C[(size_t)(rowb + r) * N + col] = f2bf(acc[mi][ni][r]);
      }
    }
}

// ---------------- GEMM 64x64, BK=64, dbuf + dist-2 prefetch, fused epilogue ----------------
// MODE 1: out = aux + acc*mask[row]; MODE 2: out = (aux + acc)*mask[row]. N exact.
// GATE=1: A = silu(h1)*h3 from Hf (stride FSTR), silu applied at LDS-store time; Kreal guards pad.
template <int MODE, int GATE>
__global__ __launch_bounds__(256) void gemm64_ep_kernel(
    const __hip_bfloat16* __restrict__ A, const __hip_bfloat16* __restrict__ BT,
    const float* __restrict__ aux, const float* __restrict__ mask,
    float* __restrict__ out, int M, int N, int K, int Kreal) {
  __shared__ short As[2][64][72];
  __shared__ short Bs[2][64][72];
  int m0 = blockIdx.x * 64, n0 = blockIdx.y * 64;
  int t = threadIdx.x;
  int lane = t & 63, wv = t >> 6;
  int wm = (wv & 1) * 32, wn = (wv >> 1) * 32;
  f32x4 acc[2][2];
#pragma unroll
  for (int i = 0; i < 2; ++i)
#pragma unroll
    for (int j = 0; j < 2; ++j) acc[i][j] = (f32x4){0.f, 0.f, 0.f, 0.f};
  const short* Ag = (const short*)A;
  const short* Bg = (const short*)BT;
  int sr = t >> 2;
  int sc = (t & 3) * 16;
  const short* Bp = Bg + (size_t)(n0 + sr) * K + sc;
  short8 b0[2], b1[2];
  short8 ra0[2], ra1[2], rh3a[2], rh3b[2];   // GATE: ra=h1, rh3=h3; else ra=A raw
  auto loadt = [&](int k0, int s) {
    b0[s] = *(const short8*)(Bp + k0);
    b1[s] = *(const short8*)(Bp + k0 + 8);
    if (GATE) {
      const short* hrow = Ag + (size_t)(m0 + sr) * FSTR;
      int k = k0 + sc;
      ra0[s]  = *(const short8*)(hrow + k);
      ra1[s]  = *(const short8*)(hrow + k + 8);
      rh3a[s] = *(const short8*)(hrow + DFFn + k);
      rh3b[s] = *(const short8*)(hrow + DFFn + k + 8);
    } else {
      const short* Ap = Ag + (size_t)(m0 + sr) * K + sc;
      ra0[s] = *(const short8*)(Ap + k0);
      ra1[s] = *(const short8*)(Ap + k0 + 8);
    }
  };
  auto store = [&](int s, int buf, int k0) {
    if (GATE) {
      int k = k0 + sc;
      short8 g0, g1;
#pragma unroll
      for (int j = 0; j < 8; ++j) {
        float v = bfs2f(ra0[s][j]);
        float sil = v / (1.f + __expf(-v));
        g0[j] = (k + j < Kreal) ? f2bfs(sil * bfs2f(rh3a[s][j])) : (short)0;
        float v2 = bfs2f(ra1[s][j]);
        float sil2 = v2 / (1.f + __expf(-v2));
        g1[j] = (k + 8 + j < Kreal) ? f2bfs(sil2 * bfs2f(rh3b[s][j])) : (short)0;
      }
      *(short8*)&As[buf][sr][sc] = g0;
      *(short8*)&As[buf][sr][sc + 8] = g1;
    } else {
      *(short8*)&As[buf][sr][sc] = ra0[s];
      *(short8*)&As[buf][sr][sc + 8] = ra1[s];
    }
    *(short8*)&Bs[buf][sr][sc] = b0[s];
    *(short8*)&Bs[buf][sr][sc + 8] = b1[s];
  };
  loadt(0, 0);
  loadt(64, 1);
  store(0, 0, 0);
  loadt(128, 0);
  __syncthreads();
  int fr = lane & 15, fq = (lane >> 4) * 8;
  int kTiles = K >> 6;
  for (int kt = 0; kt < kTiles; ++kt) {
    int buf = kt & 1;
#pragma unroll
    for (int kk = 0; kk < 2; ++kk) {
      short8 af[2], bfr[2];
#pragma unroll
      for (int i = 0; i < 2; ++i) af[i] = *(const short8*)&As[buf][wm + i * 16 + fr][kk * 32 + fq];
#pragma unroll
      for (int i = 0; i < 2; ++i) bfr[i] = *(const short8*)&Bs[buf][wn + i * 16 + fr][kk * 32 + fq];
#pragma unroll
      for (int mi = 0; mi < 2; ++mi)
#pragma unroll
        for (int ni = 0; ni < 2; ++ni)
          acc[mi][ni] = __builtin_amdgcn_mfma_f32_16x16x32_bf16(af[mi], bfr[ni], acc[mi][ni], 0, 0, 0);
    }
    if (kt + 1 < kTiles) store((kt + 1) & 1, 1 - buf, (kt + 1) << 6);
    if (kt + 3 < kTiles) loadt((kt + 3) << 6, (kt + 1) & 1);
    __syncthreads();
  }
  int fq4 = (lane >> 4) * 4;
#pragma unroll
  for (int mi = 0; mi < 2; ++mi)
#pragma unroll
    for (int ni = 0; ni < 2; ++ni) {
      int col = n0 + wn + ni * 16 + fr;
#pragma unroll
      for (int r = 0; r < 4; ++r) {
        int row = m0 + wm + mi * 16 + fq4 + r;
        float m = mask[row];
        size_t a = (size_t)row * N + col;
        float v = acc[mi][ni][r];
        if (MODE == 1) out[a] = aux[a] + v * m;
        else           out[a] = (aux[a] + v) * m;
      }
    }
}

// ---------------- chunked scan: intra-chunk + chunk-state ----------------
__global__ __launch_bounds__(256) void chunk_intra_kernel(
    const __hip_bfloat16* __restrict__ P, const float* __restrict__ dt,
    const float* __restrict__ la, float* __restrict__ ys,
    float* __restrict__ Sbuf, float* __restrict__ ecL, float* __restrict__ ec) {
  int id = blockIdx.x;
  int h = id & 15, c = (id >> 4) & 7, b = id >> 7;
  int t = threadIdx.x, lane = t & 63, wv = t >> 6;
  __shared__ __align__(16) char smem[55040];
  short* sCB = (short*)smem;             // sC [64][136] (phase<=3a), sBt [128][72] (phase>=3b)
  short* sB  = (short*)(smem + 18432);   // [64][136]
  short* sUD = (short*)(smem + 35840);   // [64 p][72]  (s-minor)
  short* sG  = (short*)(smem + 45056);   // [64 t][72]  (s-minor)
  float* scum = (float*)(smem + 54272);  // [64]
  float* sws  = scum + 64;
  float* sdt  = sws + 64;
  int row0 = b * Sn + c * CH;
  const short* Pb = (const short*)P;
#pragma unroll
  for (int i = 0; i < 4; ++i) {
    int idx = t + i * 256;
    int r = idx >> 4, kk = (idx & 15) * 8;
    *(short8*)&sCB[r * 136 + kk] = *(const short8*)(Pb + (size_t)(row0 + r) * PSTR + 4096 + h * 128 + kk);
    *(short8*)&sB [r * 136 + kk] = *(const short8*)(Pb + (size_t)(row0 + r) * PSTR + 2048 + h * 128 + kk);
  }
  if (t < 64) { sdt[t] = dt[(size_t)(row0 + t) * Hn + h]; scum[t] = la[(size_t)(row0 + t) * Hn + h]; }
  __syncthreads();
  if (wv == 0) {
    float v = scum[lane];
#pragma unroll
    for (int o = 1; o < 64; o <<= 1) { float n = __shfl_up(v, o); if (lane >= o) v += n; }
    scum[lane] = v;
    float c63 = __shfl(v, 63);
    sws[lane] = __expf(c63 - v);
    ec[((size_t)((b * NCH + c) * Hn + h)) * 64 + lane] = __expf(v);
    if (lane == 0) ecL[(b * NCH + c) * Hn + h] = __expf(c63);
  }
#pragma unroll
  for (int i = 0; i < 2; ++i) {
    int idx = t + i * 256;
    int s = idx >> 3, pc = (idx & 7) * 8;
    short8 uv = *(const short8*)(Pb + (size_t)(row0 + s) * PSTR + 1024 + h * 64 + pc);
    float dv = sdt[s];
#pragma unroll
    for (int j = 0; j < 8; ++j) sUD[(pc + j) * 72 + s] = f2bfs(bfs2f(uv[j]) * dv);
  }
  __syncthreads();
  int fr = lane & 15, fq = (lane >> 4) * 8, q4 = (lane >> 4) * 4;
  {
    short8 af[4];
#pragma unroll
    for (int k = 0; k < 4; ++k) af[k] = *(short8*)&sCB[(16 * wv + fr) * 136 + k * 32 + fq];
#pragma unroll
    for (int j = 0; j < 4; ++j) {
      f32x4 acc = (f32x4){0.f, 0.f, 0.f, 0.f};
#pragma unroll
      for (int k = 0; k < 4; ++k) {
        short8 bf = *(short8*)&sB[(16 * j + fr) * 136 + k * 32 + fq];
        acc = __builtin_amdgcn_mfma_f32_16x16x32_bf16(af[k], bf, acc, 0, 0, 0);
      }
      int ss = 16 * j + fr;
      float cs = scum[ss];
#pragma unroll
      for (int r = 0; r < 4; ++r) {
        int tt = 16 * wv + q4 + r;
        float w = (ss <= tt) ? __expf(scum[tt] - cs) : 0.f;
        sG[tt * 72 + ss] = f2bfs(acc[r] * w);
      }
    }
  }
  __syncthreads();
#pragma unroll
  for (int i = 0; i < 32; ++i) {
    int idx = t + i * 256;
    int rn = idx >> 6, s = idx & 63;
    sCB[rn * 72 + s] = f2bfs(bfs2f(sB[s * 136 + rn]) * sws[s]);
  }
  __syncthreads();
  {
    short8 ag[2];
#pragma unroll
    for (int k = 0; k < 2; ++k) ag[k] = *(short8*)&sG[(16 * wv + fr) * 72 + k * 32 + fq];
#pragma unroll
    for (int j = 0; j < 4; ++j) {
      f32x4 acc = (f32x4){0.f, 0.f, 0.f, 0.f};
#pragma unroll
      for (int k = 0; k < 2; ++k) {
        short8 bf = *(short8*)&sUD[(16 * j + fr) * 72 + k * 32 + fq];
        acc = __builtin_amdgcn_mfma_f32_16x16x32_bf16(ag[k], bf, acc, 0, 0, 0);
      }
#pragma unroll
      for (int r = 0; r < 4; ++r)
        ys[(size_t)(row0 + 16 * wv + q4 + r) * DINn + h * 64 + 16 * j + fr] = acc[r];
    }
  }
#pragma unroll
  for (int mt0 = 0; mt0 < 2; ++mt0) {
    int mt = wv * 2 + mt0;
    short8 ab[2];
#pragma unroll
    for (int k = 0; k < 2; ++k) ab[k] = *(short8*)&sCB[(16 * mt + fr) * 72 + k * 32 + fq];
#pragma unroll
    for (int j = 0; j < 4; ++j) {
      f32x4 acc = (f32x4){0.f, 0.f, 0.f, 0.f};
#pragma unroll
      for (int k = 0; k < 2; ++k) {
        short8 bf = *(short8*)&sUD[(16 * j + fr) * 72 + k * 32 + fq];
        acc = __builtin_amdgcn_mfma_f32_16x16x32_bf16(ab[k], bf, acc, 0, 0, 0);
      }
#pragma unroll
      for (int r = 0; r < 4; ++r)
        Sbuf[((size_t)((b * NCH + c) * Hn + h) * RNn + 16 * mt + q4 + r) * 64 + 16 * j + fr] = acc[r];
    }
  }
}

// ---------------- prefix over chunk states ----------------
__global__ void chunk_state_kernel(const float* __restrict__ Sbuf, const float* __restrict__ ecL,
                                   float* __restrict__ Hp) {
  int bh = blockIdx.x >> 5;
  int j = (blockIdx.x & 31) * 256 + threadIdx.x;
  int b = bh >> 4, h = bh & 15;
  float hp = 0.f;
#pragma unroll
  for (int c = 0; c < NCH; ++c) {
    size_t addr = ((size_t)((b * NCH + c) * Hn + h)) * 8192 + j;
    Hp[addr] = hp;
    hp = ecL[(b * NCH + c) * Hn + h] * hp + Sbuf[addr];
  }
}

// ---------------- inter-chunk + gate fused ----------------
__global__ __launch_bounds__(256) void inter_gate_kernel(
    const __hip_bfloat16* __restrict__ P, const float* __restrict__ Hp,
    const float* __restrict__ ec, const float* __restrict__ ys,
    const float* __restrict__ Dsk, __hip_bfloat16* __restrict__ y2b) {
  int id = blockIdx.x;
  int h = id & 15, c = (id >> 4) & 7, b = id >> 7;
  int t = threadIdx.x, lane = t & 63, wv = t >> 6;
  __shared__ __align__(16) short sC[64 * 136];
  __shared__ __align__(16) short sHt[64 * 136];      // [p][rn]
  __shared__ __align__(16) short sz[64 * 64];
  __shared__ __align__(16) short su[64 * 64];
  __shared__ float sec[64];
  int row0 = b * Sn + c * CH;
  const short* Pb = (const short*)P;
#pragma unroll
  for (int i = 0; i < 2; ++i) {
    int idx = t + i * 256;
    int r = idx >> 3, pc = (idx & 7) * 8;
    *(short8*)&sz[r * 64 + pc] = *(const short8*)(Pb + (size_t)(row0 + r) * PSTR + h * 64 + pc);
    *(short8*)&su[r * 64 + pc] = *(const short8*)(Pb + (size_t)(row0 + r) * PSTR + 1024 + h * 64 + pc);
  }
  if (c > 0) {
    size_t hbase = ((size_t)((b * NCH + c) * Hn + h)) * 8192;
#pragma unroll
    for (int i = 0; i < 4; ++i) {
      int idx = t + i * 256;
      int r = idx >> 4, kk = (idx & 15) * 8;
      *(short8*)&sC[r * 136 + kk] = *(const short8*)(Pb + (size_t)(row0 + r) * PSTR + 4096 + h * 128 + kk);
    }
#pragma unroll
    for (int i = 0; i < 32; ++i) {
      int idx = t + i * 256;
      int rn = idx >> 6, p = idx & 63;
      sHt[p * 136 + rn] = f2bfs(Hp[hbase + idx]);
    }
    if (t < 64) sec[t] = ec[((size_t)((b * NCH + c) * Hn + h)) * 64 + t];
  }
  __syncthreads();
  int fr = lane & 15, fq = (lane >> 4) * 8, q4 = (lane >> 4) * 4;
  f32x4 acc[4];
#pragma unroll
  for (int j = 0; j < 4; ++j) acc[j] = (f32x4){0.f, 0.f, 0.f, 0.f};
  if (c > 0) {
    short8 af[4];
#pragma unroll
    for (int k = 0; k < 4; ++k) af[k] = *(short8*)&sC[(16 * wv + fr) * 136 + k * 32 + fq];
#pragma unroll
    for (int j = 0; j < 4; ++j)
#pragma unroll
      for (int k = 0; k < 4; ++k) {
        short8 bf = *(short8*)&sHt[(16 * j + fr) * 136 + k * 32 + fq];
        acc[j] = __builtin_amdgcn_mfma_f32_16x16x32_bf16(af[k], bf, acc[j], 0, 0, 0);
      }
  }
  float dsk = Dsk[h];
#pragma unroll
  for (int j = 0; j < 4; ++j) {
    int col = 16 * j + fr;
#pragma unroll
    for (int r = 0; r < 4; ++r) {
      int tt = 16 * wv + q4 + r;
      size_t a = (size_t)(row0 + tt) * DINn + h * 64 + col;
      float val = ys[a];
      if (c > 0) val += sec[tt] * acc[j][r];
      float uu = bfs2f(su[tt * 64 + col]);
      float zz = bfs2f(sz[tt * 64 + col]);
      float sil = zz / (1.f + __expf(-zz));
      y2b[a] = f2bf((val + uu * dsk) * sil);
    }
  }
}

extern "C" void kernel_launch(void* const* d_in, const int* in_sizes, int n_in,
                              void* d_out, int out_size, void* d_ws, size_t ws_size,
                              hipStream_t stream) {
  const float* x    = (const float*)d_in[0];
  const float* mask = (const float*)d_in[1];
  const float* n1w  = (const float*)d_in[2];
  const float* n2w  = (const float*)d_in[3];
  const float* Wz   = (const float*)d_in[4];
  const float* Wx   = (const float*)d_in[5];
  const float* Wb   = (const float*)d_in[6];
  const float* Wc   = (const float*)d_in[7];
  const float* Wdt  = (const float*)d_in[8];
  const float* dtb  = (const float*)d_in[9];
  const float* Alog = (const float*)d_in[10];
  const float* Dsk  = (const float*)d_in[11];
  const float* Wout = (const float*)d_in[12];
  const float* w1   = (const float*)d_in[13];
  const float* w2   = (const float*)d_in[14];
  const float* w3   = (const float*)d_in[15];

  char* ws = (char*)d_ws;
  size_t off = 0;
  auto alloc = [&](size_t bytes) {
    char* p = ws + off;
    off += (bytes + 255) & ~(size_t)255;
    return p;
  };
  __hip_bfloat16* xnb = (__hip_bfloat16*)alloc((size_t)BSn * Dn * 2);
  __hip_bfloat16* P = (__hip_bfloat16*)alloc((size_t)BSn * PSTR * 2);
  float* dt  = (float*)alloc((size_t)BSn * Hn * 4);
  float* la  = (float*)alloc((size_t)BSn * Hn * 4);
  float* ys  = (float*)alloc((size_t)BSn * DINn * 4);
  float* ecL = (float*)alloc((size_t)Bn * NCH * Hn * 4);
  float* ec  = (float*)alloc((size_t)Bn * NCH * Hn * 64 * 4);
  __hip_bfloat16* WallT = (__hip_bfloat16*)alloc((size_t)PSTR * Dn * 2);   // [z|u|B|C]^T
  __hip_bfloat16* WoutT = (__hip_bfloat16*)alloc((size_t)Dn * DINn * 2);
  __hip_bfloat16* w13T  = (__hip_bfloat16*)alloc((size_t)FSTR * Dn * 2);   // [w1|w3]^T
  __hip_bfloat16* w2T   = (__hip_bfloat16*)alloc((size_t)Dn * 1408 * 2);   // K-pad 1408 (BK=64)
  // overlaid arena:
  //   Sbuf [0, 16.78M)     live: chunk_intra -> chunk_state
  //   Hp   [16.78M, 33.55M) live: chunk_state -> inter_gate
  //   y2b  [0, 4.2M)        live: inter_gate -> gemm64<1>   (over dead Sbuf)
  //   xres [8.39M, 12.58M)  live: gemm64<1> -> gemm64<2>    (over dead Sbuf)
  //   Hf   [16.78M, 28M)    live: ffn gemm -> gemm64<2>     (over dead Hp)
  char* arena = alloc(34000000);
  float* Sbuf = (float*)arena;
  float* Hp   = (float*)(arena + 16777216);
  __hip_bfloat16* y2b = (__hip_bfloat16*)arena;
  float* xres = (float*)(arena + 8388608);
  __hip_bfloat16* Hf = (__hip_bfloat16*)(arena + 16777216);

  // -------- transpose job table (single dispatch) --------
  T8 td;
  td.src[0] = Wz;   td.dst[0] = WallT;                      td.Rr[0] = 512;  td.Cc[0] = 1024; td.RrPad[0] = 512;  td.CcPad[0] = 1024;
  td.src[1] = Wx;   td.dst[1] = WallT + (size_t)1024 * 512; td.Rr[1] = 512;  td.Cc[1] = 1024; td.RrPad[1] = 512;  td.CcPad[1] = 1024;
  td.src[2] = Wb;   td.dst[2] = WallT + (size_t)2048 * 512; td.Rr[2] = 512;  td.Cc[2] = 2048; td.RrPad[2] = 512;  td.CcPad[2] = 2048;
  td.src[3] = Wc;   td.dst[3] = WallT + (size_t)4096 * 512; td.Rr[3] = 512;  td.Cc[3] = 2048; td.RrPad[3] = 512;  td.CcPad[3] = 2048;
  td.src[4] = Wout; td.dst[4] = WoutT;                      td.Rr[4] = 1024; td.Cc[4] = 512;  td.RrPad[4] = 1024; td.CcPad[4] = 512;
  td.src[5] = w1;   td.dst[5] = w13T;                       td.Rr[5] = 512;  td.Cc[5] = 1368; td.RrPad[5] = 512;  td.CcPad[5] = 1368;
  td.src[6] = w3;   td.dst[6] = w13T + (size_t)1368 * 512;  td.Rr[6] = 512;  td.Cc[6] = 1368; td.RrPad[6] = 512;  td.CcPad[6] = 1368;
  td.src[7] = w2;   td.dst[7] = w2T;                        td.Rr[7] = 1368; td.Cc[7] = 512;  td.RrPad[7] = 1408; td.CcPad[7] = 512;  // zero K-pad
  int tot = 0;
  for (int i = 0; i < 8; ++i) {
    td.gw[i] = (td.CcPad[i] + 31) / 32;
    int gh = (td.RrPad[i] + 31) / 32;
    td.start[i] = tot;
    tot += td.gw[i] * gh;
  }
  td.start[8] = tot;

  transpose8_kernel<<<tot, dim3(32, 8), 0, stream>>>(td);
  rmsnorm1_dt_kernel<<<BSn, 256, 0, stream>>>(x, n1w, mask, Wdt, dtb, Alog, xnb, dt, la);
  gemm_kernel<<<dim3(16, 48), 256, 0, stream>>>(xnb, WallT, P, BSn, PSTR, Dn);
  chunk_intra_kernel<<<Bn * NCH * Hn, 256, 0, stream>>>(P, dt, la, ys, Sbuf, ecL, ec);
  chunk_state_kernel<<<Bn * Hn * 32, 256, 0, stream>>>(Sbuf, ecL, Hp);
  inter_gate_kernel<<<Bn * NCH * Hn, 256, 0, stream>>>(P, Hp, ec, ys, Dsk, y2b);
  gemm64_ep_kernel<1, 0><<<dim3(32, 8), 256, 0, stream>>>(y2b, WoutT, x, mask, xres, BSn, Dn, DINn, DINn);
  rmsnorm2_kernel<<<BSn, 256, 0, stream>>>(xres, n2w, xnb);
  gemm_kernel<<<dim3(16, 22), 256, 0, stream>>>(xnb, w13T, Hf, BSn, FSTR, Dn);
  gemm64_ep_kernel<2, 1><<<dim3(32, 8), 256, 0, stream>>>(Hf, w2T, xres, mask, (float*)d_out, BSn, Dn, 1408, DFFn);
}

// Round 9
// 251.186 us; speedup vs baseline: 2.4925x; 2.4925x over previous
//
#include <hip/hip_runtime.h>
#include <hip/hip_bf16.h>
#include <math.h>

#define Bn 4
#define Sn 512
#define Dn 512
#define DINn 1024
#define Hn 16
#define Pn 64
#define RNn 128
#define DFFn 1368
#define BSn (Bn*Sn)
#define CH 64
#define NCH (Sn/CH)   // 8
#define PSTR 6144     // fused proj row stride: [z(1024) | u(1024) | B(2048) | C(2048)]
#define FSTR 2736     // fused ffn row stride: [h1(1368) | h3(1368)]

typedef __attribute__((ext_vector_type(8))) short short8;
typedef __attribute__((ext_vector_type(4))) float f32x4;

static __device__ __forceinline__ float bf2f(__hip_bfloat16 v){return __bfloat162float(v);}
static __device__ __forceinline__ __hip_bfloat16 f2bf(float v){return __float2bfloat16(v);}
static __device__ __forceinline__ short f2bfs(float v){ __hip_bfloat16 b=f2bf(v); short s; __builtin_memcpy(&s,&b,2); return s; }
static __device__ __forceinline__ float bfs2f(short s){ __hip_bfloat16 b; __builtin_memcpy(&b,&s,2); return bf2f(b); }

// ---------------- fused 8-way transpose+cast: f32 [Rr x Cc] -> bf16 [CcPad x RrPad] ----------------
struct T8 {
  const float* src[8];
  __hip_bfloat16* dst[8];
  int Rr[8], Cc[8], RrPad[8], CcPad[8], gw[8];
  int start[9];
};

__global__ void transpose8_kernel(T8 d) {
  int bid = blockIdx.x;
  int i = 0;
#pragma unroll
  for (int k = 1; k < 8; ++k) if (bid >= d.start[k]) i = k;
  int rel = bid - d.start[i];
  int gx = rel % d.gw[i], gy = rel / d.gw[i];
  const float* __restrict__ in = d.src[i];
  __hip_bfloat16* __restrict__ out = d.dst[i];
  int Rr = d.Rr[i], Cc = d.Cc[i], RrPad = d.RrPad[i], CcPad = d.CcPad[i];
  __shared__ __hip_bfloat16 tile[32][33];
  int c0 = gx * 32, r0 = gy * 32;
  int tx = threadIdx.x, ty = threadIdx.y;
  for (int k = ty; k < 32; k += 8) {
    int r = r0 + k, cc = c0 + tx;
    tile[k][tx] = (r < Rr && cc < Cc) ? f2bf(in[(size_t)r * Cc + cc]) : f2bf(0.f);
  }
  __syncthreads();
  for (int k = ty; k < 32; k += 8) {
    int r = c0 + k, cc = r0 + tx;
    if (r < CcPad && cc < RrPad) out[(size_t)r * RrPad + cc] = tile[tx][k];
  }
}

// ---------------- rmsnorm1 * mask -> bf16, fused dt/la ----------------
__global__ void rmsnorm1_dt_kernel(const float* __restrict__ x,
                                   const float* __restrict__ w,
                                   const float* __restrict__ mask,
                                   const float* __restrict__ Wdt,
                                   const float* __restrict__ dtb,
                                   const float* __restrict__ Alog,
                                   __hip_bfloat16* __restrict__ outb,
                                   float* __restrict__ dt, float* __restrict__ la) {
  __shared__ float xs[Dn];
  __shared__ float red[4];
  int row = blockIdx.x, t = threadIdx.x;
  const float* xr = x + (size_t)row * Dn;
  float v0 = xr[t], v1 = xr[t + 256];
  float ss = v0 * v0 + v1 * v1;
#pragma unroll
  for (int o = 32; o > 0; o >>= 1) ss += __shfl_down(ss, o);
  if ((t & 63) == 0) red[t >> 6] = ss;
  __syncthreads();
  float tot = red[0] + red[1] + red[2] + red[3];
  float sc = rsqrtf(tot * (1.f / Dn) + 1e-6f) * mask[row];
  float o0 = v0 * sc * w[t], o1v = v1 * sc * w[t + 256];
  outb[(size_t)row * Dn + t] = f2bf(o0);
  outb[(size_t)row * Dn + t + 256] = f2bf(o1v);
  xs[t] = o0;
  xs[t + 256] = o1v;
  __syncthreads();
  int h = t >> 4, j = t & 15;
  float s = 0.f;
  for (int k = j * 32; k < j * 32 + 32; ++k) s = fmaf(xs[k], Wdt[k * Hn + h], s);
#pragma unroll
  for (int o = 8; o > 0; o >>= 1) s += __shfl_down(s, o, 16);
  if (j == 0) {
    float v = s + dtb[h];
    float sp = (v > 20.f) ? v : log1pf(expf(v));
    float Ah = expf(Alog[h]);
    dt[(size_t)row * Hn + h] = sp;
    la[(size_t)row * Hn + h] = -Ah * sp;
  }
}

// ---------------- rmsnorm (f32 in, no mask) -> bf16 ----------------
__global__ void rmsnorm2_kernel(const float* __restrict__ x,
                                const float* __restrict__ w,
                                __hip_bfloat16* __restrict__ out) {
  int row = blockIdx.x, t = threadIdx.x;
  const float* xr = x + (size_t)row * Dn;
  float v0 = xr[t], v1 = xr[t + 256];
  float ss = v0 * v0 + v1 * v1;
#pragma unroll
  for (int o = 32; o > 0; o >>= 1) ss += __shfl_down(ss, o);
  __shared__ float red[4];
  if ((t & 63) == 0) red[t >> 6] = ss;
  __syncthreads();
  float tot = red[0] + red[1] + red[2] + red[3];
  float sc = rsqrtf(tot * (1.f / Dn) + 1e-6f);
  out[(size_t)row * Dn + t] = f2bf(v0 * sc * w[t]);
  out[(size_t)row * Dn + t + 256] = f2bf(v1 * sc * w[t + 256]);
}

// ---------------- GEMM 128x128: single-buffer LDS + scalar register prefetch (round-5 proven) ----------------
__global__ __launch_bounds__(256) void gemm_kernel(
    const __hip_bfloat16* __restrict__ A, const __hip_bfloat16* __restrict__ BT,
    __hip_bfloat16* __restrict__ C, int M, int N, int K) {
  __shared__ short As[128][40];
  __shared__ short Bs[128][40];
  int m0 = blockIdx.x * 128, n0 = blockIdx.y * 128;
  int t = threadIdx.x;
  int lane = t & 63, wv = t >> 6;
  int wm = (wv & 1) * 64, wn = (wv >> 1) * 64;
  f32x4 acc[4][4];
#pragma unroll
  for (int i = 0; i < 4; ++i)
#pragma unroll
    for (int j = 0; j < 4; ++j) acc[i][j] = (f32x4){0.f, 0.f, 0.f, 0.f};
  const short* Ag = (const short*)A;
  const short* Bg = (const short*)BT;
  int sr = t >> 2;
  int sc = (t & 3) * 8;
  int rb0 = n0 + sr, rb1 = n0 + sr + 64;
  bool bv0 = rb0 < N, bv1 = rb1 < N;
  const short* Ap0 = Ag + (size_t)(m0 + sr) * K + sc;
  const short* Ap1 = Ag + (size_t)(m0 + sr + 64) * K + sc;
  const short* Bp0 = Bg + (size_t)rb0 * K + sc;
  const short* Bp1 = Bg + (size_t)rb1 * K + sc;
  int kTiles = (K + 31) >> 5;
  short8 a0 = 0, a1 = 0, b0 = 0, b1 = 0;
  auto loadt = [&](int k0) {
    a0 = *(const short8*)(Ap0 + k0);
    a1 = *(const short8*)(Ap1 + k0);
    b0 = bv0 ? *(const short8*)(Bp0 + k0) : (short8)0;
    b1 = bv1 ? *(const short8*)(Bp1 + k0) : (short8)0;
  };
  loadt(0);
  int fr = lane & 15, fq = (lane >> 4) * 8;
  for (int kt = 0; kt < kTiles; ++kt) {
    __syncthreads();
    *(short8*)&As[sr][sc] = a0;
    *(short8*)&As[sr + 64][sc] = a1;
    *(short8*)&Bs[sr][sc] = b0;
    *(short8*)&Bs[sr + 64][sc] = b1;
    __syncthreads();
    if (kt + 1 < kTiles) loadt((kt + 1) << 5);   // prefetch; overlaps MFMA
    short8 af[4], bfr[4];
#pragma unroll
    for (int i = 0; i < 4; ++i) af[i] = *(const short8*)&As[wm + i * 16 + fr][fq];
#pragma unroll
    for (int i = 0; i < 4; ++i) bfr[i] = *(const short8*)&Bs[wn + i * 16 + fr][fq];
#pragma unroll
    for (int mi = 0; mi < 4; ++mi)
#pragma unroll
      for (int ni = 0; ni < 4; ++ni)
        acc[mi][ni] = __builtin_amdgcn_mfma_f32_16x16x32_bf16(af[mi], bfr[ni], acc[mi][ni], 0, 0, 0);
  }
  int fq4 = (lane >> 4) * 4;
#pragma unroll
  for (int mi = 0; mi < 4; ++mi)
#pragma unroll
    for (int ni = 0; ni < 4; ++ni) {
      int col = n0 + wn + ni * 16 + fr;
      if (col < N) {
        int rowb = m0 + wm + mi * 16 + fq4;
#pragma unroll
        for (int r = 0; r < 4; ++r)
          C[(size_t)(rowb + r) * N + col] = f2bf(acc[mi][ni][r]);
      }
    }
}

// ---------------- GEMM 64x64, BK=64, single-buffer + scalar prefetch, fused epilogue (round-7 proven) ----------------
// MODE 1: out = aux + acc*mask[row]; MODE 2: out = (aux + acc)*mask[row]. N exact (512).
// GATE=1: A-tile = silu(h1)*h3 computed from Hf (row stride FSTR) during staging; K padded, Kreal guards.
template <int MODE, int GATE>
__global__ __launch_bounds__(256) void gemm64_ep_kernel(
    const __hip_bfloat16* __restrict__ A, const __hip_bfloat16* __restrict__ BT,
    const float* __restrict__ aux, const float* __restrict__ mask,
    float* __restrict__ out, int M, int N, int K, int Kreal) {
  __shared__ short As[64][72];
  __shared__ short Bs[64][72];
  int m0 = blockIdx.x * 64, n0 = blockIdx.y * 64;
  int t = threadIdx.x;
  int lane = t & 63, wv = t >> 6;
  int wm = (wv & 1) * 32, wn = (wv >> 1) * 32;
  f32x4 acc[2][2];
#pragma unroll
  for (int i = 0; i < 2; ++i)
#pragma unroll
    for (int j = 0; j < 2; ++j) acc[i][j] = (f32x4){0.f, 0.f, 0.f, 0.f};
  const short* Ag = (const short*)A;
  const short* Bg = (const short*)BT;
  int sr = t >> 2;
  int sc = (t & 3) * 16;
  const short* Bp = Bg + (size_t)(n0 + sr) * K + sc;
  short8 a0 = 0, a1 = 0, b0 = 0, b1 = 0;
  auto loadt = [&](int k0) {
    b0 = *(const short8*)(Bp + k0);
    b1 = *(const short8*)(Bp + k0 + 8);
    if (GATE) {
      const short* hrow = Ag + (size_t)(m0 + sr) * FSTR;
      int k = k0 + sc;
      short8 h1a = *(const short8*)(hrow + k);
      short8 h1b = *(const short8*)(hrow + k + 8);
      short8 h3a = *(const short8*)(hrow + DFFn + k);
      short8 h3b = *(const short8*)(hrow + DFFn + k + 8);
#pragma unroll
      for (int j = 0; j < 8; ++j) {
        float v = bfs2f(h1a[j]);
        float sil = v / (1.f + __expf(-v));
        a0[j] = (k + j < Kreal) ? f2bfs(sil * bfs2f(h3a[j])) : (short)0;
        float v2 = bfs2f(h1b[j]);
        float sil2 = v2 / (1.f + __expf(-v2));
        a1[j] = (k + 8 + j < Kreal) ? f2bfs(sil2 * bfs2f(h3b[j])) : (short)0;
      }
    } else {
      const short* Ap = Ag + (size_t)(m0 + sr) * K + sc;
      a0 = *(const short8*)(Ap + k0);
      a1 = *(const short8*)(Ap + k0 + 8);
    }
  };
  loadt(0);
  int fr = lane & 15, fq = (lane >> 4) * 8;
  int kTiles = K >> 6;
  for (int kt = 0; kt < kTiles; ++kt) {
    __syncthreads();
    *(short8*)&As[sr][sc] = a0;
    *(short8*)&As[sr][sc + 8] = a1;
    *(short8*)&Bs[sr][sc] = b0;
    *(short8*)&Bs[sr][sc + 8] = b1;
    __syncthreads();
    if (kt + 1 < kTiles) loadt((kt + 1) << 6);
#pragma unroll
    for (int kk = 0; kk < 2; ++kk) {
      short8 af[2], bfr[2];
#pragma unroll
      for (int i = 0; i < 2; ++i) af[i] = *(const short8*)&As[wm + i * 16 + fr][kk * 32 + fq];
#pragma unroll
      for (int i = 0; i < 2; ++i) bfr[i] = *(const short8*)&Bs[wn + i * 16 + fr][kk * 32 + fq];
#pragma unroll
      for (int mi = 0; mi < 2; ++mi)
#pragma unroll
        for (int ni = 0; ni < 2; ++ni)
          acc[mi][ni] = __builtin_amdgcn_mfma_f32_16x16x32_bf16(af[mi], bfr[ni], acc[mi][ni], 0, 0, 0);
    }
  }
  int fq4 = (lane >> 4) * 4;
#pragma unroll
  for (int mi = 0; mi < 2; ++mi)
#pragma unroll
    for (int ni = 0; ni < 2; ++ni) {
      int col = n0 + wn + ni * 16 + fr;
#pragma unroll
      for (int r = 0; r < 4; ++r) {
        int row = m0 + wm + mi * 16 + fq4 + r;
        float m = mask[row];
        size_t a = (size_t)row * N + col;
        float v = acc[mi][ni][r];
        if (MODE == 1) out[a] = aux[a] + v * m;
        else           out[a] = (aux[a] + v) * m;
      }
    }
}

// ---------------- chunked scan: intra-chunk + chunk-state ----------------
__global__ __launch_bounds__(256) void chunk_intra_kernel(
    const __hip_bfloat16* __restrict__ P, const float* __restrict__ dt,
    const float* __restrict__ la, float* __restrict__ ys,
    float* __restrict__ Sbuf, float* __restrict__ ecL, float* __restrict__ ec) {
  int id = blockIdx.x;
  int h = id & 15, c = (id >> 4) & 7, b = id >> 7;
  int t = threadIdx.x, lane = t & 63, wv = t >> 6;
  __shared__ __align__(16) char smem[55040];
  short* sCB = (short*)smem;             // sC [64][136] (phase<=3a), sBt [128][72] (phase>=3b)
  short* sB  = (short*)(smem + 18432);   // [64][136]
  short* sUD = (short*)(smem + 35840);   // [64 p][72]  (s-minor)
  short* sG  = (short*)(smem + 45056);   // [64 t][72]  (s-minor)
  float* scum = (float*)(smem + 54272);  // [64]
  float* sws  = scum + 64;
  float* sdt  = sws + 64;
  int row0 = b * Sn + c * CH;
  const short* Pb = (const short*)P;
#pragma unroll
  for (int i = 0; i < 4; ++i) {
    int idx = t + i * 256;
    int r = idx >> 4, kk = (idx & 15) * 8;
    *(short8*)&sCB[r * 136 + kk] = *(const short8*)(Pb + (size_t)(row0 + r) * PSTR + 4096 + h * 128 + kk);
    *(short8*)&sB [r * 136 + kk] = *(const short8*)(Pb + (size_t)(row0 + r) * PSTR + 2048 + h * 128 + kk);
  }
  if (t < 64) { sdt[t] = dt[(size_t)(row0 + t) * Hn + h]; scum[t] = la[(size_t)(row0 + t) * Hn + h]; }
  __syncthreads();
  if (wv == 0) {
    float v = scum[lane];
#pragma unroll
    for (int o = 1; o < 64; o <<= 1) { float n = __shfl_up(v, o); if (lane >= o) v += n; }
    scum[lane] = v;
    float c63 = __shfl(v, 63);
    sws[lane] = __expf(c63 - v);
    ec[((size_t)((b * NCH + c) * Hn + h)) * 64 + lane] = __expf(v);
    if (lane == 0) ecL[(b * NCH + c) * Hn + h] = __expf(c63);
  }
#pragma unroll
  for (int i = 0; i < 2; ++i) {
    int idx = t + i * 256;
    int s = idx >> 3, pc = (idx & 7) * 8;
    short8 uv = *(const short8*)(Pb + (size_t)(row0 + s) * PSTR + 1024 + h * 64 + pc);
    float dv = sdt[s];
#pragma unroll
    for (int j = 0; j < 8; ++j) sUD[(pc + j) * 72 + s] = f2bfs(bfs2f(uv[j]) * dv);
  }
  __syncthreads();
  int fr = lane & 15, fq = (lane >> 4) * 8, q4 = (lane >> 4) * 4;
  {
    short8 af[4];
#pragma unroll
    for (int k = 0; k < 4; ++k) af[k] = *(short8*)&sCB[(16 * wv + fr) * 136 + k * 32 + fq];
#pragma unroll
    for (int j = 0; j < 4; ++j) {
      f32x4 acc = (f32x4){0.f, 0.f, 0.f, 0.f};
#pragma unroll
      for (int k = 0; k < 4; ++k) {
        short8 bf = *(short8*)&sB[(16 * j + fr) * 136 + k * 32 + fq];
        acc = __builtin_amdgcn_mfma_f32_16x16x32_bf16(af[k], bf, acc, 0, 0, 0);
      }
      int ss = 16 * j + fr;
      float cs = scum[ss];
#pragma unroll
      for (int r = 0; r < 4; ++r) {
        int tt = 16 * wv + q4 + r;
        float w = (ss <= tt) ? __expf(scum[tt] - cs) : 0.f;
        sG[tt * 72 + ss] = f2bfs(acc[r] * w);
      }
    }
  }
  __syncthreads();
#pragma unroll
  for (int i = 0; i < 32; ++i) {
    int idx = t + i * 256;
    int rn = idx >> 6, s = idx & 63;
    sCB[rn * 72 + s] = f2bfs(bfs2f(sB[s * 136 + rn]) * sws[s]);
  }
  __syncthreads();
  {
    short8 ag[2];
#pragma unroll
    for (int k = 0; k < 2; ++k) ag[k] = *(short8*)&sG[(16 * wv + fr) * 72 + k * 32 + fq];
#pragma unroll
    for (int j = 0; j < 4; ++j) {
      f32x4 acc = (f32x4){0.f, 0.f, 0.f, 0.f};
#pragma unroll
      for (int k = 0; k < 2; ++k) {
        short8 bf = *(short8*)&sUD[(16 * j + fr) * 72 + k * 32 + fq];
        acc = __builtin_amdgcn_mfma_f32_16x16x32_bf16(ag[k], bf, acc, 0, 0, 0);
      }
#pragma unroll
      for (int r = 0; r < 4; ++r)
        ys[(size_t)(row0 + 16 * wv + q4 + r) * DINn + h * 64 + 16 * j + fr] = acc[r];
    }
  }
#pragma unroll
  for (int mt0 = 0; mt0 < 2; ++mt0) {
    int mt = wv * 2 + mt0;
    short8 ab[2];
#pragma unroll
    for (int k = 0; k < 2; ++k) ab[k] = *(short8*)&sCB[(16 * mt + fr) * 72 + k * 32 + fq];
#pragma unroll
    for (int j = 0; j < 4; ++j) {
      f32x4 acc = (f32x4){0.f, 0.f, 0.f, 0.f};
#pragma unroll
      for (int k = 0; k < 2; ++k) {
        short8 bf = *(short8*)&sUD[(16 * j + fr) * 72 + k * 32 + fq];
        acc = __builtin_amdgcn_mfma_f32_16x16x32_bf16(ab[k], bf, acc, 0, 0, 0);
      }
#pragma unroll
      for (int r = 0; r < 4; ++r)
        Sbuf[((size_t)((b * NCH + c) * Hn + h) * RNn + 16 * mt + q4 + r) * 64 + 16 * j + fr] = acc[r];
    }
  }
}

// ---------------- prefix over chunk states ----------------
__global__ void chunk_state_kernel(const float* __restrict__ Sbuf, const float* __restrict__ ecL,
                                   float* __restrict__ Hp) {
  int bh = blockIdx.x >> 5;
  int j = (blockIdx.x & 31) * 256 + threadIdx.x;
  int b = bh >> 4, h = bh & 15;
  float hp = 0.f;
#pragma unroll
  for (int c = 0; c < NCH; ++c) {
    size_t addr = ((size_t)((b * NCH + c) * Hn + h)) * 8192 + j;
    Hp[addr] = hp;
    hp = ecL[(b * NCH + c) * Hn + h] * hp + Sbuf[addr];
  }
}

// ---------------- inter-chunk + gate fused ----------------
__global__ __launch_bounds__(256) void inter_gate_kernel(
    const __hip_bfloat16* __restrict__ P, const float* __restrict__ Hp,
    const float* __restrict__ ec, const float* __restrict__ ys,
    const float* __restrict__ Dsk, __hip_bfloat16* __restrict__ y2b) {
  int id = blockIdx.x;
  int h = id & 15, c = (id >> 4) & 7, b = id >> 7;
  int t = threadIdx.x, lane = t & 63, wv = t >> 6;
  __shared__ __align__(16) short sC[64 * 136];
  __shared__ __align__(16) short sHt[64 * 136];      // [p][rn]
  __shared__ __align__(16) short sz[64 * 64];
  __shared__ __align__(16) short su[64 * 64];
  __shared__ float sec[64];
  int row0 = b * Sn + c * CH;
  const short* Pb = (const short*)P;
#pragma unroll
  for (int i = 0; i < 2; ++i) {
    int idx = t + i * 256;
    int r = idx >> 3, pc = (idx & 7) * 8;
    *(short8*)&sz[r * 64 + pc] = *(const short8*)(Pb + (size_t)(row0 + r) * PSTR + h * 64 + pc);
    *(short8*)&su[r * 64 + pc] = *(const short8*)(Pb + (size_t)(row0 + r) * PSTR + 1024 + h * 64 + pc);
  }
  if (c > 0) {
    size_t hbase = ((size_t)((b * NCH + c) * Hn + h)) * 8192;
#pragma unroll
    for (int i = 0; i < 4; ++i) {
      int idx = t + i * 256;
      int r = idx >> 4, kk = (idx & 15) * 8;
      *(short8*)&sC[r * 136 + kk] = *(const short8*)(Pb + (size_t)(row0 + r) * PSTR + 4096 + h * 128 + kk);
    }
#pragma unroll
    for (int i = 0; i < 32; ++i) {
      int idx = t + i * 256;
      int rn = idx >> 6, p = idx & 63;
      sHt[p * 136 + rn] = f2bfs(Hp[hbase + idx]);
    }
    if (t < 64) sec[t] = ec[((size_t)((b * NCH + c) * Hn + h)) * 64 + t];
  }
  __syncthreads();
  int fr = lane & 15, fq = (lane >> 4) * 8, q4 = (lane >> 4) * 4;
  f32x4 acc[4];
#pragma unroll
  for (int j = 0; j < 4; ++j) acc[j] = (f32x4){0.f, 0.f, 0.f, 0.f};
  if (c > 0) {
    short8 af[4];
#pragma unroll
    for (int k = 0; k < 4; ++k) af[k] = *(short8*)&sC[(16 * wv + fr) * 136 + k * 32 + fq];
#pragma unroll
    for (int j = 0; j < 4; ++j)
#pragma unroll
      for (int k = 0; k < 4; ++k) {
        short8 bf = *(short8*)&sHt[(16 * j + fr) * 136 + k * 32 + fq];
        acc[j] = __builtin_amdgcn_mfma_f32_16x16x32_bf16(af[k], bf, acc[j], 0, 0, 0);
      }
  }
  float dsk = Dsk[h];
#pragma unroll
  for (int j = 0; j < 4; ++j) {
    int col = 16 * j + fr;
#pragma unroll
    for (int r = 0; r < 4; ++r) {
      int tt = 16 * wv + q4 + r;
      size_t a = (size_t)(row0 + tt) * DINn + h * 64 + col;
      float val = ys[a];
      if (c > 0) val += sec[tt] * acc[j][r];
      float uu = bfs2f(su[tt * 64 + col]);
      float zz = bfs2f(sz[tt * 64 + col]);
      float sil = zz / (1.f + __expf(-zz));
      y2b[a] = f2bf((val + uu * dsk) * sil);
    }
  }
}

extern "C" void kernel_launch(void* const* d_in, const int* in_sizes, int n_in,
                              void* d_out, int out_size, void* d_ws, size_t ws_size,
                              hipStream_t stream) {
  const float* x    = (const float*)d_in[0];
  const float* mask = (const float*)d_in[1];
  const float* n1w  = (const float*)d_in[2];
  const float* n2w  = (const float*)d_in[3];
  const float* Wz   = (const float*)d_in[4];
  const float* Wx   = (const float*)d_in[5];
  const float* Wb   = (const float*)d_in[6];
  const float* Wc   = (const float*)d_in[7];
  const float* Wdt  = (const float*)d_in[8];
  const float* dtb  = (const float*)d_in[9];
  const float* Alog = (const float*)d_in[10];
  const float* Dsk  = (const float*)d_in[11];
  const float* Wout = (const float*)d_in[12];
  const float* w1   = (const float*)d_in[13];
  const float* w2   = (const float*)d_in[14];
  const float* w3   = (const float*)d_in[15];

  char* ws = (char*)d_ws;
  size_t off = 0;
  auto alloc = [&](size_t bytes) {
    char* p = ws + off;
    off += (bytes + 255) & ~(size_t)255;
    return p;
  };
  __hip_bfloat16* xnb = (__hip_bfloat16*)alloc((size_t)BSn * Dn * 2);
  __hip_bfloat16* P = (__hip_bfloat16*)alloc((size_t)BSn * PSTR * 2);
  float* dt  = (float*)alloc((size_t)BSn * Hn * 4);
  float* la  = (float*)alloc((size_t)BSn * Hn * 4);
  float* ys  = (float*)alloc((size_t)BSn * DINn * 4);
  float* ecL = (float*)alloc((size_t)Bn * NCH * Hn * 4);
  float* ec  = (float*)alloc((size_t)Bn * NCH * Hn * 64 * 4);
  __hip_bfloat16* WallT = (__hip_bfloat16*)alloc((size_t)PSTR * Dn * 2);   // [z|u|B|C]^T
  __hip_bfloat16* WoutT = (__hip_bfloat16*)alloc((size_t)Dn * DINn * 2);
  __hip_bfloat16* w13T  = (__hip_bfloat16*)alloc((size_t)FSTR * Dn * 2);   // [w1|w3]^T
  __hip_bfloat16* w2T   = (__hip_bfloat16*)alloc((size_t)Dn * 1408 * 2);   // K-pad 1408 (BK=64)
  // overlaid arena:
  //   Sbuf [0, 16.78M)      live: chunk_intra -> chunk_state
  //   Hp   [16.78M, 33.55M) live: chunk_state -> inter_gate
  //   y2b  [0, 4.2M)        live: inter_gate -> gemm64<1>   (over dead Sbuf)
  //   xres [8.39M, 12.58M)  live: gemm64<1> -> gemm64<2>    (over dead Sbuf)
  //   Hf   [16.78M, 28M)    live: ffn gemm -> gemm64<2>     (over dead Hp)
  char* arena = alloc(34000000);
  float* Sbuf = (float*)arena;
  float* Hp   = (float*)(arena + 16777216);
  __hip_bfloat16* y2b = (__hip_bfloat16*)arena;
  float* xres = (float*)(arena + 8388608);
  __hip_bfloat16* Hf = (__hip_bfloat16*)(arena + 16777216);

  // -------- transpose job table (single dispatch) --------
  T8 td;
  td.src[0] = Wz;   td.dst[0] = WallT;                      td.Rr[0] = 512;  td.Cc[0] = 1024; td.RrPad[0] = 512;  td.CcPad[0] = 1024;
  td.src[1] = Wx;   td.dst[1] = WallT + (size_t)1024 * 512; td.Rr[1] = 512;  td.Cc[1] = 1024; td.RrPad[1] = 512;  td.CcPad[1] = 1024;
  td.src[2] = Wb;   td.dst[2] = WallT + (size_t)2048 * 512; td.Rr[2] = 512;  td.Cc[2] = 2048; td.RrPad[2] = 512;  td.CcPad[2] = 2048;
  td.src[3] = Wc;   td.dst[3] = WallT + (size_t)4096 * 512; td.Rr[3] = 512;  td.Cc[3] = 2048; td.RrPad[3] = 512;  td.CcPad[3] = 2048;
  td.src[4] = Wout; td.dst[4] = WoutT;                      td.Rr[4] = 1024; td.Cc[4] = 512;  td.RrPad[4] = 1024; td.CcPad[4] = 512;
  td.src[5] = w1;   td.dst[5] = w13T;                       td.Rr[5] = 512;  td.Cc[5] = 1368; td.RrPad[5] = 512;  td.CcPad[5] = 1368;
  td.src[6] = w3;   td.dst[6] = w13T + (size_t)1368 * 512;  td.Rr[6] = 512;  td.Cc[6] = 1368; td.RrPad[6] = 512;  td.CcPad[6] = 1368;
  td.src[7] = w2;   td.dst[7] = w2T;                        td.Rr[7] = 1368; td.Cc[7] = 512;  td.RrPad[7] = 1408; td.CcPad[7] = 512;  // zero K-pad
  int tot = 0;
  for (int i = 0; i < 8; ++i) {
    td.gw[i] = (td.CcPad[i] + 31) / 32;
    int gh = (td.RrPad[i] + 31) / 32;
    td.start[i] = tot;
    tot += td.gw[i] * gh;
  }
  td.start[8] = tot;

  transpose8_kernel<<<tot, dim3(32, 8), 0, stream>>>(td);
  rmsnorm1_dt_kernel<<<BSn, 256, 0, stream>>>(x, n1w, mask, Wdt, dtb, Alog, xnb, dt, la);
  gemm_kernel<<<dim3(16, 48), 256, 0, stream>>>(xnb, WallT, P, BSn, PSTR, Dn);
  chunk_intra_kernel<<<Bn * NCH * Hn, 256, 0, stream>>>(P, dt, la, ys, Sbuf, ecL, ec);
  chunk_state_kernel<<<Bn * Hn * 32, 256, 0, stream>>>(Sbuf, ecL, Hp);
  inter_gate_kernel<<<Bn * NCH * Hn, 256, 0, stream>>>(P, Hp, ec, ys, Dsk, y2b);
  gemm64_ep_kernel<1, 0><<<dim3(32, 8), 256, 0, stream>>>(y2b, WoutT, x, mask, xres, BSn, Dn, DINn, DINn);
  rmsnorm2_kernel<<<BSn, 256, 0, stream>>>(xres, n2w, xnb);
  gemm_kernel<<<dim3(16, 22), 256, 0, stream>>>(xnb, w13T, Hf, BSn, FSTR, Dn);
  gemm64_ep_kernel<2, 1><<<dim3(32, 8), 256, 0, stream>>>(Hf, w2T, xres, mask, (float*)d_out, BSn, Dn, 1408, DFFn);
}

// Round 10
// 229.452 us; speedup vs baseline: 2.7286x; 1.0947x over previous
//
#include <hip/hip_runtime.h>
#include <hip/hip_bf16.h>
#include <math.h>

#define Bn 4
#define Sn 512
#define Dn 512
#define DINn 1024
#define Hn 16
#define Pn 64
#define RNn 128
#define DFFn 1368
#define KP2 1408      // w2 K padded to BK=64 multiple
#define BSn (Bn*Sn)
#define CH 64
#define NCH (Sn/CH)   // 8
#define PSTR 6144     // fused proj row stride: [z(1024) | u(1024) | B(2048) | C(2048)]
#define FSTR 2736     // fused ffn row stride: [h1(1368) | h3(1368)]

typedef __attribute__((ext_vector_type(8))) short short8;
typedef __attribute__((ext_vector_type(4))) float f32x4;

static __device__ __forceinline__ float bf2f(__hip_bfloat16 v){return __bfloat162float(v);}
static __device__ __forceinline__ __hip_bfloat16 f2bf(float v){return __float2bfloat16(v);}
static __device__ __forceinline__ short f2bfs(float v){ __hip_bfloat16 b=f2bf(v); short s; __builtin_memcpy(&s,&b,2); return s; }
static __device__ __forceinline__ float bfs2f(short s){ __hip_bfloat16 b; __builtin_memcpy(&b,&s,2); return bf2f(b); }

// ---------------- fused 8-way transpose+cast: f32 [Rr x Cc] -> bf16 [CcPad x RrPad] ----------------
struct T8 {
  const float* src[8];
  __hip_bfloat16* dst[8];
  int Rr[8], Cc[8], RrPad[8], CcPad[8], gw[8];
  int start[9];
};

__global__ void transpose8_kernel(T8 d) {
  int bid = blockIdx.x;
  int i = 0;
#pragma unroll
  for (int k = 1; k < 8; ++k) if (bid >= d.start[k]) i = k;
  int rel = bid - d.start[i];
  int gx = rel % d.gw[i], gy = rel / d.gw[i];
  const float* __restrict__ in = d.src[i];
  __hip_bfloat16* __restrict__ out = d.dst[i];
  int Rr = d.Rr[i], Cc = d.Cc[i], RrPad = d.RrPad[i], CcPad = d.CcPad[i];
  __shared__ __hip_bfloat16 tile[32][33];
  int c0 = gx * 32, r0 = gy * 32;
  int tx = threadIdx.x, ty = threadIdx.y;
  for (int k = ty; k < 32; k += 8) {
    int r = r0 + k, cc = c0 + tx;
    tile[k][tx] = (r < Rr && cc < Cc) ? f2bf(in[(size_t)r * Cc + cc]) : f2bf(0.f);
  }
  __syncthreads();
  for (int k = ty; k < 32; k += 8) {
    int r = c0 + k, cc = r0 + tx;
    if (r < CcPad && cc < RrPad) out[(size_t)r * RrPad + cc] = tile[tx][k];
  }
}

// ---------------- rmsnorm1 * mask -> bf16, fused dt/la ----------------
__global__ void rmsnorm1_dt_kernel(const float* __restrict__ x,
                                   const float* __restrict__ w,
                                   const float* __restrict__ mask,
                                   const float* __restrict__ Wdt,
                                   const float* __restrict__ dtb,
                                   const float* __restrict__ Alog,
                                   __hip_bfloat16* __restrict__ outb,
                                   float* __restrict__ dt, float* __restrict__ la) {
  __shared__ float xs[Dn];
  __shared__ float red[4];
  int row = blockIdx.x, t = threadIdx.x;
  const float* xr = x + (size_t)row * Dn;
  float v0 = xr[t], v1 = xr[t + 256];
  float ss = v0 * v0 + v1 * v1;
#pragma unroll
  for (int o = 32; o > 0; o >>= 1) ss += __shfl_down(ss, o);
  if ((t & 63) == 0) red[t >> 6] = ss;
  __syncthreads();
  float tot = red[0] + red[1] + red[2] + red[3];
  float sc = rsqrtf(tot * (1.f / Dn) + 1e-6f) * mask[row];
  float o0 = v0 * sc * w[t], o1v = v1 * sc * w[t + 256];
  outb[(size_t)row * Dn + t] = f2bf(o0);
  outb[(size_t)row * Dn + t + 256] = f2bf(o1v);
  xs[t] = o0;
  xs[t + 256] = o1v;
  __syncthreads();
  int h = t >> 4, j = t & 15;
  float s = 0.f;
  for (int k = j * 32; k < j * 32 + 32; ++k) s = fmaf(xs[k], Wdt[k * Hn + h], s);
#pragma unroll
  for (int o = 8; o > 0; o >>= 1) s += __shfl_down(s, o, 16);
  if (j == 0) {
    float v = s + dtb[h];
    float sp = (v > 20.f) ? v : log1pf(expf(v));
    float Ah = expf(Alog[h]);
    dt[(size_t)row * Hn + h] = sp;
    la[(size_t)row * Hn + h] = -Ah * sp;
  }
}

// ---------------- rmsnorm (f32 in, no mask) -> bf16 ----------------
__global__ void rmsnorm2_kernel(const float* __restrict__ x,
                                const float* __restrict__ w,
                                __hip_bfloat16* __restrict__ out) {
  int row = blockIdx.x, t = threadIdx.x;
  const float* xr = x + (size_t)row * Dn;
  float v0 = xr[t], v1 = xr[t + 256];
  float ss = v0 * v0 + v1 * v1;
#pragma unroll
  for (int o = 32; o > 0; o >>= 1) ss += __shfl_down(ss, o);
  __shared__ float red[4];
  if ((t & 63) == 0) red[t >> 6] = ss;
  __syncthreads();
  float tot = red[0] + red[1] + red[2] + red[3];
  float sc = rsqrtf(tot * (1.f / Dn) + 1e-6f);
  out[(size_t)row * Dn + t] = f2bf(v0 * sc * w[t]);
  out[(size_t)row * Dn + t + 256] = f2bf(v1 * sc * w[t + 256]);
}

// ---------------- GEMM 128x128: single-buffer LDS + scalar register prefetch ----------------
__global__ __launch_bounds__(256) void gemm_kernel(
    const __hip_bfloat16* __restrict__ A, const __hip_bfloat16* __restrict__ BT,
    __hip_bfloat16* __restrict__ C, int M, int N, int K) {
  __shared__ short As[128][40];
  __shared__ short Bs[128][40];
  int m0 = blockIdx.x * 128, n0 = blockIdx.y * 128;
  int t = threadIdx.x;
  int lane = t & 63, wv = t >> 6;
  int wm = (wv & 1) * 64, wn = (wv >> 1) * 64;
  f32x4 acc[4][4];
#pragma unroll
  for (int i = 0; i < 4; ++i)
#pragma unroll
    for (int j = 0; j < 4; ++j) acc[i][j] = (f32x4){0.f, 0.f, 0.f, 0.f};
  const short* Ag = (const short*)A;
  const short* Bg = (const short*)BT;
  int sr = t >> 2;
  int sc = (t & 3) * 8;
  int rb0 = n0 + sr, rb1 = n0 + sr + 64;
  bool bv0 = rb0 < N, bv1 = rb1 < N;
  const short* Ap0 = Ag + (size_t)(m0 + sr) * K + sc;
  const short* Ap1 = Ag + (size_t)(m0 + sr + 64) * K + sc;
  const short* Bp0 = Bg + (size_t)rb0 * K + sc;
  const short* Bp1 = Bg + (size_t)rb1 * K + sc;
  int kTiles = (K + 31) >> 5;
  short8 a0 = 0, a1 = 0, b0 = 0, b1 = 0;
  auto loadt = [&](int k0) {
    a0 = *(const short8*)(Ap0 + k0);
    a1 = *(const short8*)(Ap1 + k0);
    b0 = bv0 ? *(const short8*)(Bp0 + k0) : (short8)0;
    b1 = bv1 ? *(const short8*)(Bp1 + k0) : (short8)0;
  };
  loadt(0);
  int fr = lane & 15, fq = (lane >> 4) * 8;
  for (int kt = 0; kt < kTiles; ++kt) {
    __syncthreads();
    *(short8*)&As[sr][sc] = a0;
    *(short8*)&As[sr + 64][sc] = a1;
    *(short8*)&Bs[sr][sc] = b0;
    *(short8*)&Bs[sr + 64][sc] = b1;
    __syncthreads();
    if (kt + 1 < kTiles) loadt((kt + 1) << 5);   // prefetch; overlaps MFMA
    short8 af[4], bfr[4];
#pragma unroll
    for (int i = 0; i < 4; ++i) af[i] = *(const short8*)&As[wm + i * 16 + fr][fq];
#pragma unroll
    for (int i = 0; i < 4; ++i) bfr[i] = *(const short8*)&Bs[wn + i * 16 + fr][fq];
#pragma unroll
    for (int mi = 0; mi < 4; ++mi)
#pragma unroll
      for (int ni = 0; ni < 4; ++ni)
        acc[mi][ni] = __builtin_amdgcn_mfma_f32_16x16x32_bf16(af[mi], bfr[ni], acc[mi][ni], 0, 0, 0);
  }
  int fq4 = (lane >> 4) * 4;
#pragma unroll
  for (int mi = 0; mi < 4; ++mi)
#pragma unroll
    for (int ni = 0; ni < 4; ++ni) {
      int col = n0 + wn + ni * 16 + fr;
      if (col < N) {
        int rowb = m0 + wm + mi * 16 + fq4;
#pragma unroll
        for (int r = 0; r < 4; ++r)
          C[(size_t)(rowb + r) * N + col] = f2bf(acc[mi][ni][r]);
      }
    }
}

// ---------------- GEMM 64x64, BK=64, single-buffer + scalar prefetch, fused epilogue ----------------
// MODE 1: out = aux + acc*mask[row]; MODE 2: out = (aux + acc)*mask[row]. N exact (512). K%64==0.
template <int MODE>
__global__ __launch_bounds__(256) void gemm64_ep_kernel(
    const __hip_bfloat16* __restrict__ A, const __hip_bfloat16* __restrict__ BT,
    const float* __restrict__ aux, const float* __restrict__ mask,
    float* __restrict__ out, int M, int N, int K) {
  __shared__ short As[64][72];
  __shared__ short Bs[64][72];
  int m0 = blockIdx.x * 64, n0 = blockIdx.y * 64;
  int t = threadIdx.x;
  int lane = t & 63, wv = t >> 6;
  int wm = (wv & 1) * 32, wn = (wv >> 1) * 32;
  f32x4 acc[2][2];
#pragma unroll
  for (int i = 0; i < 2; ++i)
#pragma unroll
    for (int j = 0; j < 2; ++j) acc[i][j] = (f32x4){0.f, 0.f, 0.f, 0.f};
  const short* Ag = (const short*)A;
  const short* Bg = (const short*)BT;
  int sr = t >> 2;
  int sc = (t & 3) * 16;
  const short* Ap = Ag + (size_t)(m0 + sr) * K + sc;
  const short* Bp = Bg + (size_t)(n0 + sr) * K + sc;
  short8 a0 = 0, a1 = 0, b0 = 0, b1 = 0;
  auto loadt = [&](int k0) {
    a0 = *(const short8*)(Ap + k0);
    a1 = *(const short8*)(Ap + k0 + 8);
    b0 = *(const short8*)(Bp + k0);
    b1 = *(const short8*)(Bp + k0 + 8);
  };
  loadt(0);
  int fr = lane & 15, fq = (lane >> 4) * 8;
  int kTiles = K >> 6;
  for (int kt = 0; kt < kTiles; ++kt) {
    __syncthreads();
    *(short8*)&As[sr][sc] = a0;
    *(short8*)&As[sr][sc + 8] = a1;
    *(short8*)&Bs[sr][sc] = b0;
    *(short8*)&Bs[sr][sc + 8] = b1;
    __syncthreads();
    if (kt + 1 < kTiles) loadt((kt + 1) << 6);
#pragma unroll
    for (int kk = 0; kk < 2; ++kk) {
      short8 af[2], bfr[2];
#pragma unroll
      for (int i = 0; i < 2; ++i) af[i] = *(const short8*)&As[wm + i * 16 + fr][kk * 32 + fq];
#pragma unroll
      for (int i = 0; i < 2; ++i) bfr[i] = *(const short8*)&Bs[wn + i * 16 + fr][kk * 32 + fq];
#pragma unroll
      for (int mi = 0; mi < 2; ++mi)
#pragma unroll
        for (int ni = 0; ni < 2; ++ni)
          acc[mi][ni] = __builtin_amdgcn_mfma_f32_16x16x32_bf16(af[mi], bfr[ni], acc[mi][ni], 0, 0, 0);
    }
  }
  int fq4 = (lane >> 4) * 4;
#pragma unroll
  for (int mi = 0; mi < 2; ++mi)
#pragma unroll
    for (int ni = 0; ni < 2; ++ni) {
      int col = n0 + wn + ni * 16 + fr;
#pragma unroll
      for (int r = 0; r < 4; ++r) {
        int row = m0 + wm + mi * 16 + fq4 + r;
        float m = mask[row];
        size_t a = (size_t)row * N + col;
        float v = acc[mi][ni][r];
        if (MODE == 1) out[a] = aux[a] + v * m;
        else           out[a] = (aux[a] + v) * m;
      }
    }
}

// ---------------- gated = silu(h1)*h3 from fused Hf -> bf16, K-padded stride KP2 ----------------
__global__ void ffngate_kernel(const __hip_bfloat16* __restrict__ Hf,
                               __hip_bfloat16* __restrict__ g) {
  int row = blockIdx.x;
  int c8 = threadIdx.x;
  if (c8 >= KP2 / 8) return;
  int c = c8 * 8;
  short* grow = (short*)g + (size_t)row * KP2;
  if (c >= DFFn) {                       // zero the K-pad (171..175)
    *(short8*)(grow + c) = (short8)0;
    return;
  }
  const short* hrow = (const short*)Hf + (size_t)row * FSTR;
  short8 a = *(const short8*)(hrow + c);
  short8 b3 = *(const short8*)(hrow + DFFn + c);
  short8 o;
#pragma unroll
  for (int j = 0; j < 8; ++j) {
    float v = bfs2f(a[j]);
    float sil = v / (1.f + __expf(-v));
    o[j] = f2bfs(sil * bfs2f(b3[j]));
  }
  *(short8*)(grow + c) = o;
}

// ---------------- chunked scan: intra-chunk + chunk-state ----------------
__global__ __launch_bounds__(256) void chunk_intra_kernel(
    const __hip_bfloat16* __restrict__ P, const float* __restrict__ dt,
    const float* __restrict__ la, float* __restrict__ ys,
    float* __restrict__ Sbuf, float* __restrict__ ecL, float* __restrict__ ec) {
  int id = blockIdx.x;
  int h = id & 15, c = (id >> 4) & 7, b = id >> 7;
  int t = threadIdx.x, lane = t & 63, wv = t >> 6;
  __shared__ __align__(16) char smem[55040];
  short* sCB = (short*)smem;             // sC [64][136] (phase<=3a), sBt [128][72] (phase>=3b)
  short* sB  = (short*)(smem + 18432);   // [64][136]
  short* sUD = (short*)(smem + 35840);   // [64 p][72]  (s-minor)
  short* sG  = (short*)(smem + 45056);   // [64 t][72]  (s-minor)
  float* scum = (float*)(smem + 54272);  // [64]
  float* sws  = scum + 64;
  float* sdt  = sws + 64;
  int row0 = b * Sn + c * CH;
  const short* Pb = (const short*)P;
#pragma unroll
  for (int i = 0; i < 4; ++i) {
    int idx = t + i * 256;
    int r = idx >> 4, kk = (idx & 15) * 8;
    *(short8*)&sCB[r * 136 + kk] = *(const short8*)(Pb + (size_t)(row0 + r) * PSTR + 4096 + h * 128 + kk);
    *(short8*)&sB [r * 136 + kk] = *(const short8*)(Pb + (size_t)(row0 + r) * PSTR + 2048 + h * 128 + kk);
  }
  if (t < 64) { sdt[t] = dt[(size_t)(row0 + t) * Hn + h]; scum[t] = la[(size_t)(row0 + t) * Hn + h]; }
  __syncthreads();
  if (wv == 0) {
    float v = scum[lane];
#pragma unroll
    for (int o = 1; o < 64; o <<= 1) { float n = __shfl_up(v, o); if (lane >= o) v += n; }
    scum[lane] = v;
    float c63 = __shfl(v, 63);
    sws[lane] = __expf(c63 - v);
    ec[((size_t)((b * NCH + c) * Hn + h)) * 64 + lane] = __expf(v);
    if (lane == 0) ecL[(b * NCH + c) * Hn + h] = __expf(c63);
  }
#pragma unroll
  for (int i = 0; i < 2; ++i) {
    int idx = t + i * 256;
    int s = idx >> 3, pc = (idx & 7) * 8;
    short8 uv = *(const short8*)(Pb + (size_t)(row0 + s) * PSTR + 1024 + h * 64 + pc);
    float dv = sdt[s];
#pragma unroll
    for (int j = 0; j < 8; ++j) sUD[(pc + j) * 72 + s] = f2bfs(bfs2f(uv[j]) * dv);
  }
  __syncthreads();
  int fr = lane & 15, fq = (lane >> 4) * 8, q4 = (lane >> 4) * 4;
  {
    short8 af[4];
#pragma unroll
    for (int k = 0; k < 4; ++k) af[k] = *(short8*)&sCB[(16 * wv + fr) * 136 + k * 32 + fq];
#pragma unroll
    for (int j = 0; j < 4; ++j) {
      f32x4 acc = (f32x4){0.f, 0.f, 0.f, 0.f};
#pragma unroll
      for (int k = 0; k < 4; ++k) {
        short8 bf = *(short8*)&sB[(16 * j + fr) * 136 + k * 32 + fq];
        acc = __builtin_amdgcn_mfma_f32_16x16x32_bf16(af[k], bf, acc, 0, 0, 0);
      }
      int ss = 16 * j + fr;
      float cs = scum[ss];
#pragma unroll
      for (int r = 0; r < 4; ++r) {
        int tt = 16 * wv + q4 + r;
        float w = (ss <= tt) ? __expf(scum[tt] - cs) : 0.f;
        sG[tt * 72 + ss] = f2bfs(acc[r] * w);
      }
    }
  }
  __syncthreads();
#pragma unroll
  for (int i = 0; i < 32; ++i) {
    int idx = t + i * 256;
    int rn = idx >> 6, s = idx & 63;
    sCB[rn * 72 + s] = f2bfs(bfs2f(sB[s * 136 + rn]) * sws[s]);
  }
  __syncthreads();
  {
    short8 ag[2];
#pragma unroll
    for (int k = 0; k < 2; ++k) ag[k] = *(short8*)&sG[(16 * wv + fr) * 72 + k * 32 + fq];
#pragma unroll
    for (int j = 0; j < 4; ++j) {
      f32x4 acc = (f32x4){0.f, 0.f, 0.f, 0.f};
#pragma unroll
      for (int k = 0; k < 2; ++k) {
        short8 bf = *(short8*)&sUD[(16 * j + fr) * 72 + k * 32 + fq];
        acc = __builtin_amdgcn_mfma_f32_16x16x32_bf16(ag[k], bf, acc, 0, 0, 0);
      }
#pragma unroll
      for (int r = 0; r < 4; ++r)
        ys[(size_t)(row0 + 16 * wv + q4 + r) * DINn + h * 64 + 16 * j + fr] = acc[r];
    }
  }
#pragma unroll
  for (int mt0 = 0; mt0 < 2; ++mt0) {
    int mt = wv * 2 + mt0;
    short8 ab[2];
#pragma unroll
    for (int k = 0; k < 2; ++k) ab[k] = *(short8*)&sCB[(16 * mt + fr) * 72 + k * 32 + fq];
#pragma unroll
    for (int j = 0; j < 4; ++j) {
      f32x4 acc = (f32x4){0.f, 0.f, 0.f, 0.f};
#pragma unroll
      for (int k = 0; k < 2; ++k) {
        short8 bf = *(short8*)&sUD[(16 * j + fr) * 72 + k * 32 + fq];
        acc = __builtin_amdgcn_mfma_f32_16x16x32_bf16(ab[k], bf, acc, 0, 0, 0);
      }
#pragma unroll
      for (int r = 0; r < 4; ++r)
        Sbuf[((size_t)((b * NCH + c) * Hn + h) * RNn + 16 * mt + q4 + r) * 64 + 16 * j + fr] = acc[r];
    }
  }
}

// ---------------- prefix over chunk states ----------------
__global__ void chunk_state_kernel(const float* __restrict__ Sbuf, const float* __restrict__ ecL,
                                   float* __restrict__ Hp) {
  int bh = blockIdx.x >> 5;
  int j = (blockIdx.x & 31) * 256 + threadIdx.x;
  int b = bh >> 4, h = bh & 15;
  float hp = 0.f;
#pragma unroll
  for (int c = 0; c < NCH; ++c) {
    size_t addr = ((size_t)((b * NCH + c) * Hn + h)) * 8192 + j;
    Hp[addr] = hp;
    hp = ecL[(b * NCH + c) * Hn + h] * hp + Sbuf[addr];
  }
}

// ---------------- inter-chunk + gate fused ----------------
__global__ __launch_bounds__(256) void inter_gate_kernel(
    const __hip_bfloat16* __restrict__ P, const float* __restrict__ Hp,
    const float* __restrict__ ec, const float* __restrict__ ys,
    const float* __restrict__ Dsk, __hip_bfloat16* __restrict__ y2b) {
  int id = blockIdx.x;
  int h = id & 15, c = (id >> 4) & 7, b = id >> 7;
  int t = threadIdx.x, lane = t & 63, wv = t >> 6;
  __shared__ __align__(16) short sC[64 * 136];
  __shared__ __align__(16) short sHt[64 * 136];      // [p][rn]
  __shared__ __align__(16) short sz[64 * 64];
  __shared__ __align__(16) short su[64 * 64];
  __shared__ float sec[64];
  int row0 = b * Sn + c * CH;
  const short* Pb = (const short*)P;
#pragma unroll
  for (int i = 0; i < 2; ++i) {
    int idx = t + i * 256;
    int r = idx >> 3, pc = (idx & 7) * 8;
    *(short8*)&sz[r * 64 + pc] = *(const short8*)(Pb + (size_t)(row0 + r) * PSTR + h * 64 + pc);
    *(short8*)&su[r * 64 + pc] = *(const short8*)(Pb + (size_t)(row0 + r) * PSTR + 1024 + h * 64 + pc);
  }
  if (c > 0) {
    size_t hbase = ((size_t)((b * NCH + c) * Hn + h)) * 8192;
#pragma unroll
    for (int i = 0; i < 4; ++i) {
      int idx = t + i * 256;
      int r = idx >> 4, kk = (idx & 15) * 8;
      *(short8*)&sC[r * 136 + kk] = *(const short8*)(Pb + (size_t)(row0 + r) * PSTR + 4096 + h * 128 + kk);
    }
#pragma unroll
    for (int i = 0; i < 32; ++i) {
      int idx = t + i * 256;
      int rn = idx >> 6, p = idx & 63;
      sHt[p * 136 + rn] = f2bfs(Hp[hbase + idx]);
    }
    if (t < 64) sec[t] = ec[((size_t)((b * NCH + c) * Hn + h)) * 64 + t];
  }
  __syncthreads();
  int fr = lane & 15, fq = (lane >> 4) * 8, q4 = (lane >> 4) * 4;
  f32x4 acc[4];
#pragma unroll
  for (int j = 0; j < 4; ++j) acc[j] = (f32x4){0.f, 0.f, 0.f, 0.f};
  if (c > 0) {
    short8 af[4];
#pragma unroll
    for (int k = 0; k < 4; ++k) af[k] = *(short8*)&sC[(16 * wv + fr) * 136 + k * 32 + fq];
#pragma unroll
    for (int j = 0; j < 4; ++j)
#pragma unroll
      for (int k = 0; k < 4; ++k) {
        short8 bf = *(short8*)&sHt[(16 * j + fr) * 136 + k * 32 + fq];
        acc[j] = __builtin_amdgcn_mfma_f32_16x16x32_bf16(af[k], bf, acc[j], 0, 0, 0);
      }
  }
  float dsk = Dsk[h];
#pragma unroll
  for (int j = 0; j < 4; ++j) {
    int col = 16 * j + fr;
#pragma unroll
    for (int r = 0; r < 4; ++r) {
      int tt = 16 * wv + q4 + r;
      size_t a = (size_t)(row0 + tt) * DINn + h * 64 + col;
      float val = ys[a];
      if (c > 0) val += sec[tt] * acc[j][r];
      float uu = bfs2f(su[tt * 64 + col]);
      float zz = bfs2f(sz[tt * 64 + col]);
      float sil = zz / (1.f + __expf(-zz));
      y2b[a] = f2bf((val + uu * dsk) * sil);
    }
  }
}

extern "C" void kernel_launch(void* const* d_in, const int* in_sizes, int n_in,
                              void* d_out, int out_size, void* d_ws, size_t ws_size,
                              hipStream_t stream) {
  const float* x    = (const float*)d_in[0];
  const float* mask = (const float*)d_in[1];
  const float* n1w  = (const float*)d_in[2];
  const float* n2w  = (const float*)d_in[3];
  const float* Wz   = (const float*)d_in[4];
  const float* Wx   = (const float*)d_in[5];
  const float* Wb   = (const float*)d_in[6];
  const float* Wc   = (const float*)d_in[7];
  const float* Wdt  = (const float*)d_in[8];
  const float* dtb  = (const float*)d_in[9];
  const float* Alog = (const float*)d_in[10];
  const float* Dsk  = (const float*)d_in[11];
  const float* Wout = (const float*)d_in[12];
  const float* w1   = (const float*)d_in[13];
  const float* w2   = (const float*)d_in[14];
  const float* w3   = (const float*)d_in[15];

  char* ws = (char*)d_ws;
  size_t off = 0;
  auto alloc = [&](size_t bytes) {
    char* p = ws + off;
    off += (bytes + 255) & ~(size_t)255;
    return p;
  };
  __hip_bfloat16* xnb = (__hip_bfloat16*)alloc((size_t)BSn * Dn * 2);
  __hip_bfloat16* P = (__hip_bfloat16*)alloc((size_t)BSn * PSTR * 2);
  float* dt  = (float*)alloc((size_t)BSn * Hn * 4);
  float* la  = (float*)alloc((size_t)BSn * Hn * 4);
  float* ys  = (float*)alloc((size_t)BSn * DINn * 4);
  float* ecL = (float*)alloc((size_t)Bn * NCH * Hn * 4);
  float* ec  = (float*)alloc((size_t)Bn * NCH * Hn * 64 * 4);
  __hip_bfloat16* WallT = (__hip_bfloat16*)alloc((size_t)PSTR * Dn * 2);   // [z|u|B|C]^T
  __hip_bfloat16* WoutT = (__hip_bfloat16*)alloc((size_t)Dn * DINn * 2);
  __hip_bfloat16* w13T  = (__hip_bfloat16*)alloc((size_t)FSTR * Dn * 2);   // [w1|w3]^T
  __hip_bfloat16* w2T   = (__hip_bfloat16*)alloc((size_t)Dn * KP2 * 2);    // K-pad 1408 (BK=64)
  // overlaid arena:
  //   Sbuf   [0, 16.78M)       live: chunk_intra -> chunk_state
  //   Hp     [16.78M, 33.55M)  live: chunk_state -> inter_gate
  //   y2b    [0, 4.2M)         live: inter_gate -> gemm64<1>   (over dead Sbuf)
  //   xres   [8.39M, 12.58M)   live: gemm64<1> -> gemm64<2>    (over dead Sbuf)
  //   Hf     [16.78M, 27.99M)  live: ffn gemm -> ffngate       (over dead Hp)
  //   gated  [27.99M, 33.76M)  live: ffngate -> gemm64<2>
  char* arena = alloc(34000000);
  float* Sbuf = (float*)arena;
  float* Hp   = (float*)(arena + 16777216);
  __hip_bfloat16* y2b = (__hip_bfloat16*)arena;
  float* xres = (float*)(arena + 8388608);
  __hip_bfloat16* Hf = (__hip_bfloat16*)(arena + 16777216);
  __hip_bfloat16* gatedb = (__hip_bfloat16*)(arena + 27984128);

  // -------- transpose job table (single dispatch) --------
  T8 td;
  td.src[0] = Wz;   td.dst[0] = WallT;                      td.Rr[0] = 512;  td.Cc[0] = 1024; td.RrPad[0] = 512;  td.CcPad[0] = 1024;
  td.src[1] = Wx;   td.dst[1] = WallT + (size_t)1024 * 512; td.Rr[1] = 512;  td.Cc[1] = 1024; td.RrPad[1] = 512;  td.CcPad[1] = 1024;
  td.src[2] = Wb;   td.dst[2] = WallT + (size_t)2048 * 512; td.Rr[2] = 512;  td.Cc[2] = 2048; td.RrPad[2] = 512;  td.CcPad[2] = 2048;
  td.src[3] = Wc;   td.dst[3] = WallT + (size_t)4096 * 512; td.Rr[3] = 512;  td.Cc[3] = 2048; td.RrPad[3] = 512;  td.CcPad[3] = 2048;
  td.src[4] = Wout; td.dst[4] = WoutT;                      td.Rr[4] = 1024; td.Cc[4] = 512;  td.RrPad[4] = 1024; td.CcPad[4] = 512;
  td.src[5] = w1;   td.dst[5] = w13T;                       td.Rr[5] = 512;  td.Cc[5] = 1368; td.RrPad[5] = 512;  td.CcPad[5] = 1368;
  td.src[6] = w3;   td.dst[6] = w13T + (size_t)1368 * 512;  td.Rr[6] = 512;  td.Cc[6] = 1368; td.RrPad[6] = 512;  td.CcPad[6] = 1368;
  td.src[7] = w2;   td.dst[7] = w2T;                        td.Rr[7] = 1368; td.Cc[7] = 512;  td.RrPad[7] = KP2;  td.CcPad[7] = 512;  // zero K-pad
  int tot = 0;
  for (int i = 0; i < 8; ++i) {
    td.gw[i] = (td.CcPad[i] + 31) / 32;
    int gh = (td.RrPad[i] + 31) / 32;
    td.start[i] = tot;
    tot += td.gw[i] * gh;
  }
  td.start[8] = tot;

  transpose8_kernel<<<tot, dim3(32, 8), 0, stream>>>(td);
  rmsnorm1_dt_kernel<<<BSn, 256, 0, stream>>>(x, n1w, mask, Wdt, dtb, Alog, xnb, dt, la);
  gemm_kernel<<<dim3(16, 48), 256, 0, stream>>>(xnb, WallT, P, BSn, PSTR, Dn);
  chunk_intra_kernel<<<Bn * NCH * Hn, 256, 0, stream>>>(P, dt, la, ys, Sbuf, ecL, ec);
  chunk_state_kernel<<<Bn * Hn * 32, 256, 0, stream>>>(Sbuf, ecL, Hp);
  inter_gate_kernel<<<Bn * NCH * Hn, 256, 0, stream>>>(P, Hp, ec, ys, Dsk, y2b);
  gemm64_ep_kernel<1><<<dim3(32, 8), 256, 0, stream>>>(y2b, WoutT, x, mask, xres, BSn, Dn, DINn);
  rmsnorm2_kernel<<<BSn, 256, 0, stream>>>(xres, n2w, xnb);
  gemm_kernel<<<dim3(16, 22), 256, 0, stream>>>(xnb, w13T, Hf, BSn, FSTR, Dn);
  ffngate_kernel<<<BSn, 192, 0, stream>>>(Hf, gatedb);
  gemm64_ep_kernel<2><<<dim3(32, 8), 256, 0, stream>>>(gatedb, w2T, xres, mask, (float*)d_out, BSn, Dn, KP2);
}

// Round 11
// 227.437 us; speedup vs baseline: 2.7528x; 1.0089x over previous
//
#include <hip/hip_runtime.h>
#include <hip/hip_bf16.h>
#include <math.h>

#define Bn 4
#define Sn 512
#define Dn 512
#define DINn 1024
#define Hn 16
#define Pn 64
#define RNn 128
#define DFFn 1368
#define KP2 1408      // w2 K padded to BK=64 multiple
#define BSn (Bn*Sn)
#define CH 64
#define NCH (Sn/CH)   // 8
#define PSTR 6144     // fused proj row stride: [z(1024) | u(1024) | B(2048) | C(2048)]
#define FSTR 2736     // fused ffn row stride: [h1(1368) | h3(1368)]
#define FPAD 2752     // w13T padded rows (zero rows 2736..2751)

typedef __attribute__((ext_vector_type(8))) short short8;
typedef __attribute__((ext_vector_type(4))) float f32x4;

static __device__ __forceinline__ float bf2f(__hip_bfloat16 v){return __bfloat162float(v);}
static __device__ __forceinline__ __hip_bfloat16 f2bf(float v){return __float2bfloat16(v);}
static __device__ __forceinline__ short f2bfs(float v){ __hip_bfloat16 b=f2bf(v); short s; __builtin_memcpy(&s,&b,2); return s; }
static __device__ __forceinline__ float bfs2f(short s){ __hip_bfloat16 b; __builtin_memcpy(&b,&s,2); return bf2f(b); }

// ---------------- fused 8-way transpose+cast: f32 [Rr x Cc] -> bf16 [CcPad x RrPad] ----------------
// float LDS tile: 33-float stride == 1 mod 32 -> conflict-free both phases (bf16 tile was NOT).
struct T8 {
  const float* src[8];
  __hip_bfloat16* dst[8];
  int Rr[8], Cc[8], RrPad[8], CcPad[8], gw[8];
  int start[9];
};

__global__ void transpose8_kernel(T8 d) {
  int bid = blockIdx.x;
  int i = 0;
#pragma unroll
  for (int k = 1; k < 8; ++k) if (bid >= d.start[k]) i = k;
  int rel = bid - d.start[i];
  int gx = rel % d.gw[i], gy = rel / d.gw[i];
  const float* __restrict__ in = d.src[i];
  __hip_bfloat16* __restrict__ out = d.dst[i];
  int Rr = d.Rr[i], Cc = d.Cc[i], RrPad = d.RrPad[i], CcPad = d.CcPad[i];
  __shared__ float tile[32][33];
  int c0 = gx * 32, r0 = gy * 32;
  int tx = threadIdx.x, ty = threadIdx.y;
  for (int k = ty; k < 32; k += 8) {
    int r = r0 + k, cc = c0 + tx;
    tile[k][tx] = (r < Rr && cc < Cc) ? in[(size_t)r * Cc + cc] : 0.f;
  }
  __syncthreads();
  for (int k = ty; k < 32; k += 8) {
    int r = c0 + k, cc = r0 + tx;
    if (r < CcPad && cc < RrPad) out[(size_t)r * RrPad + cc] = f2bf(tile[tx][k]);
  }
}

// ---------------- rmsnorm1 * mask -> bf16, fused dt/la ----------------
__global__ void rmsnorm1_dt_kernel(const float* __restrict__ x,
                                   const float* __restrict__ w,
                                   const float* __restrict__ mask,
                                   const float* __restrict__ Wdt,
                                   const float* __restrict__ dtb,
                                   const float* __restrict__ Alog,
                                   __hip_bfloat16* __restrict__ outb,
                                   float* __restrict__ dt, float* __restrict__ la) {
  __shared__ float xs[Dn];
  __shared__ float red[4];
  int row = blockIdx.x, t = threadIdx.x;
  const float* xr = x + (size_t)row * Dn;
  float v0 = xr[t], v1 = xr[t + 256];
  float ss = v0 * v0 + v1 * v1;
#pragma unroll
  for (int o = 32; o > 0; o >>= 1) ss += __shfl_down(ss, o);
  if ((t & 63) == 0) red[t >> 6] = ss;
  __syncthreads();
  float tot = red[0] + red[1] + red[2] + red[3];
  float sc = rsqrtf(tot * (1.f / Dn) + 1e-6f) * mask[row];
  float o0 = v0 * sc * w[t], o1v = v1 * sc * w[t + 256];
  outb[(size_t)row * Dn + t] = f2bf(o0);
  outb[(size_t)row * Dn + t + 256] = f2bf(o1v);
  xs[t] = o0;
  xs[t + 256] = o1v;
  __syncthreads();
  int h = t >> 4, j = t & 15;
  float s = 0.f;
  for (int k = j * 32; k < j * 32 + 32; ++k) s = fmaf(xs[k], Wdt[k * Hn + h], s);
#pragma unroll
  for (int o = 8; o > 0; o >>= 1) s += __shfl_down(s, o, 16);
  if (j == 0) {
    float v = s + dtb[h];
    float sp = (v > 20.f) ? v : log1pf(expf(v));
    float Ah = expf(Alog[h]);
    dt[(size_t)row * Hn + h] = sp;
    la[(size_t)row * Hn + h] = -Ah * sp;
  }
}

// ---------------- rmsnorm (f32 in, no mask) -> bf16 ----------------
__global__ void rmsnorm2_kernel(const float* __restrict__ x,
                                const float* __restrict__ w,
                                __hip_bfloat16* __restrict__ out) {
  int row = blockIdx.x, t = threadIdx.x;
  const float* xr = x + (size_t)row * Dn;
  float v0 = xr[t], v1 = xr[t + 256];
  float ss = v0 * v0 + v1 * v1;
#pragma unroll
  for (int o = 32; o > 0; o >>= 1) ss += __shfl_down(ss, o);
  __shared__ float red[4];
  if ((t & 63) == 0) red[t >> 6] = ss;
  __syncthreads();
  float tot = red[0] + red[1] + red[2] + red[3];
  float sc = rsqrtf(tot * (1.f / Dn) + 1e-6f);
  out[(size_t)row * Dn + t] = f2bf(v0 * sc * w[t]);
  out[(size_t)row * Dn + t + 256] = f2bf(v1 * sc * w[t + 256]);
}

// ---------------- GEMM 128x128: single-buffer LDS + scalar register prefetch ----------------
__global__ __launch_bounds__(256) void gemm_kernel(
    const __hip_bfloat16* __restrict__ A, const __hip_bfloat16* __restrict__ BT,
    __hip_bfloat16* __restrict__ C, int M, int N, int K) {
  __shared__ short As[128][40];
  __shared__ short Bs[128][40];
  int m0 = blockIdx.x * 128, n0 = blockIdx.y * 128;
  int t = threadIdx.x;
  int lane = t & 63, wv = t >> 6;
  int wm = (wv & 1) * 64, wn = (wv >> 1) * 64;
  f32x4 acc[4][4];
#pragma unroll
  for (int i = 0; i < 4; ++i)
#pragma unroll
    for (int j = 0; j < 4; ++j) acc[i][j] = (f32x4){0.f, 0.f, 0.f, 0.f};
  const short* Ag = (const short*)A;
  const short* Bg = (const short*)BT;
  int sr = t >> 2;
  int sc = (t & 3) * 8;
  int rb0 = n0 + sr, rb1 = n0 + sr + 64;
  bool bv0 = rb0 < N, bv1 = rb1 < N;
  const short* Ap0 = Ag + (size_t)(m0 + sr) * K + sc;
  const short* Ap1 = Ag + (size_t)(m0 + sr + 64) * K + sc;
  const short* Bp0 = Bg + (size_t)rb0 * K + sc;
  const short* Bp1 = Bg + (size_t)rb1 * K + sc;
  int kTiles = (K + 31) >> 5;
  short8 a0 = 0, a1 = 0, b0 = 0, b1 = 0;
  auto loadt = [&](int k0) {
    a0 = *(const short8*)(Ap0 + k0);
    a1 = *(const short8*)(Ap1 + k0);
    b0 = bv0 ? *(const short8*)(Bp0 + k0) : (short8)0;
    b1 = bv1 ? *(const short8*)(Bp1 + k0) : (short8)0;
  };
  loadt(0);
  int fr = lane & 15, fq = (lane >> 4) * 8;
  for (int kt = 0; kt < kTiles; ++kt) {
    __syncthreads();
    *(short8*)&As[sr][sc] = a0;
    *(short8*)&As[sr + 64][sc] = a1;
    *(short8*)&Bs[sr][sc] = b0;
    *(short8*)&Bs[sr + 64][sc] = b1;
    __syncthreads();
    if (kt + 1 < kTiles) loadt((kt + 1) << 5);   // prefetch; overlaps MFMA
    short8 af[4], bfr[4];
#pragma unroll
    for (int i = 0; i < 4; ++i) af[i] = *(const short8*)&As[wm + i * 16 + fr][fq];
#pragma unroll
    for (int i = 0; i < 4; ++i) bfr[i] = *(const short8*)&Bs[wn + i * 16 + fr][fq];
#pragma unroll
    for (int mi = 0; mi < 4; ++mi)
#pragma unroll
      for (int ni = 0; ni < 4; ++ni)
        acc[mi][ni] = __builtin_amdgcn_mfma_f32_16x16x32_bf16(af[mi], bfr[ni], acc[mi][ni], 0, 0, 0);
  }
  int fq4 = (lane >> 4) * 4;
#pragma unroll
  for (int mi = 0; mi < 4; ++mi)
#pragma unroll
    for (int ni = 0; ni < 4; ++ni) {
      int col = n0 + wn + ni * 16 + fr;
      if (col < N) {
        int rowb = m0 + wm + mi * 16 + fq4;
#pragma unroll
        for (int r = 0; r < 4; ++r)
          C[(size_t)(rowb + r) * N + col] = f2bf(acc[mi][ni][r]);
      }
    }
}

// ---------------- GEMM 64x64, BK=64, single-buffer + scalar prefetch, fused f32 epilogue ----------------
// MODE 1: out = aux + acc*mask[row]; MODE 2: out = (aux + acc)*mask[row]. N exact (512). K%64==0.
template <int MODE>
__global__ __launch_bounds__(256) void gemm64_ep_kernel(
    const __hip_bfloat16* __restrict__ A, const __hip_bfloat16* __restrict__ BT,
    const float* __restrict__ aux, const float* __restrict__ mask,
    float* __restrict__ out, int M, int N, int K) {
  __shared__ short As[64][72];
  __shared__ short Bs[64][72];
  int m0 = blockIdx.x * 64, n0 = blockIdx.y * 64;
  int t = threadIdx.x;
  int lane = t & 63, wv = t >> 6;
  int wm = (wv & 1) * 32, wn = (wv >> 1) * 32;
  f32x4 acc[2][2];
#pragma unroll
  for (int i = 0; i < 2; ++i)
#pragma unroll
    for (int j = 0; j < 2; ++j) acc[i][j] = (f32x4){0.f, 0.f, 0.f, 0.f};
  const short* Ag = (const short*)A;
  const short* Bg = (const short*)BT;
  int sr = t >> 2;
  int sc = (t & 3) * 16;
  const short* Ap = Ag + (size_t)(m0 + sr) * K + sc;
  const short* Bp = Bg + (size_t)(n0 + sr) * K + sc;
  short8 a0 = 0, a1 = 0, b0 = 0, b1 = 0;
  auto loadt = [&](int k0) {
    a0 = *(const short8*)(Ap + k0);
    a1 = *(const short8*)(Ap + k0 + 8);
    b0 = *(const short8*)(Bp + k0);
    b1 = *(const short8*)(Bp + k0 + 8);
  };
  loadt(0);
  int fr = lane & 15, fq = (lane >> 4) * 8;
  int kTiles = K >> 6;
  for (int kt = 0; kt < kTiles; ++kt) {
    __syncthreads();
    *(short8*)&As[sr][sc] = a0;
    *(short8*)&As[sr][sc + 8] = a1;
    *(short8*)&Bs[sr][sc] = b0;
    *(short8*)&Bs[sr][sc + 8] = b1;
    __syncthreads();
    if (kt + 1 < kTiles) loadt((kt + 1) << 6);
#pragma unroll
    for (int kk = 0; kk < 2; ++kk) {
      short8 af[2], bfr[2];
#pragma unroll
      for (int i = 0; i < 2; ++i) af[i] = *(const short8*)&As[wm + i * 16 + fr][kk * 32 + fq];
#pragma unroll
      for (int i = 0; i < 2; ++i) bfr[i] = *(const short8*)&Bs[wn + i * 16 + fr][kk * 32 + fq];
#pragma unroll
      for (int mi = 0; mi < 2; ++mi)
#pragma unroll
        for (int ni = 0; ni < 2; ++ni)
          acc[mi][ni] = __builtin_amdgcn_mfma_f32_16x16x32_bf16(af[mi], bfr[ni], acc[mi][ni], 0, 0, 0);
    }
  }
  int fq4 = (lane >> 4) * 4;
#pragma unroll
  for (int mi = 0; mi < 2; ++mi)
#pragma unroll
    for (int ni = 0; ni < 2; ++ni) {
      int col = n0 + wn + ni * 16 + fr;
#pragma unroll
      for (int r = 0; r < 4; ++r) {
        int row = m0 + wm + mi * 16 + fq4 + r;
        float m = mask[row];
        size_t a = (size_t)row * N + col;
        float v = acc[mi][ni][r];
        if (MODE == 1) out[a] = aux[a] + v * m;
        else           out[a] = (aux[a] + v) * m;
      }
    }
}

// ---------------- GEMM 64x64, BK=64, bf16 out with ldc/Nstore (for FFN: high block count) ----------------
__global__ __launch_bounds__(256) void gemm64n_kernel(
    const __hip_bfloat16* __restrict__ A, const __hip_bfloat16* __restrict__ BT,
    __hip_bfloat16* __restrict__ C, int M, int K, int ldc, int Nstore) {
  __shared__ short As[64][72];
  __shared__ short Bs[64][72];
  int m0 = blockIdx.x * 64, n0 = blockIdx.y * 64;
  int t = threadIdx.x;
  int lane = t & 63, wv = t >> 6;
  int wm = (wv & 1) * 32, wn = (wv >> 1) * 32;
  f32x4 acc[2][2];
#pragma unroll
  for (int i = 0; i < 2; ++i)
#pragma unroll
    for (int j = 0; j < 2; ++j) acc[i][j] = (f32x4){0.f, 0.f, 0.f, 0.f};
  const short* Ag = (const short*)A;
  const short* Bg = (const short*)BT;
  int sr = t >> 2;
  int sc = (t & 3) * 16;
  const short* Ap = Ag + (size_t)(m0 + sr) * K + sc;
  const short* Bp = Bg + (size_t)(n0 + sr) * K + sc;
  short8 a0 = 0, a1 = 0, b0 = 0, b1 = 0;
  auto loadt = [&](int k0) {
    a0 = *(const short8*)(Ap + k0);
    a1 = *(const short8*)(Ap + k0 + 8);
    b0 = *(const short8*)(Bp + k0);
    b1 = *(const short8*)(Bp + k0 + 8);
  };
  loadt(0);
  int fr = lane & 15, fq = (lane >> 4) * 8;
  int kTiles = K >> 6;
  for (int kt = 0; kt < kTiles; ++kt) {
    __syncthreads();
    *(short8*)&As[sr][sc] = a0;
    *(short8*)&As[sr][sc + 8] = a1;
    *(short8*)&Bs[sr][sc] = b0;
    *(short8*)&Bs[sr][sc + 8] = b1;
    __syncthreads();
    if (kt + 1 < kTiles) loadt((kt + 1) << 6);
#pragma unroll
    for (int kk = 0; kk < 2; ++kk) {
      short8 af[2], bfr[2];
#pragma unroll
      for (int i = 0; i < 2; ++i) af[i] = *(const short8*)&As[wm + i * 16 + fr][kk * 32 + fq];
#pragma unroll
      for (int i = 0; i < 2; ++i) bfr[i] = *(const short8*)&Bs[wn + i * 16 + fr][kk * 32 + fq];
#pragma unroll
      for (int mi = 0; mi < 2; ++mi)
#pragma unroll
        for (int ni = 0; ni < 2; ++ni)
          acc[mi][ni] = __builtin_amdgcn_mfma_f32_16x16x32_bf16(af[mi], bfr[ni], acc[mi][ni], 0, 0, 0);
    }
  }
  int fq4 = (lane >> 4) * 4;
#pragma unroll
  for (int mi = 0; mi < 2; ++mi)
#pragma unroll
    for (int ni = 0; ni < 2; ++ni) {
      int col = n0 + wn + ni * 16 + fr;
      if (col < Nstore) {
        int row = m0 + wm + mi * 16 + fq4;
#pragma unroll
        for (int r = 0; r < 4; ++r)
          C[(size_t)(row + r) * ldc + col] = f2bf(acc[mi][ni][r]);
      }
    }
}

// ---------------- gated = silu(h1)*h3 from fused Hf -> bf16, K-padded stride KP2 ----------------
__global__ void ffngate_kernel(const __hip_bfloat16* __restrict__ Hf,
                               __hip_bfloat16* __restrict__ g) {
  int row = blockIdx.x;
  int c8 = threadIdx.x;
  if (c8 >= KP2 / 8) return;
  int c = c8 * 8;
  short* grow = (short*)g + (size_t)row * KP2;
  if (c >= DFFn) {                       // zero the K-pad
    *(short8*)(grow + c) = (short8)0;
    return;
  }
  const short* hrow = (const short*)Hf + (size_t)row * FSTR;
  short8 a = *(const short8*)(hrow + c);
  short8 b3 = *(const short8*)(hrow + DFFn + c);
  short8 o;
#pragma unroll
  for (int j = 0; j < 8; ++j) {
    float v = bfs2f(a[j]);
    float sil = v / (1.f + __expf(-v));
    o[j] = f2bfs(sil * bfs2f(b3[j]));
  }
  *(short8*)(grow + c) = o;
}

// ---------------- chunked scan: intra-chunk + chunk-state ----------------
__global__ __launch_bounds__(256) void chunk_intra_kernel(
    const __hip_bfloat16* __restrict__ P, const float* __restrict__ dt,
    const float* __restrict__ la, float* __restrict__ ys,
    float* __restrict__ Sbuf, float* __restrict__ ecL, float* __restrict__ ec) {
  int id = blockIdx.x;
  int h = id & 15, c = (id >> 4) & 7, b = id >> 7;
  int t = threadIdx.x, lane = t & 63, wv = t >> 6;
  __shared__ __align__(16) char smem[55040];
  short* sCB = (short*)smem;             // sC [64][136] (phase<=3a), sBt [128][72] (phase>=3b)
  short* sB  = (short*)(smem + 18432);   // [64][136]
  short* sUD = (short*)(smem + 35840);   // [64 p][72]  (s-minor)
  short* sG  = (short*)(smem + 45056);   // [64 t][72]  (s-minor)
  float* scum = (float*)(smem + 54272);  // [64]
  float* sws  = scum + 64;
  float* sdt  = sws + 64;
  int row0 = b * Sn + c * CH;
  const short* Pb = (const short*)P;
#pragma unroll
  for (int i = 0; i < 4; ++i) {
    int idx = t + i * 256;
    int r = idx >> 4, kk = (idx & 15) * 8;
    *(short8*)&sCB[r * 136 + kk] = *(const short8*)(Pb + (size_t)(row0 + r) * PSTR + 4096 + h * 128 + kk);
    *(short8*)&sB [r * 136 + kk] = *(const short8*)(Pb + (size_t)(row0 + r) * PSTR + 2048 + h * 128 + kk);
  }
  if (t < 64) { sdt[t] = dt[(size_t)(row0 + t) * Hn + h]; scum[t] = la[(size_t)(row0 + t) * Hn + h]; }
  __syncthreads();
  if (wv == 0) {
    float v = scum[lane];
#pragma unroll
    for (int o = 1; o < 64; o <<= 1) { float n = __shfl_up(v, o); if (lane >= o) v += n; }
    scum[lane] = v;
    float c63 = __shfl(v, 63);
    sws[lane] = __expf(c63 - v);
    ec[((size_t)((b * NCH + c) * Hn + h)) * 64 + lane] = __expf(v);
    if (lane == 0) ecL[(b * NCH + c) * Hn + h] = __expf(c63);
  }
#pragma unroll
  for (int i = 0; i < 2; ++i) {
    int idx = t + i * 256;
    int s = idx >> 3, pc = (idx & 7) * 8;
    short8 uv = *(const short8*)(Pb + (size_t)(row0 + s) * PSTR + 1024 + h * 64 + pc);
    float dv = sdt[s];
#pragma unroll
    for (int j = 0; j < 8; ++j) sUD[(pc + j) * 72 + s] = f2bfs(bfs2f(uv[j]) * dv);
  }
  __syncthreads();
  int fr = lane & 15, fq = (lane >> 4) * 8, q4 = (lane >> 4) * 4;
  {
    short8 af[4];
#pragma unroll
    for (int k = 0; k < 4; ++k) af[k] = *(short8*)&sCB[(16 * wv + fr) * 136 + k * 32 + fq];
#pragma unroll
    for (int j = 0; j < 4; ++j) {
      f32x4 acc = (f32x4){0.f, 0.f, 0.f, 0.f};
#pragma unroll
      for (int k = 0; k < 4; ++k) {
        short8 bf = *(short8*)&sB[(16 * j + fr) * 136 + k * 32 + fq];
        acc = __builtin_amdgcn_mfma_f32_16x16x32_bf16(af[k], bf, acc, 0, 0, 0);
      }
      int ss = 16 * j + fr;
      float cs = scum[ss];
#pragma unroll
      for (int r = 0; r < 4; ++r) {
        int tt = 16 * wv + q4 + r;
        float w = (ss <= tt) ? __expf(scum[tt] - cs) : 0.f;
        sG[tt * 72 + ss] = f2bfs(acc[r] * w);
      }
    }
  }
  __syncthreads();
#pragma unroll
  for (int i = 0; i < 32; ++i) {
    int idx = t + i * 256;
    int rn = idx >> 6, s = idx & 63;
    sCB[rn * 72 + s] = f2bfs(bfs2f(sB[s * 136 + rn]) * sws[s]);
  }
  __syncthreads();
  {
    short8 ag[2];
#pragma unroll
    for (int k = 0; k < 2; ++k) ag[k] = *(short8*)&sG[(16 * wv + fr) * 72 + k * 32 + fq];
#pragma unroll
    for (int j = 0; j < 4; ++j) {
      f32x4 acc = (f32x4){0.f, 0.f, 0.f, 0.f};
#pragma unroll
      for (int k = 0; k < 2; ++k) {
        short8 bf = *(short8*)&sUD[(16 * j + fr) * 72 + k * 32 + fq];
        acc = __builtin_amdgcn_mfma_f32_16x16x32_bf16(ag[k], bf, acc, 0, 0, 0);
      }
#pragma unroll
      for (int r = 0; r < 4; ++r)
        ys[(size_t)(row0 + 16 * wv + q4 + r) * DINn + h * 64 + 16 * j + fr] = acc[r];
    }
  }
#pragma unroll
  for (int mt0 = 0; mt0 < 2; ++mt0) {
    int mt = wv * 2 + mt0;
    short8 ab[2];
#pragma unroll
    for (int k = 0; k < 2; ++k) ab[k] = *(short8*)&sCB[(16 * mt + fr) * 72 + k * 32 + fq];
#pragma unroll
    for (int j = 0; j < 4; ++j) {
      f32x4 acc = (f32x4){0.f, 0.f, 0.f, 0.f};
#pragma unroll
      for (int k = 0; k < 2; ++k) {
        short8 bf = *(short8*)&sUD[(16 * j + fr) * 72 + k * 32 + fq];
        acc = __builtin_amdgcn_mfma_f32_16x16x32_bf16(ab[k], bf, acc, 0, 0, 0);
      }
#pragma unroll
      for (int r = 0; r < 4; ++r)
        Sbuf[((size_t)((b * NCH + c) * Hn + h) * RNn + 16 * mt + q4 + r) * 64 + 16 * j + fr] = acc[r];
    }
  }
}

// ---------------- prefix over chunk states ----------------
__global__ void chunk_state_kernel(const float* __restrict__ Sbuf, const float* __restrict__ ecL,
                                   float* __restrict__ Hp) {
  int bh = blockIdx.x >> 5;
  int j = (blockIdx.x & 31) * 256 + threadIdx.x;
  int b = bh >> 4, h = bh & 15;
  float hp = 0.f;
#pragma unroll
  for (int c = 0; c < NCH; ++c) {
    size_t addr = ((size_t)((b * NCH + c) * Hn + h)) * 8192 + j;
    Hp[addr] = hp;
    hp = ecL[(b * NCH + c) * Hn + h] * hp + Sbuf[addr];
  }
}

// ---------------- inter-chunk + gate fused ----------------
__global__ __launch_bounds__(256) void inter_gate_kernel(
    const __hip_bfloat16* __restrict__ P, const float* __restrict__ Hp,
    const float* __restrict__ ec, const float* __restrict__ ys,
    const float* __restrict__ Dsk, __hip_bfloat16* __restrict__ y2b) {
  int id = blockIdx.x;
  int h = id & 15, c = (id >> 4) & 7, b = id >> 7;
  int t = threadIdx.x, lane = t & 63, wv = t >> 6;
  __shared__ __align__(16) short sC[64 * 136];
  __shared__ __align__(16) short sHt[64 * 136];      // [p][rn]
  __shared__ __align__(16) short sz[64 * 64];
  __shared__ __align__(16) short su[64 * 64];
  __shared__ float sec[64];
  int row0 = b * Sn + c * CH;
  const short* Pb = (const short*)P;
#pragma unroll
  for (int i = 0; i < 2; ++i) {
    int idx = t + i * 256;
    int r = idx >> 3, pc = (idx & 7) * 8;
    *(short8*)&sz[r * 64 + pc] = *(const short8*)(Pb + (size_t)(row0 + r) * PSTR + h * 64 + pc);
    *(short8*)&su[r * 64 + pc] = *(const short8*)(Pb + (size_t)(row0 + r) * PSTR + 1024 + h * 64 + pc);
  }
  if (c > 0) {
    size_t hbase = ((size_t)((b * NCH + c) * Hn + h)) * 8192;
#pragma unroll
    for (int i = 0; i < 4; ++i) {
      int idx = t + i * 256;
      int r = idx >> 4, kk = (idx & 15) * 8;
      *(short8*)&sC[r * 136 + kk] = *(const short8*)(Pb + (size_t)(row0 + r) * PSTR + 4096 + h * 128 + kk);
    }
#pragma unroll
    for (int i = 0; i < 32; ++i) {
      int idx = t + i * 256;
      int rn = idx >> 6, p = idx & 63;
      sHt[p * 136 + rn] = f2bfs(Hp[hbase + idx]);
    }
    if (t < 64) sec[t] = ec[((size_t)((b * NCH + c) * Hn + h)) * 64 + t];
  }
  __syncthreads();
  int fr = lane & 15, fq = (lane >> 4) * 8, q4 = (lane >> 4) * 4;
  f32x4 acc[4];
#pragma unroll
  for (int j = 0; j < 4; ++j) acc[j] = (f32x4){0.f, 0.f, 0.f, 0.f};
  if (c > 0) {
    short8 af[4];
#pragma unroll
    for (int k = 0; k < 4; ++k) af[k] = *(short8*)&sC[(16 * wv + fr) * 136 + k * 32 + fq];
#pragma unroll
    for (int j = 0; j < 4; ++j)
#pragma unroll
      for (int k = 0; k < 4; ++k) {
        short8 bf = *(short8*)&sHt[(16 * j + fr) * 136 + k * 32 + fq];
        acc[j] = __builtin_amdgcn_mfma_f32_16x16x32_bf16(af[k], bf, acc[j], 0, 0, 0);
      }
  }
  float dsk = Dsk[h];
#pragma unroll
  for (int j = 0; j < 4; ++j) {
    int col = 16 * j + fr;
#pragma unroll
    for (int r = 0; r < 4; ++r) {
      int tt = 16 * wv + q4 + r;
      size_t a = (size_t)(row0 + tt) * DINn + h * 64 + col;
      float val = ys[a];
      if (c > 0) val += sec[tt] * acc[j][r];
      float uu = bfs2f(su[tt * 64 + col]);
      float zz = bfs2f(sz[tt * 64 + col]);
      float sil = zz / (1.f + __expf(-zz));
      y2b[a] = f2bf((val + uu * dsk) * sil);
    }
  }
}

extern "C" void kernel_launch(void* const* d_in, const int* in_sizes, int n_in,
                              void* d_out, int out_size, void* d_ws, size_t ws_size,
                              hipStream_t stream) {
  const float* x    = (const float*)d_in[0];
  const float* mask = (const float*)d_in[1];
  const float* n1w  = (const float*)d_in[2];
  const float* n2w  = (const float*)d_in[3];
  const float* Wz   = (const float*)d_in[4];
  const float* Wx   = (const float*)d_in[5];
  const float* Wb   = (const float*)d_in[6];
  const float* Wc   = (const float*)d_in[7];
  const float* Wdt  = (const float*)d_in[8];
  const float* dtb  = (const float*)d_in[9];
  const float* Alog = (const float*)d_in[10];
  const float* Dsk  = (const float*)d_in[11];
  const float* Wout = (const float*)d_in[12];
  const float* w1   = (const float*)d_in[13];
  const float* w2   = (const float*)d_in[14];
  const float* w3   = (const float*)d_in[15];

  char* ws = (char*)d_ws;
  size_t off = 0;
  auto alloc = [&](size_t bytes) {
    char* p = ws + off;
    off += (bytes + 255) & ~(size_t)255;
    return p;
  };
  __hip_bfloat16* xnb = (__hip_bfloat16*)alloc((size_t)BSn * Dn * 2);
  __hip_bfloat16* P = (__hip_bfloat16*)alloc((size_t)BSn * PSTR * 2);
  float* dt  = (float*)alloc((size_t)BSn * Hn * 4);
  float* la  = (float*)alloc((size_t)BSn * Hn * 4);
  float* ys  = (float*)alloc((size_t)BSn * DINn * 4);
  float* ecL = (float*)alloc((size_t)Bn * NCH * Hn * 4);
  float* ec  = (float*)alloc((size_t)Bn * NCH * Hn * 64 * 4);
  __hip_bfloat16* WallT = (__hip_bfloat16*)alloc((size_t)PSTR * Dn * 2);   // [z|u|B|C]^T
  __hip_bfloat16* WoutT = (__hip_bfloat16*)alloc((size_t)Dn * DINn * 2);
  __hip_bfloat16* w13T  = (__hip_bfloat16*)alloc((size_t)FPAD * Dn * 2);   // [w1|w3|zeros]^T, 2752 rows
  __hip_bfloat16* w2T   = (__hip_bfloat16*)alloc((size_t)Dn * KP2 * 2);    // K-pad 1408 (BK=64)
  // overlaid arena:
  //   Sbuf   [0, 16.78M)       live: chunk_intra -> chunk_state
  //   Hp     [16.78M, 33.55M)  live: chunk_state -> inter_gate
  //   y2b    [0, 4.2M)         live: inter_gate -> gemm64<1>   (over dead Sbuf)
  //   xres   [8.39M, 12.58M)   live: gemm64<1> -> gemm64<2>    (over dead Sbuf)
  //   Hf     [16.78M, 27.99M)  live: ffn gemm -> ffngate       (over dead Hp)
  //   gated  [27.99M, 33.76M)  live: ffngate -> gemm64<2>
  char* arena = alloc(34000000);
  float* Sbuf = (float*)arena;
  float* Hp   = (float*)(arena + 16777216);
  __hip_bfloat16* y2b = (__hip_bfloat16*)arena;
  float* xres = (float*)(arena + 8388608);
  __hip_bfloat16* Hf = (__hip_bfloat16*)(arena + 16777216);
  __hip_bfloat16* gatedb = (__hip_bfloat16*)(arena + 27984128);

  // -------- transpose job table (single dispatch) --------
  T8 td;
  td.src[0] = Wz;   td.dst[0] = WallT;                      td.Rr[0] = 512;  td.Cc[0] = 1024; td.RrPad[0] = 512;  td.CcPad[0] = 1024;
  td.src[1] = Wx;   td.dst[1] = WallT + (size_t)1024 * 512; td.Rr[1] = 512;  td.Cc[1] = 1024; td.RrPad[1] = 512;  td.CcPad[1] = 1024;
  td.src[2] = Wb;   td.dst[2] = WallT + (size_t)2048 * 512; td.Rr[2] = 512;  td.Cc[2] = 2048; td.RrPad[2] = 512;  td.CcPad[2] = 2048;
  td.src[3] = Wc;   td.dst[3] = WallT + (size_t)4096 * 512; td.Rr[3] = 512;  td.Cc[3] = 2048; td.RrPad[3] = 512;  td.CcPad[3] = 2048;
  td.src[4] = Wout; td.dst[4] = WoutT;                      td.Rr[4] = 1024; td.Cc[4] = 512;  td.RrPad[4] = 1024; td.CcPad[4] = 512;
  td.src[5] = w1;   td.dst[5] = w13T;                       td.Rr[5] = 512;  td.Cc[5] = 1368; td.RrPad[5] = 512;  td.CcPad[5] = 1368;
  td.src[6] = w3;   td.dst[6] = w13T + (size_t)1368 * 512;  td.Rr[6] = 512;  td.Cc[6] = 1368; td.RrPad[6] = 512;  td.CcPad[6] = 1384; // zero rows -> 2752 total
  td.src[7] = w2;   td.dst[7] = w2T;                        td.Rr[7] = 1368; td.Cc[7] = 512;  td.RrPad[7] = KP2;  td.CcPad[7] = 512;  // zero K-pad
  int tot = 0;
  for (int i = 0; i < 8; ++i) {
    td.gw[i] = (td.CcPad[i] + 31) / 32;
    int gh = (td.RrPad[i] + 31) / 32;
    td.start[i] = tot;
    tot += td.gw[i] * gh;
  }
  td.start[8] = tot;

  transpose8_kernel<<<tot, dim3(32, 8), 0, stream>>>(td);
  rmsnorm1_dt_kernel<<<BSn, 256, 0, stream>>>(x, n1w, mask, Wdt, dtb, Alog, xnb, dt, la);
  gemm_kernel<<<dim3(16, 48), 256, 0, stream>>>(xnb, WallT, P, BSn, PSTR, Dn);
  chunk_intra_kernel<<<Bn * NCH * Hn, 256, 0, stream>>>(P, dt, la, ys, Sbuf, ecL, ec);
  chunk_state_kernel<<<Bn * Hn * 32, 256, 0, stream>>>(Sbuf, ecL, Hp);
  inter_gate_kernel<<<Bn * NCH * Hn, 256, 0, stream>>>(P, Hp, ec, ys, Dsk, y2b);
  gemm64_ep_kernel<1><<<dim3(32, 8), 256, 0, stream>>>(y2b, WoutT, x, mask, xres, BSn, Dn, DINn);
  rmsnorm2_kernel<<<BSn, 256, 0, stream>>>(xres, n2w, xnb);
  gemm64n_kernel<<<dim3(32, 43), 256, 0, stream>>>(xnb, w13T, Hf, BSn, Dn, FSTR, FSTR);
  ffngate_kernel<<<BSn, 192, 0, stream>>>(Hf, gatedb);
  gemm64_ep_kernel<2><<<dim3(32, 8), 256, 0, stream>>>(gatedb, w2T, xres, mask, (float*)d_out, BSn, Dn, KP2);
}

// Round 12
// 222.993 us; speedup vs baseline: 2.8076x; 1.0199x over previous
//
#include <hip/hip_runtime.h>
#include <hip/hip_bf16.h>
#include <math.h>

#define Bn 4
#define Sn 512
#define Dn 512
#define DINn 1024
#define Hn 16
#define Pn 64
#define RNn 128
#define DFFn 1368
#define KP2 1408      // w2 K padded to BK=64 multiple
#define BSn (Bn*Sn)
#define CH 64
#define NCH (Sn/CH)   // 8
#define PSTR 6144     // fused proj row stride: [z(1024) | u(1024) | B(2048) | C(2048)]
#define FSTR 2736     // fused ffn row stride: [h1(1368) | h3(1368)]
#define FPAD 2752     // w13T padded rows (zero rows 2736..2751)

typedef __attribute__((ext_vector_type(8))) short short8;
typedef __attribute__((ext_vector_type(4))) float f32x4;

static __device__ __forceinline__ float bf2f(__hip_bfloat16 v){return __bfloat162float(v);}
static __device__ __forceinline__ __hip_bfloat16 f2bf(float v){return __float2bfloat16(v);}
static __device__ __forceinline__ short f2bfs(float v){ __hip_bfloat16 b=f2bf(v); short s; __builtin_memcpy(&s,&b,2); return s; }
static __device__ __forceinline__ float bfs2f(short s){ __hip_bfloat16 b; __builtin_memcpy(&b,&s,2); return bf2f(b); }

// ---------------- fused 8-way transpose+cast: f32 [Rr x Cc] -> bf16 [CcPad x RrPad] ----------------
struct T8 {
  const float* src[8];
  __hip_bfloat16* dst[8];
  int Rr[8], Cc[8], RrPad[8], CcPad[8], gw[8];
  int start[9];
};

__global__ void transpose8_kernel(T8 d) {
  int bid = blockIdx.x;
  int i = 0;
#pragma unroll
  for (int k = 1; k < 8; ++k) if (bid >= d.start[k]) i = k;
  int rel = bid - d.start[i];
  int gx = rel % d.gw[i], gy = rel / d.gw[i];
  const float* __restrict__ in = d.src[i];
  __hip_bfloat16* __restrict__ out = d.dst[i];
  int Rr = d.Rr[i], Cc = d.Cc[i], RrPad = d.RrPad[i], CcPad = d.CcPad[i];
  __shared__ float tile[32][33];
  int c0 = gx * 32, r0 = gy * 32;
  int tx = threadIdx.x, ty = threadIdx.y;
  for (int k = ty; k < 32; k += 8) {
    int r = r0 + k, cc = c0 + tx;
    tile[k][tx] = (r < Rr && cc < Cc) ? in[(size_t)r * Cc + cc] : 0.f;
  }
  __syncthreads();
  for (int k = ty; k < 32; k += 8) {
    int r = c0 + k, cc = r0 + tx;
    if (r < CcPad && cc < RrPad) out[(size_t)r * RrPad + cc] = f2bf(tile[tx][k]);
  }
}

// ---------------- rmsnorm1 * mask -> bf16, fused dt/la ----------------
__global__ void rmsnorm1_dt_kernel(const float* __restrict__ x,
                                   const float* __restrict__ w,
                                   const float* __restrict__ mask,
                                   const float* __restrict__ Wdt,
                                   const float* __restrict__ dtb,
                                   const float* __restrict__ Alog,
                                   __hip_bfloat16* __restrict__ outb,
                                   float* __restrict__ dt, float* __restrict__ la) {
  __shared__ float xs[Dn];
  __shared__ float red[4];
  int row = blockIdx.x, t = threadIdx.x;
  const float* xr = x + (size_t)row * Dn;
  float v0 = xr[t], v1 = xr[t + 256];
  float ss = v0 * v0 + v1 * v1;
#pragma unroll
  for (int o = 32; o > 0; o >>= 1) ss += __shfl_down(ss, o);
  if ((t & 63) == 0) red[t >> 6] = ss;
  __syncthreads();
  float tot = red[0] + red[1] + red[2] + red[3];
  float sc = rsqrtf(tot * (1.f / Dn) + 1e-6f) * mask[row];
  float o0 = v0 * sc * w[t], o1v = v1 * sc * w[t + 256];
  outb[(size_t)row * Dn + t] = f2bf(o0);
  outb[(size_t)row * Dn + t + 256] = f2bf(o1v);
  xs[t] = o0;
  xs[t + 256] = o1v;
  __syncthreads();
  int h = t >> 4, j = t & 15;
  float s = 0.f;
  for (int k = j * 32; k < j * 32 + 32; ++k) s = fmaf(xs[k], Wdt[k * Hn + h], s);
#pragma unroll
  for (int o = 8; o > 0; o >>= 1) s += __shfl_down(s, o, 16);
  if (j == 0) {
    float v = s + dtb[h];
    float sp = (v > 20.f) ? v : log1pf(expf(v));
    float Ah = expf(Alog[h]);
    dt[(size_t)row * Hn + h] = sp;
    la[(size_t)row * Hn + h] = -Ah * sp;
  }
}

// ---------------- rmsnorm (f32 in, no mask) -> bf16 ----------------
__global__ void rmsnorm2_kernel(const float* __restrict__ x,
                                const float* __restrict__ w,
                                __hip_bfloat16* __restrict__ out) {
  int row = blockIdx.x, t = threadIdx.x;
  const float* xr = x + (size_t)row * Dn;
  float v0 = xr[t], v1 = xr[t + 256];
  float ss = v0 * v0 + v1 * v1;
#pragma unroll
  for (int o = 32; o > 0; o >>= 1) ss += __shfl_down(ss, o);
  __shared__ float red[4];
  if ((t & 63) == 0) red[t >> 6] = ss;
  __syncthreads();
  float tot = red[0] + red[1] + red[2] + red[3];
  float sc = rsqrtf(tot * (1.f / Dn) + 1e-6f);
  out[(size_t)row * Dn + t] = f2bf(v0 * sc * w[t]);
  out[(size_t)row * Dn + t + 256] = f2bf(v1 * sc * w[t + 256]);
}

// ---------------- GEMM 128x128, BK=32, TRUE double-buffer, x2-unrolled (compile-time buf idx) ----------------
__global__ __launch_bounds__(256) void gemm_kernel(
    const __hip_bfloat16* __restrict__ A, const __hip_bfloat16* __restrict__ BT,
    __hip_bfloat16* __restrict__ C, int M, int N, int K) {
  __shared__ short As[2][128][40];
  __shared__ short Bs[2][128][40];
  int m0 = blockIdx.x * 128, n0 = blockIdx.y * 128;
  int t = threadIdx.x;
  int lane = t & 63, wv = t >> 6;
  int wm = (wv & 1) * 64, wn = (wv >> 1) * 64;
  f32x4 acc[4][4];
#pragma unroll
  for (int i = 0; i < 4; ++i)
#pragma unroll
    for (int j = 0; j < 4; ++j) acc[i][j] = (f32x4){0.f, 0.f, 0.f, 0.f};
  const short* Ag = (const short*)A;
  const short* Bg = (const short*)BT;
  int sr = t >> 2;
  int sc = (t & 3) * 8;
  int rb0 = n0 + sr, rb1 = n0 + sr + 64;
  bool bv0 = rb0 < N, bv1 = rb1 < N;
  const short* Ap0 = Ag + (size_t)(m0 + sr) * K + sc;
  const short* Ap1 = Ag + (size_t)(m0 + sr + 64) * K + sc;
  const short* Bp0 = Bg + (size_t)rb0 * K + sc;
  const short* Bp1 = Bg + (size_t)rb1 * K + sc;
  int kTiles = (K + 31) >> 5;   // even (16 for K=512)
  int fr = lane & 15, fq = (lane >> 4) * 8;
  // two NAMED scalar prefetch sets (compile-time — round-8 spill was runtime-indexed arrays)
  short8 a0A = 0, a1A = 0, b0A = 0, b1A = 0;
  short8 a0B = 0, a1B = 0, b0B = 0, b1B = 0;
  auto loadA = [&](int k0) {
    a0A = *(const short8*)(Ap0 + k0);
    a1A = *(const short8*)(Ap1 + k0);
    b0A = bv0 ? *(const short8*)(Bp0 + k0) : (short8)0;
    b1A = bv1 ? *(const short8*)(Bp1 + k0) : (short8)0;
  };
  auto loadB = [&](int k0) {
    a0B = *(const short8*)(Ap0 + k0);
    a1B = *(const short8*)(Ap1 + k0);
    b0B = bv0 ? *(const short8*)(Bp0 + k0) : (short8)0;
    b1B = bv1 ? *(const short8*)(Bp1 + k0) : (short8)0;
  };
  auto storeA = [&](int buf) {
    *(short8*)&As[buf][sr][sc] = a0A;
    *(short8*)&As[buf][sr + 64][sc] = a1A;
    *(short8*)&Bs[buf][sr][sc] = b0A;
    *(short8*)&Bs[buf][sr + 64][sc] = b1A;
  };
  auto storeB = [&](int buf) {
    *(short8*)&As[buf][sr][sc] = a0B;
    *(short8*)&As[buf][sr + 64][sc] = a1B;
    *(short8*)&Bs[buf][sr][sc] = b0B;
    *(short8*)&Bs[buf][sr + 64][sc] = b1B;
  };
  auto mfma = [&](int buf) {
    short8 af[4], bfr[4];
#pragma unroll
    for (int i = 0; i < 4; ++i) af[i] = *(const short8*)&As[buf][wm + i * 16 + fr][fq];
#pragma unroll
    for (int i = 0; i < 4; ++i) bfr[i] = *(const short8*)&Bs[buf][wn + i * 16 + fr][fq];
#pragma unroll
    for (int mi = 0; mi < 4; ++mi)
#pragma unroll
      for (int ni = 0; ni < 4; ++ni)
        acc[mi][ni] = __builtin_amdgcn_mfma_f32_16x16x32_bf16(af[mi], bfr[ni], acc[mi][ni], 0, 0, 0);
  };
  // prologue: tile0 -> buf0; tile1 -> regsA
  loadA(0);
  storeA(0);
  loadA(32);
  __syncthreads();
  for (int kt = 0; kt < kTiles; kt += 2) {
    // phase even: compute buf0; stage tile kt+1 -> buf1; prefetch tile kt+2 -> regsB
    storeA(1);
    if (kt + 2 < kTiles) loadB((kt + 2) << 5);
    mfma(0);
    __syncthreads();
    // phase odd: compute buf1; stage tile kt+2 -> buf0; prefetch tile kt+3 -> regsA
    if (kt + 2 < kTiles) storeB(0);
    if (kt + 3 < kTiles) loadA((kt + 3) << 5);
    mfma(1);
    __syncthreads();
  }
  int fq4 = (lane >> 4) * 4;
#pragma unroll
  for (int mi = 0; mi < 4; ++mi)
#pragma unroll
    for (int ni = 0; ni < 4; ++ni) {
      int col = n0 + wn + ni * 16 + fr;
      if (col < N) {
        int rowb = m0 + wm + mi * 16 + fq4;
#pragma unroll
        for (int r = 0; r < 4; ++r)
          C[(size_t)(rowb + r) * N + col] = f2bf(acc[mi][ni][r]);
      }
    }
}

// ---------------- GEMM 64x64, BK=64, double-buffer x2-unrolled, fused f32 epilogue ----------------
// MODE 1: out = aux + acc*mask[row]; MODE 2: out = (aux + acc)*mask[row]. N exact (512). kTiles even.
template <int MODE>
__global__ __launch_bounds__(256) void gemm64_ep_kernel(
    const __hip_bfloat16* __restrict__ A, const __hip_bfloat16* __restrict__ BT,
    const float* __restrict__ aux, const float* __restrict__ mask,
    float* __restrict__ out, int M, int N, int K) {
  __shared__ short As[2][64][72];
  __shared__ short Bs[2][64][72];
  int m0 = blockIdx.x * 64, n0 = blockIdx.y * 64;
  int t = threadIdx.x;
  int lane = t & 63, wv = t >> 6;
  int wm = (wv & 1) * 32, wn = (wv >> 1) * 32;
  f32x4 acc[2][2];
#pragma unroll
  for (int i = 0; i < 2; ++i)
#pragma unroll
    for (int j = 0; j < 2; ++j) acc[i][j] = (f32x4){0.f, 0.f, 0.f, 0.f};
  const short* Ag = (const short*)A;
  const short* Bg = (const short*)BT;
  int sr = t >> 2;
  int sc = (t & 3) * 16;
  const short* Ap = Ag + (size_t)(m0 + sr) * K + sc;
  const short* Bp = Bg + (size_t)(n0 + sr) * K + sc;
  int fr = lane & 15, fq = (lane >> 4) * 8;
  int kTiles = K >> 6;
  short8 a0A = 0, a1A = 0, b0A = 0, b1A = 0;
  short8 a0B = 0, a1B = 0, b0B = 0, b1B = 0;
  auto loadA = [&](int k0) {
    a0A = *(const short8*)(Ap + k0);
    a1A = *(const short8*)(Ap + k0 + 8);
    b0A = *(const short8*)(Bp + k0);
    b1A = *(const short8*)(Bp + k0 + 8);
  };
  auto loadB = [&](int k0) {
    a0B = *(const short8*)(Ap + k0);
    a1B = *(const short8*)(Ap + k0 + 8);
    b0B = *(const short8*)(Bp + k0);
    b1B = *(const short8*)(Bp + k0 + 8);
  };
  auto storeA = [&](int buf) {
    *(short8*)&As[buf][sr][sc] = a0A;
    *(short8*)&As[buf][sr][sc + 8] = a1A;
    *(short8*)&Bs[buf][sr][sc] = b0A;
    *(short8*)&Bs[buf][sr][sc + 8] = b1A;
  };
  auto storeB = [&](int buf) {
    *(short8*)&As[buf][sr][sc] = a0B;
    *(short8*)&As[buf][sr][sc + 8] = a1B;
    *(short8*)&Bs[buf][sr][sc] = b0B;
    *(short8*)&Bs[buf][sr][sc + 8] = b1B;
  };
  auto mfma = [&](int buf) {
#pragma unroll
    for (int kk = 0; kk < 2; ++kk) {
      short8 af[2], bfr[2];
#pragma unroll
      for (int i = 0; i < 2; ++i) af[i] = *(const short8*)&As[buf][wm + i * 16 + fr][kk * 32 + fq];
#pragma unroll
      for (int i = 0; i < 2; ++i) bfr[i] = *(const short8*)&Bs[buf][wn + i * 16 + fr][kk * 32 + fq];
#pragma unroll
      for (int mi = 0; mi < 2; ++mi)
#pragma unroll
        for (int ni = 0; ni < 2; ++ni)
          acc[mi][ni] = __builtin_amdgcn_mfma_f32_16x16x32_bf16(af[mi], bfr[ni], acc[mi][ni], 0, 0, 0);
    }
  };
  loadA(0);
  storeA(0);
  loadA(64);
  __syncthreads();
  for (int kt = 0; kt < kTiles; kt += 2) {
    storeA(1);
    if (kt + 2 < kTiles) loadB((kt + 2) << 6);
    mfma(0);
    __syncthreads();
    if (kt + 2 < kTiles) storeB(0);
    if (kt + 3 < kTiles) loadA((kt + 3) << 6);
    mfma(1);
    __syncthreads();
  }
  int fq4 = (lane >> 4) * 4;
#pragma unroll
  for (int mi = 0; mi < 2; ++mi)
#pragma unroll
    for (int ni = 0; ni < 2; ++ni) {
      int col = n0 + wn + ni * 16 + fr;
#pragma unroll
      for (int r = 0; r < 4; ++r) {
        int row = m0 + wm + mi * 16 + fq4 + r;
        float m = mask[row];
        size_t a = (size_t)row * N + col;
        float v = acc[mi][ni][r];
        if (MODE == 1) out[a] = aux[a] + v * m;
        else           out[a] = (aux[a] + v) * m;
      }
    }
}

// ---------------- GEMM 64x64, BK=64, double-buffer, bf16 out with ldc/Nstore (FFN) ----------------
__global__ __launch_bounds__(256) void gemm64n_kernel(
    const __hip_bfloat16* __restrict__ A, const __hip_bfloat16* __restrict__ BT,
    __hip_bfloat16* __restrict__ C, int M, int K, int ldc, int Nstore) {
  __shared__ short As[2][64][72];
  __shared__ short Bs[2][64][72];
  int m0 = blockIdx.x * 64, n0 = blockIdx.y * 64;
  int t = threadIdx.x;
  int lane = t & 63, wv = t >> 6;
  int wm = (wv & 1) * 32, wn = (wv >> 1) * 32;
  f32x4 acc[2][2];
#pragma unroll
  for (int i = 0; i < 2; ++i)
#pragma unroll
    for (int j = 0; j < 2; ++j) acc[i][j] = (f32x4){0.f, 0.f, 0.f, 0.f};
  const short* Ag = (const short*)A;
  const short* Bg = (const short*)BT;
  int sr = t >> 2;
  int sc = (t & 3) * 16;
  const short* Ap = Ag + (size_t)(m0 + sr) * K + sc;
  const short* Bp = Bg + (size_t)(n0 + sr) * K + sc;
  int fr = lane & 15, fq = (lane >> 4) * 8;
  int kTiles = K >> 6;
  short8 a0A = 0, a1A = 0, b0A = 0, b1A = 0;
  short8 a0B = 0, a1B = 0, b0B = 0, b1B = 0;
  auto loadA = [&](int k0) {
    a0A = *(const short8*)(Ap + k0);
    a1A = *(const short8*)(Ap + k0 + 8);
    b0A = *(const short8*)(Bp + k0);
    b1A = *(const short8*)(Bp + k0 + 8);
  };
  auto loadB = [&](int k0) {
    a0B = *(const short8*)(Ap + k0);
    a1B = *(const short8*)(Ap + k0 + 8);
    b0B = *(const short8*)(Bp + k0);
    b1B = *(const short8*)(Bp + k0 + 8);
  };
  auto storeA = [&](int buf) {
    *(short8*)&As[buf][sr][sc] = a0A;
    *(short8*)&As[buf][sr][sc + 8] = a1A;
    *(short8*)&Bs[buf][sr][sc] = b0A;
    *(short8*)&Bs[buf][sr][sc + 8] = b1A;
  };
  auto storeB = [&](int buf) {
    *(short8*)&As[buf][sr][sc] = a0B;
    *(short8*)&As[buf][sr][sc + 8] = a1B;
    *(short8*)&Bs[buf][sr][sc] = b0B;
    *(short8*)&Bs[buf][sr][sc + 8] = b1B;
  };
  auto mfma = [&](int buf) {
#pragma unroll
    for (int kk = 0; kk < 2; ++kk) {
      short8 af[2], bfr[2];
#pragma unroll
      for (int i = 0; i < 2; ++i) af[i] = *(const short8*)&As[buf][wm + i * 16 + fr][kk * 32 + fq];
#pragma unroll
      for (int i = 0; i < 2; ++i) bfr[i] = *(const short8*)&Bs[buf][wn + i * 16 + fr][kk * 32 + fq];
#pragma unroll
      for (int mi = 0; mi < 2; ++mi)
#pragma unroll
        for (int ni = 0; ni < 2; ++ni)
          acc[mi][ni] = __builtin_amdgcn_mfma_f32_16x16x32_bf16(af[mi], bfr[ni], acc[mi][ni], 0, 0, 0);
    }
  };
  loadA(0);
  storeA(0);
  loadA(64);
  __syncthreads();
  for (int kt = 0; kt < kTiles; kt += 2) {
    storeA(1);
    if (kt + 2 < kTiles) loadB((kt + 2) << 6);
    mfma(0);
    __syncthreads();
    if (kt + 2 < kTiles) storeB(0);
    if (kt + 3 < kTiles) loadA((kt + 3) << 6);
    mfma(1);
    __syncthreads();
  }
  int fq4 = (lane >> 4) * 4;
#pragma unroll
  for (int mi = 0; mi < 2; ++mi)
#pragma unroll
    for (int ni = 0; ni < 2; ++ni) {
      int col = n0 + wn + ni * 16 + fr;
      if (col < Nstore) {
        int row = m0 + wm + mi * 16 + fq4;
#pragma unroll
        for (int r = 0; r < 4; ++r)
          C[(size_t)(row + r) * ldc + col] = f2bf(acc[mi][ni][r]);
      }
    }
}

// ---------------- gated = silu(h1)*h3 from fused Hf -> bf16, K-padded stride KP2 ----------------
__global__ void ffngate_kernel(const __hip_bfloat16* __restrict__ Hf,
                               __hip_bfloat16* __restrict__ g) {
  int row = blockIdx.x;
  int c8 = threadIdx.x;
  if (c8 >= KP2 / 8) return;
  int c = c8 * 8;
  short* grow = (short*)g + (size_t)row * KP2;
  if (c >= DFFn) {                       // zero the K-pad
    *(short8*)(grow + c) = (short8)0;
    return;
  }
  const short* hrow = (const short*)Hf + (size_t)row * FSTR;
  short8 a = *(const short8*)(hrow + c);
  short8 b3 = *(const short8*)(hrow + DFFn + c);
  short8 o;
#pragma unroll
  for (int j = 0; j < 8; ++j) {
    float v = bfs2f(a[j]);
    float sil = v / (1.f + __expf(-v));
    o[j] = f2bfs(sil * bfs2f(b3[j]));
  }
  *(short8*)(grow + c) = o;
}

// ---------------- chunked scan: intra-chunk + chunk-state ----------------
__global__ __launch_bounds__(256) void chunk_intra_kernel(
    const __hip_bfloat16* __restrict__ P, const float* __restrict__ dt,
    const float* __restrict__ la, float* __restrict__ ys,
    float* __restrict__ Sbuf, float* __restrict__ ecL, float* __restrict__ ec) {
  int id = blockIdx.x;
  int h = id & 15, c = (id >> 4) & 7, b = id >> 7;
  int t = threadIdx.x, lane = t & 63, wv = t >> 6;
  __shared__ __align__(16) char smem[55040];
  short* sCB = (short*)smem;             // sC [64][136] (phase<=3a), sBt [128][72] (phase>=3b)
  short* sB  = (short*)(smem + 18432);   // [64][136]
  short* sUD = (short*)(smem + 35840);   // [64 p][72]  (s-minor)
  short* sG  = (short*)(smem + 45056);   // [64 t][72]  (s-minor)
  float* scum = (float*)(smem + 54272);  // [64]
  float* sws  = scum + 64;
  float* sdt  = sws + 64;
  int row0 = b * Sn + c * CH;
  const short* Pb = (const short*)P;
#pragma unroll
  for (int i = 0; i < 4; ++i) {
    int idx = t + i * 256;
    int r = idx >> 4, kk = (idx & 15) * 8;
    *(short8*)&sCB[r * 136 + kk] = *(const short8*)(Pb + (size_t)(row0 + r) * PSTR + 4096 + h * 128 + kk);
    *(short8*)&sB [r * 136 + kk] = *(const short8*)(Pb + (size_t)(row0 + r) * PSTR + 2048 + h * 128 + kk);
  }
  if (t < 64) { sdt[t] = dt[(size_t)(row0 + t) * Hn + h]; scum[t] = la[(size_t)(row0 + t) * Hn + h]; }
  __syncthreads();
  if (wv == 0) {
    float v = scum[lane];
#pragma unroll
    for (int o = 1; o < 64; o <<= 1) { float n = __shfl_up(v, o); if (lane >= o) v += n; }
    scum[lane] = v;
    float c63 = __shfl(v, 63);
    sws[lane] = __expf(c63 - v);
    ec[((size_t)((b * NCH + c) * Hn + h)) * 64 + lane] = __expf(v);
    if (lane == 0) ecL[(b * NCH + c) * Hn + h] = __expf(c63);
  }
#pragma unroll
  for (int i = 0; i < 2; ++i) {
    int idx = t + i * 256;
    int s = idx >> 3, pc = (idx & 7) * 8;
    short8 uv = *(const short8*)(Pb + (size_t)(row0 + s) * PSTR + 1024 + h * 64 + pc);
    float dv = sdt[s];
#pragma unroll
    for (int j = 0; j < 8; ++j) sUD[(pc + j) * 72 + s] = f2bfs(bfs2f(uv[j]) * dv);
  }
  __syncthreads();
  int fr = lane & 15, fq = (lane >> 4) * 8, q4 = (lane >> 4) * 4;
  {
    short8 af[4];
#pragma unroll
    for (int k = 0; k < 4; ++k) af[k] = *(short8*)&sCB[(16 * wv + fr) * 136 + k * 32 + fq];
#pragma unroll
    for (int j = 0; j < 4; ++j) {
      f32x4 acc = (f32x4){0.f, 0.f, 0.f, 0.f};
#pragma unroll
      for (int k = 0; k < 4; ++k) {
        short8 bf = *(short8*)&sB[(16 * j + fr) * 136 + k * 32 + fq];
        acc = __builtin_amdgcn_mfma_f32_16x16x32_bf16(af[k], bf, acc, 0, 0, 0);
      }
      int ss = 16 * j + fr;
      float cs = scum[ss];
#pragma unroll
      for (int r = 0; r < 4; ++r) {
        int tt = 16 * wv + q4 + r;
        float w = (ss <= tt) ? __expf(scum[tt] - cs) : 0.f;
        sG[tt * 72 + ss] = f2bfs(acc[r] * w);
      }
    }
  }
  __syncthreads();
#pragma unroll
  for (int i = 0; i < 32; ++i) {
    int idx = t + i * 256;
    int rn = idx >> 6, s = idx & 63;
    sCB[rn * 72 + s] = f2bfs(bfs2f(sB[s * 136 + rn]) * sws[s]);
  }
  __syncthreads();
  {
    short8 ag[2];
#pragma unroll
    for (int k = 0; k < 2; ++k) ag[k] = *(short8*)&sG[(16 * wv + fr) * 72 + k * 32 + fq];
#pragma unroll
    for (int j = 0; j < 4; ++j) {
      f32x4 acc = (f32x4){0.f, 0.f, 0.f, 0.f};
#pragma unroll
      for (int k = 0; k < 2; ++k) {
        short8 bf = *(short8*)&sUD[(16 * j + fr) * 72 + k * 32 + fq];
        acc = __builtin_amdgcn_mfma_f32_16x16x32_bf16(ag[k], bf, acc, 0, 0, 0);
      }
#pragma unroll
      for (int r = 0; r < 4; ++r)
        ys[(size_t)(row0 + 16 * wv + q4 + r) * DINn + h * 64 + 16 * j + fr] = acc[r];
    }
  }
#pragma unroll
  for (int mt0 = 0; mt0 < 2; ++mt0) {
    int mt = wv * 2 + mt0;
    short8 ab[2];
#pragma unroll
    for (int k = 0; k < 2; ++k) ab[k] = *(short8*)&sCB[(16 * mt + fr) * 72 + k * 32 + fq];
#pragma unroll
    for (int j = 0; j < 4; ++j) {
      f32x4 acc = (f32x4){0.f, 0.f, 0.f, 0.f};
#pragma unroll
      for (int k = 0; k < 2; ++k) {
        short8 bf = *(short8*)&sUD[(16 * j + fr) * 72 + k * 32 + fq];
        acc = __builtin_amdgcn_mfma_f32_16x16x32_bf16(ab[k], bf, acc, 0, 0, 0);
      }
#pragma unroll
      for (int r = 0; r < 4; ++r)
        Sbuf[((size_t)((b * NCH + c) * Hn + h) * RNn + 16 * mt + q4 + r) * 64 + 16 * j + fr] = acc[r];
    }
  }
}

// ---------------- prefix over chunk states ----------------
__global__ void chunk_state_kernel(const float* __restrict__ Sbuf, const float* __restrict__ ecL,
                                   float* __restrict__ Hp) {
  int bh = blockIdx.x >> 5;
  int j = (blockIdx.x & 31) * 256 + threadIdx.x;
  int b = bh >> 4, h = bh & 15;
  float hp = 0.f;
#pragma unroll
  for (int c = 0; c < NCH; ++c) {
    size_t addr = ((size_t)((b * NCH + c) * Hn + h)) * 8192 + j;
    Hp[addr] = hp;
    hp = ecL[(b * NCH + c) * Hn + h] * hp + Sbuf[addr];
  }
}

// ---------------- inter-chunk + gate fused ----------------
__global__ __launch_bounds__(256) void inter_gate_kernel(
    const __hip_bfloat16* __restrict__ P, const float* __restrict__ Hp,
    const float* __restrict__ ec, const float* __restrict__ ys,
    const float* __restrict__ Dsk, __hip_bfloat16* __restrict__ y2b) {
  int id = blockIdx.x;
  int h = id & 15, c = (id >> 4) & 7, b = id >> 7;
  int t = threadIdx.x, lane = t & 63, wv = t >> 6;
  __shared__ __align__(16) short sC[64 * 136];
  __shared__ __align__(16) short sHt[64 * 136];      // [p][rn]
  __shared__ __align__(16) short sz[64 * 64];
  __shared__ __align__(16) short su[64 * 64];
  __shared__ float sec[64];
  int row0 = b * Sn + c * CH;
  const short* Pb = (const short*)P;
#pragma unroll
  for (int i = 0; i < 2; ++i) {
    int idx = t + i * 256;
    int r = idx >> 3, pc = (idx & 7) * 8;
    *(short8*)&sz[r * 64 + pc] = *(const short8*)(Pb + (size_t)(row0 + r) * PSTR + h * 64 + pc);
    *(short8*)&su[r * 64 + pc] = *(const short8*)(Pb + (size_t)(row0 + r) * PSTR + 1024 + h * 64 + pc);
  }
  if (c > 0) {
    size_t hbase = ((size_t)((b * NCH + c) * Hn + h)) * 8192;
#pragma unroll
    for (int i = 0; i < 4; ++i) {
      int idx = t + i * 256;
      int r = idx >> 4, kk = (idx & 15) * 8;
      *(short8*)&sC[r * 136 + kk] = *(const short8*)(Pb + (size_t)(row0 + r) * PSTR + 4096 + h * 128 + kk);
    }
#pragma unroll
    for (int i = 0; i < 32; ++i) {
      int idx = t + i * 256;
      int rn = idx >> 6, p = idx & 63;
      sHt[p * 136 + rn] = f2bfs(Hp[hbase + idx]);
    }
    if (t < 64) sec[t] = ec[((size_t)((b * NCH + c) * Hn + h)) * 64 + t];
  }
  __syncthreads();
  int fr = lane & 15, fq = (lane >> 4) * 8, q4 = (lane >> 4) * 4;
  f32x4 acc[4];
#pragma unroll
  for (int j = 0; j < 4; ++j) acc[j] = (f32x4){0.f, 0.f, 0.f, 0.f};
  if (c > 0) {
    short8 af[4];
#pragma unroll
    for (int k = 0; k < 4; ++k) af[k] = *(short8*)&sC[(16 * wv + fr) * 136 + k * 32 + fq];
#pragma unroll
    for (int j = 0; j < 4; ++j)
#pragma unroll
      for (int k = 0; k < 4; ++k) {
        short8 bf = *(short8*)&sHt[(16 * j + fr) * 136 + k * 32 + fq];
        acc[j] = __builtin_amdgcn_mfma_f32_16x16x32_bf16(af[k], bf, acc[j], 0, 0, 0);
      }
  }
  float dsk = Dsk[h];
#pragma unroll
  for (int j = 0; j < 4; ++j) {
    int col = 16 * j + fr;
#pragma unroll
    for (int r = 0; r < 4; ++r) {
      int tt = 16 * wv + q4 + r;
      size_t a = (size_t)(row0 + tt) * DINn + h * 64 + col;
      float val = ys[a];
      if (c > 0) val += sec[tt] * acc[j][r];
      float uu = bfs2f(su[tt * 64 + col]);
      float zz = bfs2f(sz[tt * 64 + col]);
      float sil = zz / (1.f + __expf(-zz));
      y2b[a] = f2bf((val + uu * dsk) * sil);
    }
  }
}

extern "C" void kernel_launch(void* const* d_in, const int* in_sizes, int n_in,
                              void* d_out, int out_size, void* d_ws, size_t ws_size,
                              hipStream_t stream) {
  const float* x    = (const float*)d_in[0];
  const float* mask = (const float*)d_in[1];
  const float* n1w  = (const float*)d_in[2];
  const float* n2w  = (const float*)d_in[3];
  const float* Wz   = (const float*)d_in[4];
  const float* Wx   = (const float*)d_in[5];
  const float* Wb   = (const float*)d_in[6];
  const float* Wc   = (const float*)d_in[7];
  const float* Wdt  = (const float*)d_in[8];
  const float* dtb  = (const float*)d_in[9];
  const float* Alog = (const float*)d_in[10];
  const float* Dsk  = (const float*)d_in[11];
  const float* Wout = (const float*)d_in[12];
  const float* w1   = (const float*)d_in[13];
  const float* w2   = (const float*)d_in[14];
  const float* w3   = (const float*)d_in[15];

  char* ws = (char*)d_ws;
  size_t off = 0;
  auto alloc = [&](size_t bytes) {
    char* p = ws + off;
    off += (bytes + 255) & ~(size_t)255;
    return p;
  };
  __hip_bfloat16* xnb = (__hip_bfloat16*)alloc((size_t)BSn * Dn * 2);
  __hip_bfloat16* P = (__hip_bfloat16*)alloc((size_t)BSn * PSTR * 2);
  float* dt  = (float*)alloc((size_t)BSn * Hn * 4);
  float* la  = (float*)alloc((size_t)BSn * Hn * 4);
  float* ys  = (float*)alloc((size_t)BSn * DINn * 4);
  float* ecL = (float*)alloc((size_t)Bn * NCH * Hn * 4);
  float* ec  = (float*)alloc((size_t)Bn * NCH * Hn * 64 * 4);
  __hip_bfloat16* WallT = (__hip_bfloat16*)alloc((size_t)PSTR * Dn * 2);   // [z|u|B|C]^T
  __hip_bfloat16* WoutT = (__hip_bfloat16*)alloc((size_t)Dn * DINn * 2);
  __hip_bfloat16* w13T  = (__hip_bfloat16*)alloc((size_t)FPAD * Dn * 2);   // [w1|w3|zeros]^T, 2752 rows
  __hip_bfloat16* w2T   = (__hip_bfloat16*)alloc((size_t)Dn * KP2 * 2);    // K-pad 1408 (BK=64)
  // overlaid arena (same liveness plan as round 10/11)
  char* arena = alloc(34000000);
  float* Sbuf = (float*)arena;
  float* Hp   = (float*)(arena + 16777216);
  __hip_bfloat16* y2b = (__hip_bfloat16*)arena;
  float* xres = (float*)(arena + 8388608);
  __hip_bfloat16* Hf = (__hip_bfloat16*)(arena + 16777216);
  __hip_bfloat16* gatedb = (__hip_bfloat16*)(arena + 27984128);

  // -------- transpose job table (single dispatch) --------
  T8 td;
  td.src[0] = Wz;   td.dst[0] = WallT;                      td.Rr[0] = 512;  td.Cc[0] = 1024; td.RrPad[0] = 512;  td.CcPad[0] = 1024;
  td.src[1] = Wx;   td.dst[1] = WallT + (size_t)1024 * 512; td.Rr[1] = 512;  td.Cc[1] = 1024; td.RrPad[1] = 512;  td.CcPad[1] = 1024;
  td.src[2] = Wb;   td.dst[2] = WallT + (size_t)2048 * 512; td.Rr[2] = 512;  td.Cc[2] = 2048; td.RrPad[2] = 512;  td.CcPad[2] = 2048;
  td.src[3] = Wc;   td.dst[3] = WallT + (size_t)4096 * 512; td.Rr[3] = 512;  td.Cc[3] = 2048; td.RrPad[3] = 512;  td.CcPad[3] = 2048;
  td.src[4] = Wout; td.dst[4] = WoutT;                      td.Rr[4] = 1024; td.Cc[4] = 512;  td.RrPad[4] = 1024; td.CcPad[4] = 512;
  td.src[5] = w1;   td.dst[5] = w13T;                       td.Rr[5] = 512;  td.Cc[5] = 1368; td.RrPad[5] = 512;  td.CcPad[5] = 1368;
  td.src[6] = w3;   td.dst[6] = w13T + (size_t)1368 * 512;  td.Rr[6] = 512;  td.Cc[6] = 1368; td.RrPad[6] = 512;  td.CcPad[6] = 1384; // zero rows -> 2752 total
  td.src[7] = w2;   td.dst[7] = w2T;                        td.Rr[7] = 1368; td.Cc[7] = 512;  td.RrPad[7] = KP2;  td.CcPad[7] = 512;  // zero K-pad
  int tot = 0;
  for (int i = 0; i < 8; ++i) {
    td.gw[i] = (td.CcPad[i] + 31) / 32;
    int gh = (td.RrPad[i] + 31) / 32;
    td.start[i] = tot;
    tot += td.gw[i] * gh;
  }
  td.start[8] = tot;

  transpose8_kernel<<<tot, dim3(32, 8), 0, stream>>>(td);
  rmsnorm1_dt_kernel<<<BSn, 256, 0, stream>>>(x, n1w, mask, Wdt, dtb, Alog, xnb, dt, la);
  gemm_kernel<<<dim3(16, 48), 256, 0, stream>>>(xnb, WallT, P, BSn, PSTR, Dn);
  chunk_intra_kernel<<<Bn * NCH * Hn, 256, 0, stream>>>(P, dt, la, ys, Sbuf, ecL, ec);
  chunk_state_kernel<<<Bn * Hn * 32, 256, 0, stream>>>(Sbuf, ecL, Hp);
  inter_gate_kernel<<<Bn * NCH * Hn, 256, 0, stream>>>(P, Hp, ec, ys, Dsk, y2b);
  gemm64_ep_kernel<1><<<dim3(32, 8), 256, 0, stream>>>(y2b, WoutT, x, mask, xres, BSn, Dn, DINn);
  rmsnorm2_kernel<<<BSn, 256, 0, stream>>>(xres, n2w, xnb);
  gemm64n_kernel<<<dim3(32, 43), 256, 0, stream>>>(xnb, w13T, Hf, BSn, Dn, FSTR, FSTR);
  ffngate_kernel<<<BSn, 192, 0, stream>>>(Hf, gatedb);
  gemm64_ep_kernel<2><<<dim3(32, 8), 256, 0, stream>>>(gatedb, w2T, xres, mask, (float*)d_out, BSn, Dn, KP2);
}

// Round 13
// 219.729 us; speedup vs baseline: 2.8493x; 1.0149x over previous
//
#include <hip/hip_runtime.h>
#include <hip/hip_bf16.h>
#include <math.h>

#define Bn 4
#define Sn 512
#define Dn 512
#define DINn 1024
#define Hn 16
#define Pn 64
#define RNn 128
#define DFFn 1368
#define KP2 1408      // w2 K padded to BK=64 multiple
#define BSn (Bn*Sn)
#define CH 64
#define NCH (Sn/CH)   // 8
#define PSTR 6144     // fused proj row stride: [z(1024) | u(1024) | B(2048) | C(2048)]
#define FSTR 2736     // fused ffn row stride: [h1(1368) | h3(1368)]
#define FPAD 2816     // w13T padded rows (zero rows 2736..2815)

typedef __attribute__((ext_vector_type(8))) short short8;
typedef __attribute__((ext_vector_type(4))) float f32x4;

static __device__ __forceinline__ float bf2f(__hip_bfloat16 v){return __bfloat162float(v);}
static __device__ __forceinline__ __hip_bfloat16 f2bf(float v){return __float2bfloat16(v);}
static __device__ __forceinline__ short f2bfs(float v){ __hip_bfloat16 b=f2bf(v); short s; __builtin_memcpy(&s,&b,2); return s; }
static __device__ __forceinline__ float bfs2f(short s){ __hip_bfloat16 b; __builtin_memcpy(&b,&s,2); return bf2f(b); }

// ---------------- fused 8-way transpose+cast: f32 [Rr x Cc] -> bf16 [CcPad x RrPad] ----------------
struct T8 {
  const float* src[8];
  __hip_bfloat16* dst[8];
  int Rr[8], Cc[8], RrPad[8], CcPad[8], gw[8];
  int start[9];
};

__global__ void transpose8_kernel(T8 d) {
  int bid = blockIdx.x;
  int i = 0;
#pragma unroll
  for (int k = 1; k < 8; ++k) if (bid >= d.start[k]) i = k;
  int rel = bid - d.start[i];
  int gx = rel % d.gw[i], gy = rel / d.gw[i];
  const float* __restrict__ in = d.src[i];
  __hip_bfloat16* __restrict__ out = d.dst[i];
  int Rr = d.Rr[i], Cc = d.Cc[i], RrPad = d.RrPad[i], CcPad = d.CcPad[i];
  __shared__ float tile[32][33];
  int c0 = gx * 32, r0 = gy * 32;
  int tx = threadIdx.x, ty = threadIdx.y;
  for (int k = ty; k < 32; k += 8) {
    int r = r0 + k, cc = c0 + tx;
    tile[k][tx] = (r < Rr && cc < Cc) ? in[(size_t)r * Cc + cc] : 0.f;
  }
  __syncthreads();
  for (int k = ty; k < 32; k += 8) {
    int r = c0 + k, cc = r0 + tx;
    if (r < CcPad && cc < RrPad) out[(size_t)r * RrPad + cc] = f2bf(tile[tx][k]);
  }
}

// ---------------- rmsnorm1 * mask -> bf16, fused dt/la ----------------
__global__ void rmsnorm1_dt_kernel(const float* __restrict__ x,
                                   const float* __restrict__ w,
                                   const float* __restrict__ mask,
                                   const float* __restrict__ Wdt,
                                   const float* __restrict__ dtb,
                                   const float* __restrict__ Alog,
                                   __hip_bfloat16* __restrict__ outb,
                                   float* __restrict__ dt, float* __restrict__ la) {
  __shared__ float xs[Dn];
  __shared__ float red[4];
  int row = blockIdx.x, t = threadIdx.x;
  const float* xr = x + (size_t)row * Dn;
  float v0 = xr[t], v1 = xr[t + 256];
  float ss = v0 * v0 + v1 * v1;
#pragma unroll
  for (int o = 32; o > 0; o >>= 1) ss += __shfl_down(ss, o);
  if ((t & 63) == 0) red[t >> 6] = ss;
  __syncthreads();
  float tot = red[0] + red[1] + red[2] + red[3];
  float sc = rsqrtf(tot * (1.f / Dn) + 1e-6f) * mask[row];
  float o0 = v0 * sc * w[t], o1v = v1 * sc * w[t + 256];
  outb[(size_t)row * Dn + t] = f2bf(o0);
  outb[(size_t)row * Dn + t + 256] = f2bf(o1v);
  xs[t] = o0;
  xs[t + 256] = o1v;
  __syncthreads();
  int h = t >> 4, j = t & 15;
  float s = 0.f;
  for (int k = j * 32; k < j * 32 + 32; ++k) s = fmaf(xs[k], Wdt[k * Hn + h], s);
#pragma unroll
  for (int o = 8; o > 0; o >>= 1) s += __shfl_down(s, o, 16);
  if (j == 0) {
    float v = s + dtb[h];
    float sp = (v > 20.f) ? v : log1pf(expf(v));
    float Ah = expf(Alog[h]);
    dt[(size_t)row * Hn + h] = sp;
    la[(size_t)row * Hn + h] = -Ah * sp;
  }
}

// ---------------- rmsnorm (f32 in, no mask) -> bf16 ----------------
__global__ void rmsnorm2_kernel(const float* __restrict__ x,
                                const float* __restrict__ w,
                                __hip_bfloat16* __restrict__ out) {
  int row = blockIdx.x, t = threadIdx.x;
  const float* xr = x + (size_t)row * Dn;
  float v0 = xr[t], v1 = xr[t + 256];
  float ss = v0 * v0 + v1 * v1;
#pragma unroll
  for (int o = 32; o > 0; o >>= 1) ss += __shfl_down(ss, o);
  __shared__ float red[4];
  if ((t & 63) == 0) red[t >> 6] = ss;
  __syncthreads();
  float tot = red[0] + red[1] + red[2] + red[3];
  float sc = rsqrtf(tot * (1.f / Dn) + 1e-6f);
  out[(size_t)row * Dn + t] = f2bf(v0 * sc * w[t]);
  out[(size_t)row * Dn + t + 256] = f2bf(v1 * sc * w[t + 256]);
}

// ---------------- GEMM 128x128, BK=32, TRUE double-buffer, x2-unrolled ----------------
__global__ __launch_bounds__(256) void gemm_kernel(
    const __hip_bfloat16* __restrict__ A, const __hip_bfloat16* __restrict__ BT,
    __hip_bfloat16* __restrict__ C, int M, int N, int K) {
  __shared__ short As[2][128][40];
  __shared__ short Bs[2][128][40];
  int m0 = blockIdx.x * 128, n0 = blockIdx.y * 128;
  int t = threadIdx.x;
  int lane = t & 63, wv = t >> 6;
  int wm = (wv & 1) * 64, wn = (wv >> 1) * 64;
  f32x4 acc[4][4];
#pragma unroll
  for (int i = 0; i < 4; ++i)
#pragma unroll
    for (int j = 0; j < 4; ++j) acc[i][j] = (f32x4){0.f, 0.f, 0.f, 0.f};
  const short* Ag = (const short*)A;
  const short* Bg = (const short*)BT;
  int sr = t >> 2;
  int sc = (t & 3) * 8;
  int rb0 = n0 + sr, rb1 = n0 + sr + 64;
  bool bv0 = rb0 < N, bv1 = rb1 < N;
  const short* Ap0 = Ag + (size_t)(m0 + sr) * K + sc;
  const short* Ap1 = Ag + (size_t)(m0 + sr + 64) * K + sc;
  const short* Bp0 = Bg + (size_t)rb0 * K + sc;
  const short* Bp1 = Bg + (size_t)rb1 * K + sc;
  int kTiles = (K + 31) >> 5;
  int fr = lane & 15, fq = (lane >> 4) * 8;
  short8 a0A = 0, a1A = 0, b0A = 0, b1A = 0;
  short8 a0B = 0, a1B = 0, b0B = 0, b1B = 0;
  auto loadA = [&](int k0) {
    a0A = *(const short8*)(Ap0 + k0);
    a1A = *(const short8*)(Ap1 + k0);
    b0A = bv0 ? *(const short8*)(Bp0 + k0) : (short8)0;
    b1A = bv1 ? *(const short8*)(Bp1 + k0) : (short8)0;
  };
  auto loadB = [&](int k0) {
    a0B = *(const short8*)(Ap0 + k0);
    a1B = *(const short8*)(Ap1 + k0);
    b0B = bv0 ? *(const short8*)(Bp0 + k0) : (short8)0;
    b1B = bv1 ? *(const short8*)(Bp1 + k0) : (short8)0;
  };
  auto storeA = [&](int buf) {
    *(short8*)&As[buf][sr][sc] = a0A;
    *(short8*)&As[buf][sr + 64][sc] = a1A;
    *(short8*)&Bs[buf][sr][sc] = b0A;
    *(short8*)&Bs[buf][sr + 64][sc] = b1A;
  };
  auto storeB = [&](int buf) {
    *(short8*)&As[buf][sr][sc] = a0B;
    *(short8*)&As[buf][sr + 64][sc] = a1B;
    *(short8*)&Bs[buf][sr][sc] = b0B;
    *(short8*)&Bs[buf][sr + 64][sc] = b1B;
  };
  auto mfma = [&](int buf) {
    short8 af[4], bfr[4];
#pragma unroll
    for (int i = 0; i < 4; ++i) af[i] = *(const short8*)&As[buf][wm + i * 16 + fr][fq];
#pragma unroll
    for (int i = 0; i < 4; ++i) bfr[i] = *(const short8*)&Bs[buf][wn + i * 16 + fr][fq];
#pragma unroll
    for (int mi = 0; mi < 4; ++mi)
#pragma unroll
      for (int ni = 0; ni < 4; ++ni)
        acc[mi][ni] = __builtin_amdgcn_mfma_f32_16x16x32_bf16(af[mi], bfr[ni], acc[mi][ni], 0, 0, 0);
  };
  loadA(0);
  storeA(0);
  loadA(32);
  __syncthreads();
  for (int kt = 0; kt < kTiles; kt += 2) {
    storeA(1);
    if (kt + 2 < kTiles) loadB((kt + 2) << 5);
    mfma(0);
    __syncthreads();
    if (kt + 2 < kTiles) storeB(0);
    if (kt + 3 < kTiles) loadA((kt + 3) << 5);
    mfma(1);
    __syncthreads();
  }
  int fq4 = (lane >> 4) * 4;
#pragma unroll
  for (int mi = 0; mi < 4; ++mi)
#pragma unroll
    for (int ni = 0; ni < 4; ++ni) {
      int col = n0 + wn + ni * 16 + fr;
      if (col < N) {
        int rowb = m0 + wm + mi * 16 + fq4;
#pragma unroll
        for (int r = 0; r < 4; ++r)
          C[(size_t)(rowb + r) * N + col] = f2bf(acc[mi][ni][r]);
      }
    }
}

// ---------------- GEMM 64x64, BK=64, double-buffer x2-unrolled, fused f32 epilogue ----------------
// MODE 1: out = aux + acc*mask[row]; MODE 2: out = (aux + acc)*mask[row]. N exact (512). kTiles even.
template <int MODE>
__global__ __launch_bounds__(256) void gemm64_ep_kernel(
    const __hip_bfloat16* __restrict__ A, const __hip_bfloat16* __restrict__ BT,
    const float* __restrict__ aux, const float* __restrict__ mask,
    float* __restrict__ out, int M, int N, int K) {
  __shared__ short As[2][64][72];
  __shared__ short Bs[2][64][72];
  int m0 = blockIdx.x * 64, n0 = blockIdx.y * 64;
  int t = threadIdx.x;
  int lane = t & 63, wv = t >> 6;
  int wm = (wv & 1) * 32, wn = (wv >> 1) * 32;
  f32x4 acc[2][2];
#pragma unroll
  for (int i = 0; i < 2; ++i)
#pragma unroll
    for (int j = 0; j < 2; ++j) acc[i][j] = (f32x4){0.f, 0.f, 0.f, 0.f};
  const short* Ag = (const short*)A;
  const short* Bg = (const short*)BT;
  int sr = t >> 2;
  int sc = (t & 3) * 16;
  const short* Ap = Ag + (size_t)(m0 + sr) * K + sc;
  const short* Bp = Bg + (size_t)(n0 + sr) * K + sc;
  int fr = lane & 15, fq = (lane >> 4) * 8;
  int kTiles = K >> 6;
  short8 a0A = 0, a1A = 0, b0A = 0, b1A = 0;
  short8 a0B = 0, a1B = 0, b0B = 0, b1B = 0;
  auto loadA = [&](int k0) {
    a0A = *(const short8*)(Ap + k0);
    a1A = *(const short8*)(Ap + k0 + 8);
    b0A = *(const short8*)(Bp + k0);
    b1A = *(const short8*)(Bp + k0 + 8);
  };
  auto loadB = [&](int k0) {
    a0B = *(const short8*)(Ap + k0);
    a1B = *(const short8*)(Ap + k0 + 8);
    b0B = *(const short8*)(Bp + k0);
    b1B = *(const short8*)(Bp + k0 + 8);
  };
  auto storeA = [&](int buf) {
    *(short8*)&As[buf][sr][sc] = a0A;
    *(short8*)&As[buf][sr][sc + 8] = a1A;
    *(short8*)&Bs[buf][sr][sc] = b0A;
    *(short8*)&Bs[buf][sr][sc + 8] = b1A;
  };
  auto storeB = [&](int buf) {
    *(short8*)&As[buf][sr][sc] = a0B;
    *(short8*)&As[buf][sr][sc + 8] = a1B;
    *(short8*)&Bs[buf][sr][sc] = b0B;
    *(short8*)&Bs[buf][sr][sc + 8] = b1B;
  };
  auto mfma = [&](int buf) {
#pragma unroll
    for (int kk = 0; kk < 2; ++kk) {
      short8 af[2], bfr[2];
#pragma unroll
      for (int i = 0; i < 2; ++i) af[i] = *(const short8*)&As[buf][wm + i * 16 + fr][kk * 32 + fq];
#pragma unroll
      for (int i = 0; i < 2; ++i) bfr[i] = *(const short8*)&Bs[buf][wn + i * 16 + fr][kk * 32 + fq];
#pragma unroll
      for (int mi = 0; mi < 2; ++mi)
#pragma unroll
        for (int ni = 0; ni < 2; ++ni)
          acc[mi][ni] = __builtin_amdgcn_mfma_f32_16x16x32_bf16(af[mi], bfr[ni], acc[mi][ni], 0, 0, 0);
    }
  };
  loadA(0);
  storeA(0);
  loadA(64);
  __syncthreads();
  for (int kt = 0; kt < kTiles; kt += 2) {
    storeA(1);
    if (kt + 2 < kTiles) loadB((kt + 2) << 6);
    mfma(0);
    __syncthreads();
    if (kt + 2 < kTiles) storeB(0);
    if (kt + 3 < kTiles) loadA((kt + 3) << 6);
    mfma(1);
    __syncthreads();
  }
  int fq4 = (lane >> 4) * 4;
#pragma unroll
  for (int mi = 0; mi < 2; ++mi)
#pragma unroll
    for (int ni = 0; ni < 2; ++ni) {
      int col = n0 + wn + ni * 16 + fr;
#pragma unroll
      for (int r = 0; r < 4; ++r) {
        int row = m0 + wm + mi * 16 + fq4 + r;
        float m = mask[row];
        size_t a = (size_t)row * N + col;
        float v = acc[mi][ni][r];
        if (MODE == 1) out[a] = aux[a] + v * m;
        else           out[a] = (aux[a] + v) * m;
      }
    }
}

// ---------------- fused FFN GEMM: gated = silu(A@w1) * (A@w3), double-buffer ----------------
// BT = w13T (FPAD rows: w1[0..1367], w3[1368..2735], zeros beyond). Writes G [M, KP2] bf16,
// zeroing pad cols >= DFFn. Grid (M/64, KP2/64). SiLU in epilogue only.
__global__ __launch_bounds__(256) void gemm64g_kernel(
    const __hip_bfloat16* __restrict__ A, const __hip_bfloat16* __restrict__ BT,
    __hip_bfloat16* __restrict__ G, int M, int K) {
  __shared__ short As[2][64][72];
  __shared__ short B1s[2][64][72];
  __shared__ short B3s[2][64][72];
  int m0 = blockIdx.x * 64, n0 = blockIdx.y * 64;
  int t = threadIdx.x;
  int lane = t & 63, wv = t >> 6;
  int wm = (wv & 1) * 32, wn = (wv >> 1) * 32;
  f32x4 acc1[2][2], acc3[2][2];
#pragma unroll
  for (int i = 0; i < 2; ++i)
#pragma unroll
    for (int j = 0; j < 2; ++j) {
      acc1[i][j] = (f32x4){0.f, 0.f, 0.f, 0.f};
      acc3[i][j] = (f32x4){0.f, 0.f, 0.f, 0.f};
    }
  const short* Ag = (const short*)A;
  const short* Bg = (const short*)BT;
  int sr = t >> 2;
  int sc = (t & 3) * 16;
  const short* Ap  = Ag + (size_t)(m0 + sr) * K + sc;
  const short* B1p = Bg + (size_t)(n0 + sr) * K + sc;
  const short* B3p = Bg + (size_t)(DFFn + n0 + sr) * K + sc;
  int fr = lane & 15, fq = (lane >> 4) * 8;
  int kTiles = K >> 6;   // 8
  short8 a0A = 0, a1A = 0, c0A = 0, c1A = 0, d0A = 0, d1A = 0;
  short8 a0B = 0, a1B = 0, c0B = 0, c1B = 0, d0B = 0, d1B = 0;
  auto loadA = [&](int k0) {
    a0A = *(const short8*)(Ap + k0);
    a1A = *(const short8*)(Ap + k0 + 8);
    c0A = *(const short8*)(B1p + k0);
    c1A = *(const short8*)(B1p + k0 + 8);
    d0A = *(const short8*)(B3p + k0);
    d1A = *(const short8*)(B3p + k0 + 8);
  };
  auto loadB = [&](int k0) {
    a0B = *(const short8*)(Ap + k0);
    a1B = *(const short8*)(Ap + k0 + 8);
    c0B = *(const short8*)(B1p + k0);
    c1B = *(const short8*)(B1p + k0 + 8);
    d0B = *(const short8*)(B3p + k0);
    d1B = *(const short8*)(B3p + k0 + 8);
  };
  auto storeA = [&](int buf) {
    *(short8*)&As[buf][sr][sc] = a0A;
    *(short8*)&As[buf][sr][sc + 8] = a1A;
    *(short8*)&B1s[buf][sr][sc] = c0A;
    *(short8*)&B1s[buf][sr][sc + 8] = c1A;
    *(short8*)&B3s[buf][sr][sc] = d0A;
    *(short8*)&B3s[buf][sr][sc + 8] = d1A;
  };
  auto storeB = [&](int buf) {
    *(short8*)&As[buf][sr][sc] = a0B;
    *(short8*)&As[buf][sr][sc + 8] = a1B;
    *(short8*)&B1s[buf][sr][sc] = c0B;
    *(short8*)&B1s[buf][sr][sc + 8] = c1B;
    *(short8*)&B3s[buf][sr][sc] = d0B;
    *(short8*)&B3s[buf][sr][sc + 8] = d1B;
  };
  auto mfma = [&](int buf) {
#pragma unroll
    for (int kk = 0; kk < 2; ++kk) {
      short8 af[2], b1f[2], b3f[2];
#pragma unroll
      for (int i = 0; i < 2; ++i) af[i]  = *(const short8*)&As[buf][wm + i * 16 + fr][kk * 32 + fq];
#pragma unroll
      for (int i = 0; i < 2; ++i) b1f[i] = *(const short8*)&B1s[buf][wn + i * 16 + fr][kk * 32 + fq];
#pragma unroll
      for (int i = 0; i < 2; ++i) b3f[i] = *(const short8*)&B3s[buf][wn + i * 16 + fr][kk * 32 + fq];
#pragma unroll
      for (int mi = 0; mi < 2; ++mi)
#pragma unroll
        for (int ni = 0; ni < 2; ++ni) {
          acc1[mi][ni] = __builtin_amdgcn_mfma_f32_16x16x32_bf16(af[mi], b1f[ni], acc1[mi][ni], 0, 0, 0);
          acc3[mi][ni] = __builtin_amdgcn_mfma_f32_16x16x32_bf16(af[mi], b3f[ni], acc3[mi][ni], 0, 0, 0);
        }
    }
  };
  loadA(0);
  storeA(0);
  loadA(64);
  __syncthreads();
  for (int kt = 0; kt < kTiles; kt += 2) {
    storeA(1);
    if (kt + 2 < kTiles) loadB((kt + 2) << 6);
    mfma(0);
    __syncthreads();
    if (kt + 2 < kTiles) storeB(0);
    if (kt + 3 < kTiles) loadA((kt + 3) << 6);
    mfma(1);
    __syncthreads();
  }
  int fq4 = (lane >> 4) * 4;
#pragma unroll
  for (int mi = 0; mi < 2; ++mi)
#pragma unroll
    for (int ni = 0; ni < 2; ++ni) {
      int col = n0 + wn + ni * 16 + fr;
      bool valid = col < DFFn;
#pragma unroll
      for (int r = 0; r < 4; ++r) {
        int row = m0 + wm + mi * 16 + fq4 + r;
        float h1v = acc1[mi][ni][r];
        float sil = h1v / (1.f + __expf(-h1v));
        float g = sil * acc3[mi][ni][r];
        G[(size_t)row * KP2 + col] = valid ? f2bf(g) : f2bf(0.f);
      }
    }
}

// ---------------- chunked scan: intra-chunk + chunk-state ----------------
__global__ __launch_bounds__(256) void chunk_intra_kernel(
    const __hip_bfloat16* __restrict__ P, const float* __restrict__ dt,
    const float* __restrict__ la, float* __restrict__ ys,
    float* __restrict__ Sbuf, float* __restrict__ ecL, float* __restrict__ ec) {
  int id = blockIdx.x;
  int h = id & 15, c = (id >> 4) & 7, b = id >> 7;
  int t = threadIdx.x, lane = t & 63, wv = t >> 6;
  __shared__ __align__(16) char smem[55040];
  short* sCB = (short*)smem;             // sC [64][136] (phase<=3a), sBt [128][72] (phase>=3b)
  short* sB  = (short*)(smem + 18432);   // [64][136]
  short* sUD = (short*)(smem + 35840);   // [64 p][72]  (s-minor)
  short* sG  = (short*)(smem + 45056);   // [64 t][72]  (s-minor)
  float* scum = (float*)(smem + 54272);  // [64]
  float* sws  = scum + 64;
  float* sdt  = sws + 64;
  int row0 = b * Sn + c * CH;
  const short* Pb = (const short*)P;
#pragma unroll
  for (int i = 0; i < 4; ++i) {
    int idx = t + i * 256;
    int r = idx >> 4, kk = (idx & 15) * 8;
    *(short8*)&sCB[r * 136 + kk] = *(const short8*)(Pb + (size_t)(row0 + r) * PSTR + 4096 + h * 128 + kk);
    *(short8*)&sB [r * 136 + kk] = *(const short8*)(Pb + (size_t)(row0 + r) * PSTR + 2048 + h * 128 + kk);
  }
  if (t < 64) { sdt[t] = dt[(size_t)(row0 + t) * Hn + h]; scum[t] = la[(size_t)(row0 + t) * Hn + h]; }
  __syncthreads();
  if (wv == 0) {
    float v = scum[lane];
#pragma unroll
    for (int o = 1; o < 64; o <<= 1) { float n = __shfl_up(v, o); if (lane >= o) v += n; }
    scum[lane] = v;
    float c63 = __shfl(v, 63);
    sws[lane] = __expf(c63 - v);
    ec[((size_t)((b * NCH + c) * Hn + h)) * 64 + lane] = __expf(v);
    if (lane == 0) ecL[(b * NCH + c) * Hn + h] = __expf(c63);
  }
#pragma unroll
  for (int i = 0; i < 2; ++i) {
    int idx = t + i * 256;
    int s = idx >> 3, pc = (idx & 7) * 8;
    short8 uv = *(const short8*)(Pb + (size_t)(row0 + s) * PSTR + 1024 + h * 64 + pc);
    float dv = sdt[s];
#pragma unroll
    for (int j = 0; j < 8; ++j) sUD[(pc + j) * 72 + s] = f2bfs(bfs2f(uv[j]) * dv);
  }
  __syncthreads();
  int fr = lane & 15, fq = (lane >> 4) * 8, q4 = (lane >> 4) * 4;
  {
    short8 af[4];
#pragma unroll
    for (int k = 0; k < 4; ++k) af[k] = *(short8*)&sCB[(16 * wv + fr) * 136 + k * 32 + fq];
#pragma unroll
    for (int j = 0; j < 4; ++j) {
      f32x4 acc = (f32x4){0.f, 0.f, 0.f, 0.f};
#pragma unroll
      for (int k = 0; k < 4; ++k) {
        short8 bf = *(short8*)&sB[(16 * j + fr) * 136 + k * 32 + fq];
        acc = __builtin_amdgcn_mfma_f32_16x16x32_bf16(af[k], bf, acc, 0, 0, 0);
      }
      int ss = 16 * j + fr;
      float cs = scum[ss];
#pragma unroll
      for (int r = 0; r < 4; ++r) {
        int tt = 16 * wv + q4 + r;
        float w = (ss <= tt) ? __expf(scum[tt] - cs) : 0.f;
        sG[tt * 72 + ss] = f2bfs(acc[r] * w);
      }
    }
  }
  __syncthreads();
#pragma unroll
  for (int i = 0; i < 32; ++i) {
    int idx = t + i * 256;
    int rn = idx >> 6, s = idx & 63;
    sCB[rn * 72 + s] = f2bfs(bfs2f(sB[s * 136 + rn]) * sws[s]);
  }
  __syncthreads();
  {
    short8 ag[2];
#pragma unroll
    for (int k = 0; k < 2; ++k) ag[k] = *(short8*)&sG[(16 * wv + fr) * 72 + k * 32 + fq];
#pragma unroll
    for (int j = 0; j < 4; ++j) {
      f32x4 acc = (f32x4){0.f, 0.f, 0.f, 0.f};
#pragma unroll
      for (int k = 0; k < 2; ++k) {
        short8 bf = *(short8*)&sUD[(16 * j + fr) * 72 + k * 32 + fq];
        acc = __builtin_amdgcn_mfma_f32_16x16x32_bf16(ag[k], bf, acc, 0, 0, 0);
      }
#pragma unroll
      for (int r = 0; r < 4; ++r)
        ys[(size_t)(row0 + 16 * wv + q4 + r) * DINn + h * 64 + 16 * j + fr] = acc[r];
    }
  }
#pragma unroll
  for (int mt0 = 0; mt0 < 2; ++mt0) {
    int mt = wv * 2 + mt0;
    short8 ab[2];
#pragma unroll
    for (int k = 0; k < 2; ++k) ab[k] = *(short8*)&sCB[(16 * mt + fr) * 72 + k * 32 + fq];
#pragma unroll
    for (int j = 0; j < 4; ++j) {
      f32x4 acc = (f32x4){0.f, 0.f, 0.f, 0.f};
#pragma unroll
      for (int k = 0; k < 2; ++k) {
        short8 bf = *(short8*)&sUD[(16 * j + fr) * 72 + k * 32 + fq];
        acc = __builtin_amdgcn_mfma_f32_16x16x32_bf16(ab[k], bf, acc, 0, 0, 0);
      }
#pragma unroll
      for (int r = 0; r < 4; ++r)
        Sbuf[((size_t)((b * NCH + c) * Hn + h) * RNn + 16 * mt + q4 + r) * 64 + 16 * j + fr] = acc[r];
    }
  }
}

// ---------------- prefix over chunk states ----------------
__global__ void chunk_state_kernel(const float* __restrict__ Sbuf, const float* __restrict__ ecL,
                                   float* __restrict__ Hp) {
  int bh = blockIdx.x >> 5;
  int j = (blockIdx.x & 31) * 256 + threadIdx.x;
  int b = bh >> 4, h = bh & 15;
  float hp = 0.f;
#pragma unroll
  for (int c = 0; c < NCH; ++c) {
    size_t addr = ((size_t)((b * NCH + c) * Hn + h)) * 8192 + j;
    Hp[addr] = hp;
    hp = ecL[(b * NCH + c) * Hn + h] * hp + Sbuf[addr];
  }
}

// ---------------- inter-chunk + gate fused ----------------
__global__ __launch_bounds__(256) void inter_gate_kernel(
    const __hip_bfloat16* __restrict__ P, const float* __restrict__ Hp,
    const float* __restrict__ ec, const float* __restrict__ ys,
    const float* __restrict__ Dsk, __hip_bfloat16* __restrict__ y2b) {
  int id = blockIdx.x;
  int h = id & 15, c = (id >> 4) & 7, b = id >> 7;
  int t = threadIdx.x, lane = t & 63, wv = t >> 6;
  __shared__ __align__(16) short sC[64 * 136];
  __shared__ __align__(16) short sHt[64 * 136];      // [p][rn]
  __shared__ __align__(16) short sz[64 * 64];
  __shared__ __align__(16) short su[64 * 64];
  __shared__ float sec[64];
  int row0 = b * Sn + c * CH;
  const short* Pb = (const short*)P;
#pragma unroll
  for (int i = 0; i < 2; ++i) {
    int idx = t + i * 256;
    int r = idx >> 3, pc = (idx & 7) * 8;
    *(short8*)&sz[r * 64 + pc] = *(const short8*)(Pb + (size_t)(row0 + r) * PSTR + h * 64 + pc);
    *(short8*)&su[r * 64 + pc] = *(const short8*)(Pb + (size_t)(row0 + r) * PSTR + 1024 + h * 64 + pc);
  }
  if (c > 0) {
    size_t hbase = ((size_t)((b * NCH + c) * Hn + h)) * 8192;
#pragma unroll
    for (int i = 0; i < 4; ++i) {
      int idx = t + i * 256;
      int r = idx >> 4, kk = (idx & 15) * 8;
      *(short8*)&sC[r * 136 + kk] = *(const short8*)(Pb + (size_t)(row0 + r) * PSTR + 4096 + h * 128 + kk);
    }
#pragma unroll
    for (int i = 0; i < 32; ++i) {
      int idx = t + i * 256;
      int rn = idx >> 6, p = idx & 63;
      sHt[p * 136 + rn] = f2bfs(Hp[hbase + idx]);
    }
    if (t < 64) sec[t] = ec[((size_t)((b * NCH + c) * Hn + h)) * 64 + t];
  }
  __syncthreads();
  int fr = lane & 15, fq = (lane >> 4) * 8, q4 = (lane >> 4) * 4;
  f32x4 acc[4];
#pragma unroll
  for (int j = 0; j < 4; ++j) acc[j] = (f32x4){0.f, 0.f, 0.f, 0.f};
  if (c > 0) {
    short8 af[4];
#pragma unroll
    for (int k = 0; k < 4; ++k) af[k] = *(short8*)&sC[(16 * wv + fr) * 136 + k * 32 + fq];
#pragma unroll
    for (int j = 0; j < 4; ++j)
#pragma unroll
      for (int k = 0; k < 4; ++k) {
        short8 bf = *(short8*)&sHt[(16 * j + fr) * 136 + k * 32 + fq];
        acc[j] = __builtin_amdgcn_mfma_f32_16x16x32_bf16(af[k], bf, acc[j], 0, 0, 0);
      }
  }
  float dsk = Dsk[h];
#pragma unroll
  for (int j = 0; j < 4; ++j) {
    int col = 16 * j + fr;
#pragma unroll
    for (int r = 0; r < 4; ++r) {
      int tt = 16 * wv + q4 + r;
      size_t a = (size_t)(row0 + tt) * DINn + h * 64 + col;
      float val = ys[a];
      if (c > 0) val += sec[tt] * acc[j][r];
      float uu = bfs2f(su[tt * 64 + col]);
      float zz = bfs2f(sz[tt * 64 + col]);
      float sil = zz / (1.f + __expf(-zz));
      y2b[a] = f2bf((val + uu * dsk) * sil);
    }
  }
}

extern "C" void kernel_launch(void* const* d_in, const int* in_sizes, int n_in,
                              void* d_out, int out_size, void* d_ws, size_t ws_size,
                              hipStream_t stream) {
  const float* x    = (const float*)d_in[0];
  const float* mask = (const float*)d_in[1];
  const float* n1w  = (const float*)d_in[2];
  const float* n2w  = (const float*)d_in[3];
  const float* Wz   = (const float*)d_in[4];
  const float* Wx   = (const float*)d_in[5];
  const float* Wb   = (const float*)d_in[6];
  const float* Wc   = (const float*)d_in[7];
  const float* Wdt  = (const float*)d_in[8];
  const float* dtb  = (const float*)d_in[9];
  const float* Alog = (const float*)d_in[10];
  const float* Dsk  = (const float*)d_in[11];
  const float* Wout = (const float*)d_in[12];
  const float* w1   = (const float*)d_in[13];
  const float* w2   = (const float*)d_in[14];
  const float* w3   = (const float*)d_in[15];

  char* ws = (char*)d_ws;
  size_t off = 0;
  auto alloc = [&](size_t bytes) {
    char* p = ws + off;
    off += (bytes + 255) & ~(size_t)255;
    return p;
  };
  __hip_bfloat16* xnb = (__hip_bfloat16*)alloc((size_t)BSn * Dn * 2);
  __hip_bfloat16* P = (__hip_bfloat16*)alloc((size_t)BSn * PSTR * 2);
  float* dt  = (float*)alloc((size_t)BSn * Hn * 4);
  float* la  = (float*)alloc((size_t)BSn * Hn * 4);
  float* ys  = (float*)alloc((size_t)BSn * DINn * 4);
  float* ecL = (float*)alloc((size_t)Bn * NCH * Hn * 4);
  float* ec  = (float*)alloc((size_t)Bn * NCH * Hn * 64 * 4);
  __hip_bfloat16* WallT = (__hip_bfloat16*)alloc((size_t)PSTR * Dn * 2);   // [z|u|B|C]^T
  __hip_bfloat16* WoutT = (__hip_bfloat16*)alloc((size_t)Dn * DINn * 2);
  __hip_bfloat16* w13T  = (__hip_bfloat16*)alloc((size_t)FPAD * Dn * 2);   // [w1|w3|zeros]^T, 2816 rows
  __hip_bfloat16* w2T   = (__hip_bfloat16*)alloc((size_t)Dn * KP2 * 2);    // K-pad 1408 (BK=64)
  // overlaid arena:
  //   Sbuf   [0, 16.78M)       live: chunk_intra -> chunk_state
  //   Hp     [16.78M, 33.55M)  live: chunk_state -> inter_gate
  //   y2b    [0, 4.2M)         live: inter_gate -> gemm64<1>   (over dead Sbuf)
  //   xres   [8.39M, 12.58M)   live: gemm64<1> -> gemm64<2>    (over dead Sbuf)
  //   gated  [16.78M, 22.55M)  live: gemm64g -> gemm64<2>      (over dead Hp)
  char* arena = alloc(34000000);
  float* Sbuf = (float*)arena;
  float* Hp   = (float*)(arena + 16777216);
  __hip_bfloat16* y2b = (__hip_bfloat16*)arena;
  float* xres = (float*)(arena + 8388608);
  __hip_bfloat16* gatedb = (__hip_bfloat16*)(arena + 16777216);

  // -------- transpose job table (single dispatch) --------
  T8 td;
  td.src[0] = Wz;   td.dst[0] = WallT;                      td.Rr[0] = 512;  td.Cc[0] = 1024; td.RrPad[0] = 512;  td.CcPad[0] = 1024;
  td.src[1] = Wx;   td.dst[1] = WallT + (size_t)1024 * 512; td.Rr[1] = 512;  td.Cc[1] = 1024; td.RrPad[1] = 512;  td.CcPad[1] = 1024;
  td.src[2] = Wb;   td.dst[2] = WallT + (size_t)2048 * 512; td.Rr[2] = 512;  td.Cc[2] = 2048; td.RrPad[2] = 512;  td.CcPad[2] = 2048;
  td.src[3] = Wc;   td.dst[3] = WallT + (size_t)4096 * 512; td.Rr[3] = 512;  td.Cc[3] = 2048; td.RrPad[3] = 512;  td.CcPad[3] = 2048;
  td.src[4] = Wout; td.dst[4] = WoutT;                      td.Rr[4] = 1024; td.Cc[4] = 512;  td.RrPad[4] = 1024; td.CcPad[4] = 512;
  td.src[5] = w1;   td.dst[5] = w13T;                       td.Rr[5] = 512;  td.Cc[5] = 1368; td.RrPad[5] = 512;  td.CcPad[5] = 1368;
  td.src[6] = w3;   td.dst[6] = w13T + (size_t)1368 * 512;  td.Rr[6] = 512;  td.Cc[6] = 1368; td.RrPad[6] = 512;  td.CcPad[6] = 1448; // zero rows -> 2816 total
  td.src[7] = w2;   td.dst[7] = w2T;                        td.Rr[7] = 1368; td.Cc[7] = 512;  td.RrPad[7] = KP2;  td.CcPad[7] = 512;  // zero K-pad
  int tot = 0;
  for (int i = 0; i < 8; ++i) {
    td.gw[i] = (td.CcPad[i] + 31) / 32;
    int gh = (td.RrPad[i] + 31) / 32;
    td.start[i] = tot;
    tot += td.gw[i] * gh;
  }
  td.start[8] = tot;

  transpose8_kernel<<<tot, dim3(32, 8), 0, stream>>>(td);
  rmsnorm1_dt_kernel<<<BSn, 256, 0, stream>>>(x, n1w, mask, Wdt, dtb, Alog, xnb, dt, la);
  gemm_kernel<<<dim3(16, 48), 256, 0, stream>>>(xnb, WallT, P, BSn, PSTR, Dn);
  chunk_intra_kernel<<<Bn * NCH * Hn, 256, 0, stream>>>(P, dt, la, ys, Sbuf, ecL, ec);
  chunk_state_kernel<<<Bn * Hn * 32, 256, 0, stream>>>(Sbuf, ecL, Hp);
  inter_gate_kernel<<<Bn * NCH * Hn, 256, 0, stream>>>(P, Hp, ec, ys, Dsk, y2b);
  gemm64_ep_kernel<1><<<dim3(32, 8), 256, 0, stream>>>(y2b, WoutT, x, mask, xres, BSn, Dn, DINn);
  rmsnorm2_kernel<<<BSn, 256, 0, stream>>>(xres, n2w, xnb);
  gemm64g_kernel<<<dim3(32, KP2 / 64), 256, 0, stream>>>(xnb, w13T, gatedb, BSn, Dn);
  gemm64_ep_kernel<2><<<dim3(32, 8), 256, 0, stream>>>(gatedb, w2T, xres, mask, (float*)d_out, BSn, Dn, KP2);
}

// Round 14
// 214.681 us; speedup vs baseline: 2.9163x; 1.0235x over previous
//
#include <hip/hip_runtime.h>
#include <hip/hip_bf16.h>
#include <math.h>

#define Bn 4
#define Sn 512
#define Dn 512
#define DINn 1024
#define Hn 16
#define Pn 64
#define RNn 128
#define DFFn 1368
#define KP2 1408      // w2 K padded to BK=64 multiple
#define BSn (Bn*Sn)
#define CH 64
#define NCH (Sn/CH)   // 8
#define PSTR 6144     // fused proj row stride: [z(1024) | u(1024) | B(2048) | C(2048)]
#define FSTR 2736     // fused ffn row stride: [h1(1368) | h3(1368)]
#define FPAD 2816     // w13T padded rows (zero rows 2736..2815)

typedef __attribute__((ext_vector_type(8))) short short8;
typedef __attribute__((ext_vector_type(4))) float f32x4;

static __device__ __forceinline__ float bf2f(__hip_bfloat16 v){return __bfloat162float(v);}
static __device__ __forceinline__ __hip_bfloat16 f2bf(float v){return __float2bfloat16(v);}
static __device__ __forceinline__ short f2bfs(float v){ __hip_bfloat16 b=f2bf(v); short s; __builtin_memcpy(&s,&b,2); return s; }
static __device__ __forceinline__ float bfs2f(short s){ __hip_bfloat16 b; __builtin_memcpy(&b,&s,2); return bf2f(b); }

// ---------------- prep: 8 weight transposes (float tile, conflict-free) + rmsnorm1+dt ----------------
struct T8 {
  const float* src[8];
  __hip_bfloat16* dst[8];
  int Rr[8], Cc[8], RrPad[8], CcPad[8], gw[8];
  int start[9];
};

__global__ __launch_bounds__(256) void prep_kernel(
    T8 d, const float* __restrict__ x, const float* __restrict__ w,
    const float* __restrict__ mask, const float* __restrict__ Wdt,
    const float* __restrict__ dtb, const float* __restrict__ Alog,
    __hip_bfloat16* __restrict__ outb, float* __restrict__ dt,
    float* __restrict__ la, int tstart) {
  __shared__ float tile[32][33];
  __shared__ float xs[Dn];
  __shared__ float red[4];
  int bid = blockIdx.x, t = threadIdx.x;
  if (bid < tstart) {
    int i = 0;
#pragma unroll
    for (int k = 1; k < 8; ++k) if (bid >= d.start[k]) i = k;
    int rel = bid - d.start[i];
    int gx = rel % d.gw[i], gy = rel / d.gw[i];
    const float* in = d.src[i];
    __hip_bfloat16* out = d.dst[i];
    int Rr = d.Rr[i], Cc = d.Cc[i], RrPad = d.RrPad[i], CcPad = d.CcPad[i];
    int c0 = gx * 32, r0 = gy * 32;
    int tx = t & 31, ty = t >> 5;
    for (int k = ty; k < 32; k += 8) {
      int r = r0 + k, cc = c0 + tx;
      tile[k][tx] = (r < Rr && cc < Cc) ? in[(size_t)r * Cc + cc] : 0.f;
    }
    __syncthreads();
    for (int k = ty; k < 32; k += 8) {
      int r = c0 + k, cc = r0 + tx;
      if (r < CcPad && cc < RrPad) out[(size_t)r * RrPad + cc] = f2bf(tile[tx][k]);
    }
  } else {
    int row = bid - tstart;
    const float* xr = x + (size_t)row * Dn;
    float v0 = xr[t], v1 = xr[t + 256];
    float ss = v0 * v0 + v1 * v1;
#pragma unroll
    for (int o = 32; o > 0; o >>= 1) ss += __shfl_down(ss, o);
    if ((t & 63) == 0) red[t >> 6] = ss;
    __syncthreads();
    float tot = red[0] + red[1] + red[2] + red[3];
    float sc = rsqrtf(tot * (1.f / Dn) + 1e-6f) * mask[row];
    float o0 = v0 * sc * w[t], o1v = v1 * sc * w[t + 256];
    outb[(size_t)row * Dn + t] = f2bf(o0);
    outb[(size_t)row * Dn + t + 256] = f2bf(o1v);
    xs[t] = o0;
    xs[t + 256] = o1v;
    __syncthreads();
    int h = t >> 4, j = t & 15;
    float s = 0.f;
    for (int k = j * 32; k < j * 32 + 32; ++k) s = fmaf(xs[k], Wdt[k * Hn + h], s);
#pragma unroll
    for (int o = 8; o > 0; o >>= 1) s += __shfl_down(s, o, 16);
    if (j == 0) {
      float v = s + dtb[h];
      float sp = (v > 20.f) ? v : log1pf(expf(v));
      float Ah = expf(Alog[h]);
      dt[(size_t)row * Hn + h] = sp;
      la[(size_t)row * Hn + h] = -Ah * sp;
    }
  }
}

// ---------------- rmsnorm (f32 in, no mask) -> bf16 ----------------
__global__ void rmsnorm2_kernel(const float* __restrict__ x,
                                const float* __restrict__ w,
                                __hip_bfloat16* __restrict__ out) {
  int row = blockIdx.x, t = threadIdx.x;
  const float* xr = x + (size_t)row * Dn;
  float v0 = xr[t], v1 = xr[t + 256];
  float ss = v0 * v0 + v1 * v1;
#pragma unroll
  for (int o = 32; o > 0; o >>= 1) ss += __shfl_down(ss, o);
  __shared__ float red[4];
  if ((t & 63) == 0) red[t >> 6] = ss;
  __syncthreads();
  float tot = red[0] + red[1] + red[2] + red[3];
  float sc = rsqrtf(tot * (1.f / Dn) + 1e-6f);
  out[(size_t)row * Dn + t] = f2bf(v0 * sc * w[t]);
  out[(size_t)row * Dn + t + 256] = f2bf(v1 * sc * w[t + 256]);
}

// ---------------- GEMM 128x128, BK=32, TRUE double-buffer, x2-unrolled ----------------
__global__ __launch_bounds__(256) void gemm_kernel(
    const __hip_bfloat16* __restrict__ A, const __hip_bfloat16* __restrict__ BT,
    __hip_bfloat16* __restrict__ C, int M, int N, int K) {
  __shared__ short As[2][128][40];
  __shared__ short Bs[2][128][40];
  int m0 = blockIdx.x * 128, n0 = blockIdx.y * 128;
  int t = threadIdx.x;
  int lane = t & 63, wv = t >> 6;
  int wm = (wv & 1) * 64, wn = (wv >> 1) * 64;
  f32x4 acc[4][4];
#pragma unroll
  for (int i = 0; i < 4; ++i)
#pragma unroll
    for (int j = 0; j < 4; ++j) acc[i][j] = (f32x4){0.f, 0.f, 0.f, 0.f};
  const short* Ag = (const short*)A;
  const short* Bg = (const short*)BT;
  int sr = t >> 2;
  int sc = (t & 3) * 8;
  int rb0 = n0 + sr, rb1 = n0 + sr + 64;
  bool bv0 = rb0 < N, bv1 = rb1 < N;
  const short* Ap0 = Ag + (size_t)(m0 + sr) * K + sc;
  const short* Ap1 = Ag + (size_t)(m0 + sr + 64) * K + sc;
  const short* Bp0 = Bg + (size_t)rb0 * K + sc;
  const short* Bp1 = Bg + (size_t)rb1 * K + sc;
  int kTiles = (K + 31) >> 5;
  int fr = lane & 15, fq = (lane >> 4) * 8;
  short8 a0A = 0, a1A = 0, b0A = 0, b1A = 0;
  short8 a0B = 0, a1B = 0, b0B = 0, b1B = 0;
  auto loadA = [&](int k0) {
    a0A = *(const short8*)(Ap0 + k0);
    a1A = *(const short8*)(Ap1 + k0);
    b0A = bv0 ? *(const short8*)(Bp0 + k0) : (short8)0;
    b1A = bv1 ? *(const short8*)(Bp1 + k0) : (short8)0;
  };
  auto loadB = [&](int k0) {
    a0B = *(const short8*)(Ap0 + k0);
    a1B = *(const short8*)(Ap1 + k0);
    b0B = bv0 ? *(const short8*)(Bp0 + k0) : (short8)0;
    b1B = bv1 ? *(const short8*)(Bp1 + k0) : (short8)0;
  };
  auto storeA = [&](int buf) {
    *(short8*)&As[buf][sr][sc] = a0A;
    *(short8*)&As[buf][sr + 64][sc] = a1A;
    *(short8*)&Bs[buf][sr][sc] = b0A;
    *(short8*)&Bs[buf][sr + 64][sc] = b1A;
  };
  auto storeB = [&](int buf) {
    *(short8*)&As[buf][sr][sc] = a0B;
    *(short8*)&As[buf][sr + 64][sc] = a1B;
    *(short8*)&Bs[buf][sr][sc] = b0B;
    *(short8*)&Bs[buf][sr + 64][sc] = b1B;
  };
  auto mfma = [&](int buf) {
    short8 af[4], bfr[4];
#pragma unroll
    for (int i = 0; i < 4; ++i) af[i] = *(const short8*)&As[buf][wm + i * 16 + fr][fq];
#pragma unroll
    for (int i = 0; i < 4; ++i) bfr[i] = *(const short8*)&Bs[buf][wn + i * 16 + fr][fq];
#pragma unroll
    for (int mi = 0; mi < 4; ++mi)
#pragma unroll
      for (int ni = 0; ni < 4; ++ni)
        acc[mi][ni] = __builtin_amdgcn_mfma_f32_16x16x32_bf16(af[mi], bfr[ni], acc[mi][ni], 0, 0, 0);
  };
  loadA(0);
  storeA(0);
  loadA(32);
  __syncthreads();
  for (int kt = 0; kt < kTiles; kt += 2) {
    storeA(1);
    if (kt + 2 < kTiles) loadB((kt + 2) << 5);
    mfma(0);
    __syncthreads();
    if (kt + 2 < kTiles) storeB(0);
    if (kt + 3 < kTiles) loadA((kt + 3) << 5);
    mfma(1);
    __syncthreads();
  }
  int fq4 = (lane >> 4) * 4;
#pragma unroll
  for (int mi = 0; mi < 4; ++mi)
#pragma unroll
    for (int ni = 0; ni < 4; ++ni) {
      int col = n0 + wn + ni * 16 + fr;
      if (col < N) {
        int rowb = m0 + wm + mi * 16 + fq4;
#pragma unroll
        for (int r = 0; r < 4; ++r)
          C[(size_t)(rowb + r) * N + col] = f2bf(acc[mi][ni][r]);
      }
    }
}

// ---------------- GEMM 64x64, BK=64, double-buffer x2-unrolled, fused f32 epilogue ----------------
// MODE 1: out = aux + acc*mask[row]; MODE 2: out = (aux + acc)*mask[row]. N exact (512). kTiles even.
template <int MODE>
__global__ __launch_bounds__(256) void gemm64_ep_kernel(
    const __hip_bfloat16* __restrict__ A, const __hip_bfloat16* __restrict__ BT,
    const float* __restrict__ aux, const float* __restrict__ mask,
    float* __restrict__ out, int M, int N, int K) {
  __shared__ short As[2][64][72];
  __shared__ short Bs[2][64][72];
  int m0 = blockIdx.x * 64, n0 = blockIdx.y * 64;
  int t = threadIdx.x;
  int lane = t & 63, wv = t >> 6;
  int wm = (wv & 1) * 32, wn = (wv >> 1) * 32;
  f32x4 acc[2][2];
#pragma unroll
  for (int i = 0; i < 2; ++i)
#pragma unroll
    for (int j = 0; j < 2; ++j) acc[i][j] = (f32x4){0.f, 0.f, 0.f, 0.f};
  const short* Ag = (const short*)A;
  const short* Bg = (const short*)BT;
  int sr = t >> 2;
  int sc = (t & 3) * 16;
  const short* Ap = Ag + (size_t)(m0 + sr) * K + sc;
  const short* Bp = Bg + (size_t)(n0 + sr) * K + sc;
  int fr = lane & 15, fq = (lane >> 4) * 8;
  int kTiles = K >> 6;
  short8 a0A = 0, a1A = 0, b0A = 0, b1A = 0;
  short8 a0B = 0, a1B = 0, b0B = 0, b1B = 0;
  auto loadA = [&](int k0) {
    a0A = *(const short8*)(Ap + k0);
    a1A = *(const short8*)(Ap + k0 + 8);
    b0A = *(const short8*)(Bp + k0);
    b1A = *(const short8*)(Bp + k0 + 8);
  };
  auto loadB = [&](int k0) {
    a0B = *(const short8*)(Ap + k0);
    a1B = *(const short8*)(Ap + k0 + 8);
    b0B = *(const short8*)(Bp + k0);
    b1B = *(const short8*)(Bp + k0 + 8);
  };
  auto storeA = [&](int buf) {
    *(short8*)&As[buf][sr][sc] = a0A;
    *(short8*)&As[buf][sr][sc + 8] = a1A;
    *(short8*)&Bs[buf][sr][sc] = b0A;
    *(short8*)&Bs[buf][sr][sc + 8] = b1A;
  };
  auto storeB = [&](int buf) {
    *(short8*)&As[buf][sr][sc] = a0B;
    *(short8*)&As[buf][sr][sc + 8] = a1B;
    *(short8*)&Bs[buf][sr][sc] = b0B;
    *(short8*)&Bs[buf][sr][sc + 8] = b1B;
  };
  auto mfma = [&](int buf) {
#pragma unroll
    for (int kk = 0; kk < 2; ++kk) {
      short8 af[2], bfr[2];
#pragma unroll
      for (int i = 0; i < 2; ++i) af[i] = *(const short8*)&As[buf][wm + i * 16 + fr][kk * 32 + fq];
#pragma unroll
      for (int i = 0; i < 2; ++i) bfr[i] = *(const short8*)&Bs[buf][wn + i * 16 + fr][kk * 32 + fq];
#pragma unroll
      for (int mi = 0; mi < 2; ++mi)
#pragma unroll
        for (int ni = 0; ni < 2; ++ni)
          acc[mi][ni] = __builtin_amdgcn_mfma_f32_16x16x32_bf16(af[mi], bfr[ni], acc[mi][ni], 0, 0, 0);
    }
  };
  loadA(0);
  storeA(0);
  loadA(64);
  __syncthreads();
  for (int kt = 0; kt < kTiles; kt += 2) {
    storeA(1);
    if (kt + 2 < kTiles) loadB((kt + 2) << 6);
    mfma(0);
    __syncthreads();
    if (kt + 2 < kTiles) storeB(0);
    if (kt + 3 < kTiles) loadA((kt + 3) << 6);
    mfma(1);
    __syncthreads();
  }
  int fq4 = (lane >> 4) * 4;
#pragma unroll
  for (int mi = 0; mi < 2; ++mi)
#pragma unroll
    for (int ni = 0; ni < 2; ++ni) {
      int col = n0 + wn + ni * 16 + fr;
#pragma unroll
      for (int r = 0; r < 4; ++r) {
        int row = m0 + wm + mi * 16 + fq4 + r;
        float m = mask[row];
        size_t a = (size_t)row * N + col;
        float v = acc[mi][ni][r];
        if (MODE == 1) out[a] = aux[a] + v * m;
        else           out[a] = (aux[a] + v) * m;
      }
    }
}

// ---------------- fused FFN GEMM: gated = silu(A@w1) * (A@w3), double-buffer ----------------
__global__ __launch_bounds__(256) void gemm64g_kernel(
    const __hip_bfloat16* __restrict__ A, const __hip_bfloat16* __restrict__ BT,
    __hip_bfloat16* __restrict__ G, int M, int K) {
  __shared__ short As[2][64][72];
  __shared__ short B1s[2][64][72];
  __shared__ short B3s[2][64][72];
  int m0 = blockIdx.x * 64, n0 = blockIdx.y * 64;
  int t = threadIdx.x;
  int lane = t & 63, wv = t >> 6;
  int wm = (wv & 1) * 32, wn = (wv >> 1) * 32;
  f32x4 acc1[2][2], acc3[2][2];
#pragma unroll
  for (int i = 0; i < 2; ++i)
#pragma unroll
    for (int j = 0; j < 2; ++j) {
      acc1[i][j] = (f32x4){0.f, 0.f, 0.f, 0.f};
      acc3[i][j] = (f32x4){0.f, 0.f, 0.f, 0.f};
    }
  const short* Ag = (const short*)A;
  const short* Bg = (const short*)BT;
  int sr = t >> 2;
  int sc = (t & 3) * 16;
  const short* Ap  = Ag + (size_t)(m0 + sr) * K + sc;
  const short* B1p = Bg + (size_t)(n0 + sr) * K + sc;
  const short* B3p = Bg + (size_t)(DFFn + n0 + sr) * K + sc;
  int fr = lane & 15, fq = (lane >> 4) * 8;
  int kTiles = K >> 6;
  short8 a0A = 0, a1A = 0, c0A = 0, c1A = 0, d0A = 0, d1A = 0;
  short8 a0B = 0, a1B = 0, c0B = 0, c1B = 0, d0B = 0, d1B = 0;
  auto loadA = [&](int k0) {
    a0A = *(const short8*)(Ap + k0);
    a1A = *(const short8*)(Ap + k0 + 8);
    c0A = *(const short8*)(B1p + k0);
    c1A = *(const short8*)(B1p + k0 + 8);
    d0A = *(const short8*)(B3p + k0);
    d1A = *(const short8*)(B3p + k0 + 8);
  };
  auto loadB = [&](int k0) {
    a0B = *(const short8*)(Ap + k0);
    a1B = *(const short8*)(Ap + k0 + 8);
    c0B = *(const short8*)(B1p + k0);
    c1B = *(const short8*)(B1p + k0 + 8);
    d0B = *(const short8*)(B3p + k0);
    d1B = *(const short8*)(B3p + k0 + 8);
  };
  auto storeA = [&](int buf) {
    *(short8*)&As[buf][sr][sc] = a0A;
    *(short8*)&As[buf][sr][sc + 8] = a1A;
    *(short8*)&B1s[buf][sr][sc] = c0A;
    *(short8*)&B1s[buf][sr][sc + 8] = c1A;
    *(short8*)&B3s[buf][sr][sc] = d0A;
    *(short8*)&B3s[buf][sr][sc + 8] = d1A;
  };
  auto storeB = [&](int buf) {
    *(short8*)&As[buf][sr][sc] = a0B;
    *(short8*)&As[buf][sr][sc + 8] = a1B;
    *(short8*)&B1s[buf][sr][sc] = c0B;
    *(short8*)&B1s[buf][sr][sc + 8] = c1B;
    *(short8*)&B3s[buf][sr][sc] = d0B;
    *(short8*)&B3s[buf][sr][sc + 8] = d1B;
  };
  auto mfma = [&](int buf) {
#pragma unroll
    for (int kk = 0; kk < 2; ++kk) {
      short8 af[2], b1f[2], b3f[2];
#pragma unroll
      for (int i = 0; i < 2; ++i) af[i]  = *(const short8*)&As[buf][wm + i * 16 + fr][kk * 32 + fq];
#pragma unroll
      for (int i = 0; i < 2; ++i) b1f[i] = *(const short8*)&B1s[buf][wn + i * 16 + fr][kk * 32 + fq];
#pragma unroll
      for (int i = 0; i < 2; ++i) b3f[i] = *(const short8*)&B3s[buf][wn + i * 16 + fr][kk * 32 + fq];
#pragma unroll
      for (int mi = 0; mi < 2; ++mi)
#pragma unroll
        for (int ni = 0; ni < 2; ++ni) {
          acc1[mi][ni] = __builtin_amdgcn_mfma_f32_16x16x32_bf16(af[mi], b1f[ni], acc1[mi][ni], 0, 0, 0);
          acc3[mi][ni] = __builtin_amdgcn_mfma_f32_16x16x32_bf16(af[mi], b3f[ni], acc3[mi][ni], 0, 0, 0);
        }
    }
  };
  loadA(0);
  storeA(0);
  loadA(64);
  __syncthreads();
  for (int kt = 0; kt < kTiles; kt += 2) {
    storeA(1);
    if (kt + 2 < kTiles) loadB((kt + 2) << 6);
    mfma(0);
    __syncthreads();
    if (kt + 2 < kTiles) storeB(0);
    if (kt + 3 < kTiles) loadA((kt + 3) << 6);
    mfma(1);
    __syncthreads();
  }
  int fq4 = (lane >> 4) * 4;
#pragma unroll
  for (int mi = 0; mi < 2; ++mi)
#pragma unroll
    for (int ni = 0; ni < 2; ++ni) {
      int col = n0 + wn + ni * 16 + fr;
      bool valid = col < DFFn;
#pragma unroll
      for (int r = 0; r < 4; ++r) {
        int row = m0 + wm + mi * 16 + fq4 + r;
        float h1v = acc1[mi][ni][r];
        float sil = h1v / (1.f + __expf(-h1v));
        float g = sil * acc3[mi][ni][r];
        G[(size_t)row * KP2 + col] = valid ? f2bf(g) : f2bf(0.f);
      }
    }
}

// ---------------- chunked scan: intra-chunk + chunk-state (bf16 ys/Sbuf outputs) ----------------
__global__ __launch_bounds__(256) void chunk_intra_kernel(
    const __hip_bfloat16* __restrict__ P, const float* __restrict__ dt,
    const float* __restrict__ la, __hip_bfloat16* __restrict__ ysb,
    __hip_bfloat16* __restrict__ Sbuf, float* __restrict__ ecL, float* __restrict__ ec) {
  int id = blockIdx.x;
  int h = id & 15, c = (id >> 4) & 7, b = id >> 7;
  int t = threadIdx.x, lane = t & 63, wv = t >> 6;
  __shared__ __align__(16) char smem[55040];
  short* sCB = (short*)smem;             // sC [64][136] (phase<=3a), sBt [128][72] (phase>=3b)
  short* sB  = (short*)(smem + 18432);   // [64][136]
  short* sUD = (short*)(smem + 35840);   // [64 p][72]  (s-minor)
  short* sG  = (short*)(smem + 45056);   // [64 t][72]  (s-minor)
  float* scum = (float*)(smem + 54272);  // [64]
  float* sws  = scum + 64;
  float* sdt  = sws + 64;
  int row0 = b * Sn + c * CH;
  const short* Pb = (const short*)P;
#pragma unroll
  for (int i = 0; i < 4; ++i) {
    int idx = t + i * 256;
    int r = idx >> 4, kk = (idx & 15) * 8;
    *(short8*)&sCB[r * 136 + kk] = *(const short8*)(Pb + (size_t)(row0 + r) * PSTR + 4096 + h * 128 + kk);
    *(short8*)&sB [r * 136 + kk] = *(const short8*)(Pb + (size_t)(row0 + r) * PSTR + 2048 + h * 128 + kk);
  }
  if (t < 64) { sdt[t] = dt[(size_t)(row0 + t) * Hn + h]; scum[t] = la[(size_t)(row0 + t) * Hn + h]; }
  __syncthreads();
  if (wv == 0) {
    float v = scum[lane];
#pragma unroll
    for (int o = 1; o < 64; o <<= 1) { float n = __shfl_up(v, o); if (lane >= o) v += n; }
    scum[lane] = v;
    float c63 = __shfl(v, 63);
    sws[lane] = __expf(c63 - v);
    ec[((size_t)((b * NCH + c) * Hn + h)) * 64 + lane] = __expf(v);
    if (lane == 0) ecL[(b * NCH + c) * Hn + h] = __expf(c63);
  }
#pragma unroll
  for (int i = 0; i < 2; ++i) {
    int idx = t + i * 256;
    int s = idx >> 3, pc = (idx & 7) * 8;
    short8 uv = *(const short8*)(Pb + (size_t)(row0 + s) * PSTR + 1024 + h * 64 + pc);
    float dv = sdt[s];
#pragma unroll
    for (int j = 0; j < 8; ++j) sUD[(pc + j) * 72 + s] = f2bfs(bfs2f(uv[j]) * dv);
  }
  __syncthreads();
  int fr = lane & 15, fq = (lane >> 4) * 8, q4 = (lane >> 4) * 4;
  {
    short8 af[4];
#pragma unroll
    for (int k = 0; k < 4; ++k) af[k] = *(short8*)&sCB[(16 * wv + fr) * 136 + k * 32 + fq];
#pragma unroll
    for (int j = 0; j < 4; ++j) {
      f32x4 acc = (f32x4){0.f, 0.f, 0.f, 0.f};
#pragma unroll
      for (int k = 0; k < 4; ++k) {
        short8 bf = *(short8*)&sB[(16 * j + fr) * 136 + k * 32 + fq];
        acc = __builtin_amdgcn_mfma_f32_16x16x32_bf16(af[k], bf, acc, 0, 0, 0);
      }
      int ss = 16 * j + fr;
      float cs = scum[ss];
#pragma unroll
      for (int r = 0; r < 4; ++r) {
        int tt = 16 * wv + q4 + r;
        float w = (ss <= tt) ? __expf(scum[tt] - cs) : 0.f;
        sG[tt * 72 + ss] = f2bfs(acc[r] * w);
      }
    }
  }
  __syncthreads();
#pragma unroll
  for (int i = 0; i < 32; ++i) {
    int idx = t + i * 256;
    int rn = idx >> 6, s = idx & 63;
    sCB[rn * 72 + s] = f2bfs(bfs2f(sB[s * 136 + rn]) * sws[s]);
  }
  __syncthreads();
  {
    short8 ag[2];
#pragma unroll
    for (int k = 0; k < 2; ++k) ag[k] = *(short8*)&sG[(16 * wv + fr) * 72 + k * 32 + fq];
#pragma unroll
    for (int j = 0; j < 4; ++j) {
      f32x4 acc = (f32x4){0.f, 0.f, 0.f, 0.f};
#pragma unroll
      for (int k = 0; k < 2; ++k) {
        short8 bf = *(short8*)&sUD[(16 * j + fr) * 72 + k * 32 + fq];
        acc = __builtin_amdgcn_mfma_f32_16x16x32_bf16(ag[k], bf, acc, 0, 0, 0);
      }
#pragma unroll
      for (int r = 0; r < 4; ++r)
        ysb[(size_t)(row0 + 16 * wv + q4 + r) * DINn + h * 64 + 16 * j + fr] = f2bf(acc[r]);
    }
  }
#pragma unroll
  for (int mt0 = 0; mt0 < 2; ++mt0) {
    int mt = wv * 2 + mt0;
    short8 ab[2];
#pragma unroll
    for (int k = 0; k < 2; ++k) ab[k] = *(short8*)&sCB[(16 * mt + fr) * 72 + k * 32 + fq];
#pragma unroll
    for (int j = 0; j < 4; ++j) {
      f32x4 acc = (f32x4){0.f, 0.f, 0.f, 0.f};
#pragma unroll
      for (int k = 0; k < 2; ++k) {
        short8 bf = *(short8*)&sUD[(16 * j + fr) * 72 + k * 32 + fq];
        acc = __builtin_amdgcn_mfma_f32_16x16x32_bf16(ab[k], bf, acc, 0, 0, 0);
      }
#pragma unroll
      for (int r = 0; r < 4; ++r)
        ((short*)Sbuf)[((size_t)((b * NCH + c) * Hn + h) * RNn + 16 * mt + q4 + r) * 64 + 16 * j + fr] =
            f2bfs(acc[r]);
    }
  }
}

// ---------------- prefix over chunk states (bf16 in/out, f32 accumulate, 2 elems/thread) ----------------
__global__ void chunk_state_kernel(const __hip_bfloat16* __restrict__ Sbuf,
                                   const float* __restrict__ ecL,
                                   __hip_bfloat16* __restrict__ Hp) {
  int bh = blockIdx.x >> 4;                          // 64 (b,h) pairs x 16 blocks
  int j = ((blockIdx.x & 15) * 256 + threadIdx.x) * 2;
  int b = bh >> 4, h = bh & 15;
  const short* Sb = (const short*)Sbuf;
  short* Hs = (short*)Hp;
  float hp0 = 0.f, hp1 = 0.f;
#pragma unroll
  for (int c = 0; c < NCH; ++c) {
    size_t addr = ((size_t)((b * NCH + c) * Hn + h)) * 8192 + j;
    short2 sv = *(const short2*)(Sb + addr);
    *(short2*)(Hs + addr) = make_short2(f2bfs(hp0), f2bfs(hp1));
    float e = ecL[(b * NCH + c) * Hn + h];
    hp0 = e * hp0 + bfs2f(sv.x);
    hp1 = e * hp1 + bfs2f(sv.y);
  }
}

// ---------------- inter-chunk + gate fused (bf16 Hp/ys inputs) ----------------
__global__ __launch_bounds__(256) void inter_gate_kernel(
    const __hip_bfloat16* __restrict__ P, const __hip_bfloat16* __restrict__ Hp,
    const float* __restrict__ ec, const __hip_bfloat16* __restrict__ ysb,
    const float* __restrict__ Dsk, __hip_bfloat16* __restrict__ y2b) {
  int id = blockIdx.x;
  int h = id & 15, c = (id >> 4) & 7, b = id >> 7;
  int t = threadIdx.x, lane = t & 63, wv = t >> 6;
  __shared__ __align__(16) short sC[64 * 136];
  __shared__ __align__(16) short sHt[64 * 136];      // [p][rn]
  __shared__ __align__(16) short sz[64 * 64];
  __shared__ __align__(16) short su[64 * 64];
  __shared__ float sec[64];
  int row0 = b * Sn + c * CH;
  const short* Pb = (const short*)P;
#pragma unroll
  for (int i = 0; i < 2; ++i) {
    int idx = t + i * 256;
    int r = idx >> 3, pc = (idx & 7) * 8;
    *(short8*)&sz[r * 64 + pc] = *(const short8*)(Pb + (size_t)(row0 + r) * PSTR + h * 64 + pc);
    *(short8*)&su[r * 64 + pc] = *(const short8*)(Pb + (size_t)(row0 + r) * PSTR + 1024 + h * 64 + pc);
  }
  if (c > 0) {
    const short* Hps = (const short*)Hp;
    size_t hbase = ((size_t)((b * NCH + c) * Hn + h)) * 8192;
#pragma unroll
    for (int i = 0; i < 4; ++i) {
      int idx = t + i * 256;
      int r = idx >> 4, kk = (idx & 15) * 8;
      *(short8*)&sC[r * 136 + kk] = *(const short8*)(Pb + (size_t)(row0 + r) * PSTR + 4096 + h * 128 + kk);
    }
#pragma unroll
    for (int i = 0; i < 32; ++i) {
      int idx = t + i * 256;
      int rn = idx >> 6, p = idx & 63;
      sHt[p * 136 + rn] = Hps[hbase + idx];
    }
    if (t < 64) sec[t] = ec[((size_t)((b * NCH + c) * Hn + h)) * 64 + t];
  }
  __syncthreads();
  int fr = lane & 15, fq = (lane >> 4) * 8, q4 = (lane >> 4) * 4;
  f32x4 acc[4];
#pragma unroll
  for (int j = 0; j < 4; ++j) acc[j] = (f32x4){0.f, 0.f, 0.f, 0.f};
  if (c > 0) {
    short8 af[4];
#pragma unroll
    for (int k = 0; k < 4; ++k) af[k] = *(short8*)&sC[(16 * wv + fr) * 136 + k * 32 + fq];
#pragma unroll
    for (int j = 0; j < 4; ++j)
#pragma unroll
      for (int k = 0; k < 4; ++k) {
        short8 bf = *(short8*)&sHt[(16 * j + fr) * 136 + k * 32 + fq];
        acc[j] = __builtin_amdgcn_mfma_f32_16x16x32_bf16(af[k], bf, acc[j], 0, 0, 0);
      }
  }
  float dsk = Dsk[h];
#pragma unroll
  for (int j = 0; j < 4; ++j) {
    int col = 16 * j + fr;
#pragma unroll
    for (int r = 0; r < 4; ++r) {
      int tt = 16 * wv + q4 + r;
      size_t a = (size_t)(row0 + tt) * DINn + h * 64 + col;
      float val = bf2f(ysb[a]);
      if (c > 0) val += sec[tt] * acc[j][r];
      float uu = bfs2f(su[tt * 64 + col]);
      float zz = bfs2f(sz[tt * 64 + col]);
      float sil = zz / (1.f + __expf(-zz));
      y2b[a] = f2bf((val + uu * dsk) * sil);
    }
  }
}

extern "C" void kernel_launch(void* const* d_in, const int* in_sizes, int n_in,
                              void* d_out, int out_size, void* d_ws, size_t ws_size,
                              hipStream_t stream) {
  const float* x    = (const float*)d_in[0];
  const float* mask = (const float*)d_in[1];
  const float* n1w  = (const float*)d_in[2];
  const float* n2w  = (const float*)d_in[3];
  const float* Wz   = (const float*)d_in[4];
  const float* Wx   = (const float*)d_in[5];
  const float* Wb   = (const float*)d_in[6];
  const float* Wc   = (const float*)d_in[7];
  const float* Wdt  = (const float*)d_in[8];
  const float* dtb  = (const float*)d_in[9];
  const float* Alog = (const float*)d_in[10];
  const float* Dsk  = (const float*)d_in[11];
  const float* Wout = (const float*)d_in[12];
  const float* w1   = (const float*)d_in[13];
  const float* w2   = (const float*)d_in[14];
  const float* w3   = (const float*)d_in[15];

  char* ws = (char*)d_ws;
  size_t off = 0;
  auto alloc = [&](size_t bytes) {
    char* p = ws + off;
    off += (bytes + 255) & ~(size_t)255;
    return p;
  };
  __hip_bfloat16* xnb = (__hip_bfloat16*)alloc((size_t)BSn * Dn * 2);
  __hip_bfloat16* P = (__hip_bfloat16*)alloc((size_t)BSn * PSTR * 2);
  float* dt  = (float*)alloc((size_t)BSn * Hn * 4);
  float* la  = (float*)alloc((size_t)BSn * Hn * 4);
  __hip_bfloat16* ysb = (__hip_bfloat16*)alloc((size_t)BSn * DINn * 2);
  float* ecL = (float*)alloc((size_t)Bn * NCH * Hn * 4);
  float* ec  = (float*)alloc((size_t)Bn * NCH * Hn * 64 * 4);
  __hip_bfloat16* WallT = (__hip_bfloat16*)alloc((size_t)PSTR * Dn * 2);   // [z|u|B|C]^T
  __hip_bfloat16* WoutT = (__hip_bfloat16*)alloc((size_t)Dn * DINn * 2);
  __hip_bfloat16* w13T  = (__hip_bfloat16*)alloc((size_t)FPAD * Dn * 2);   // [w1|w3|zeros]^T, 2816 rows
  __hip_bfloat16* w2T   = (__hip_bfloat16*)alloc((size_t)Dn * KP2 * 2);    // K-pad 1408 (BK=64)
  // overlaid arena (bf16 scan intermediates):
  //   Sbuf  bf16 [0, 8.39M)      live: chunk_intra -> chunk_state
  //   Hp    bf16 [8.39M, 16.78M) live: chunk_state -> inter_gate
  //   y2b   bf16 [16.78M, 20.97M) live: inter_gate -> gemm64<1>
  //   xres  f32  [0, 4.2M)        live: gemm64<1> -> gemm64<2>  (over dead Sbuf)
  //   gated bf16 [4.2M, 10M)      live: gemm64g -> gemm64<2>    (over dead Sbuf/Hp)
  char* arena = alloc(22000000);
  __hip_bfloat16* Sbuf = (__hip_bfloat16*)arena;
  __hip_bfloat16* Hp   = (__hip_bfloat16*)(arena + 8388608);
  __hip_bfloat16* y2b  = (__hip_bfloat16*)(arena + 16777216);
  float* xres          = (float*)arena;
  __hip_bfloat16* gatedb = (__hip_bfloat16*)(arena + 4194304);

  // -------- transpose job table --------
  T8 td;
  td.src[0] = Wz;   td.dst[0] = WallT;                      td.Rr[0] = 512;  td.Cc[0] = 1024; td.RrPad[0] = 512;  td.CcPad[0] = 1024;
  td.src[1] = Wx;   td.dst[1] = WallT + (size_t)1024 * 512; td.Rr[1] = 512;  td.Cc[1] = 1024; td.RrPad[1] = 512;  td.CcPad[1] = 1024;
  td.src[2] = Wb;   td.dst[2] = WallT + (size_t)2048 * 512; td.Rr[2] = 512;  td.Cc[2] = 2048; td.RrPad[2] = 512;  td.CcPad[2] = 2048;
  td.src[3] = Wc;   td.dst[3] = WallT + (size_t)4096 * 512; td.Rr[3] = 512;  td.Cc[3] = 2048; td.RrPad[3] = 512;  td.CcPad[3] = 2048;
  td.src[4] = Wout; td.dst[4] = WoutT;                      td.Rr[4] = 1024; td.Cc[4] = 512;  td.RrPad[4] = 1024; td.CcPad[4] = 512;
  td.src[5] = w1;   td.dst[5] = w13T;                       td.Rr[5] = 512;  td.Cc[5] = 1368; td.RrPad[5] = 512;  td.CcPad[5] = 1368;
  td.src[6] = w3;   td.dst[6] = w13T + (size_t)1368 * 512;  td.Rr[6] = 512;  td.Cc[6] = 1368; td.RrPad[6] = 512;  td.CcPad[6] = 1448; // zero rows -> 2816 total
  td.src[7] = w2;   td.dst[7] = w2T;                        td.Rr[7] = 1368; td.Cc[7] = 512;  td.RrPad[7] = KP2;  td.CcPad[7] = 512;  // zero K-pad
  int tot = 0;
  for (int i = 0; i < 8; ++i) {
    td.gw[i] = (td.CcPad[i] + 31) / 32;
    int gh = (td.RrPad[i] + 31) / 32;
    td.start[i] = tot;
    tot += td.gw[i] * gh;
  }
  td.start[8] = tot;

  prep_kernel<<<tot + BSn, 256, 0, stream>>>(td, x, n1w, mask, Wdt, dtb, Alog, xnb, dt, la, tot);
  gemm_kernel<<<dim3(16, 48), 256, 0, stream>>>(xnb, WallT, P, BSn, PSTR, Dn);
  chunk_intra_kernel<<<Bn * NCH * Hn, 256, 0, stream>>>(P, dt, la, ysb, Sbuf, ecL, ec);
  chunk_state_kernel<<<Bn * Hn * 16, 256, 0, stream>>>(Sbuf, ecL, Hp);
  inter_gate_kernel<<<Bn * NCH * Hn, 256, 0, stream>>>(P, Hp, ec, ysb, Dsk, y2b);
  gemm64_ep_kernel<1><<<dim3(32, 8), 256, 0, stream>>>(y2b, WoutT, x, mask, xres, BSn, Dn, DINn);
  rmsnorm2_kernel<<<BSn, 256, 0, stream>>>(xres, n2w, xnb);
  gemm64g_kernel<<<dim3(32, KP2 / 64), 256, 0, stream>>>(xnb, w13T, gatedb, BSn, Dn);
  gemm64_ep_kernel<2><<<dim3(32, 8), 256, 0, stream>>>(gatedb, w2T, xres, mask, (float*)d_out, BSn, Dn, KP2);
}

// Round 15
// 209.154 us; speedup vs baseline: 2.9934x; 1.0264x over previous
//
#include <hip/hip_runtime.h>
#include <hip/hip_bf16.h>
#include <math.h>

#define Bn 4
#define Sn 512
#define Dn 512
#define DINn 1024
#define Hn 16
#define Pn 64
#define RNn 128
#define DFFn 1368
#define KP2 1408      // w2 K padded to BK=64 multiple
#define BSn (Bn*Sn)
#define CH 64
#define NCH (Sn/CH)   // 8
#define PSTR 6144     // fused proj row stride: [z(1024) | u(1024) | B(2048) | C(2048)]
#define FSTR 2736     // fused ffn row stride: [h1(1368) | h3(1368)]
#define FPAD 2816     // w13T padded rows (zero rows 2736..2815)

typedef __attribute__((ext_vector_type(8))) short short8;
typedef __attribute__((ext_vector_type(4))) float f32x4;
typedef __attribute__((ext_vector_type(4))) short short4v;

static __device__ __forceinline__ float bf2f(__hip_bfloat16 v){return __bfloat162float(v);}
static __device__ __forceinline__ __hip_bfloat16 f2bf(float v){return __float2bfloat16(v);}
static __device__ __forceinline__ short f2bfs(float v){ __hip_bfloat16 b=f2bf(v); short s; __builtin_memcpy(&s,&b,2); return s; }
static __device__ __forceinline__ float bfs2f(short s){ __hip_bfloat16 b; __builtin_memcpy(&b,&s,2); return bf2f(b); }

// ---------------- prep: 8 weight transposes (64x64 tiles, float4 loads) + rmsnorm1+dt ----------------
struct T8 {
  const float* src[8];
  __hip_bfloat16* dst[8];
  int Rr[8], Cc[8], RrPad[8], CcPad[8], gw[8];
  int start[9];
};

__global__ __launch_bounds__(256) void prep_kernel(
    T8 d, const float* __restrict__ x, const float* __restrict__ w,
    const float* __restrict__ mask, const float* __restrict__ Wdt,
    const float* __restrict__ dtb, const float* __restrict__ Alog,
    __hip_bfloat16* __restrict__ outb, float* __restrict__ dt,
    float* __restrict__ la, int tstart) {
  __shared__ float tile[64][65];
  __shared__ float xs[Dn];
  __shared__ float red[4];
  int bid = blockIdx.x, t = threadIdx.x;
  if (bid < tstart) {
    int i = 0;
#pragma unroll
    for (int k = 1; k < 8; ++k) if (bid >= d.start[k]) i = k;
    int rel = bid - d.start[i];
    int gx = rel % d.gw[i], gy = rel / d.gw[i];   // gx over CcPad (out rows), gy over RrPad (out cols)
    const float* in = d.src[i];
    __hip_bfloat16* out = d.dst[i];
    int Rr = d.Rr[i], Cc = d.Cc[i], RrPad = d.RrPad[i], CcPad = d.CcPad[i];
    int tx = t & 15, ty = t >> 4;                 // tx: 4-col group, ty: 16 rows
    // load 64x64 tile (row = original row, col = original col), float4 per lane
#pragma unroll
    for (int i4 = 0; i4 < 4; ++i4) {
      int r = gy * 64 + ty + i4 * 16;
      int c0 = gx * 64 + tx * 4;
      f32x4 v = (f32x4){0.f, 0.f, 0.f, 0.f};
      if (r < Rr && c0 + 3 < Cc) v = *(const f32x4*)(in + (size_t)r * Cc + c0);  // Cc%4==0 -> all-in/out
      tile[ty + i4 * 16][tx * 4 + 0] = v[0];
      tile[ty + i4 * 16][tx * 4 + 1] = v[1];
      tile[ty + i4 * 16][tx * 4 + 2] = v[2];
      tile[ty + i4 * 16][tx * 4 + 3] = v[3];
    }
    __syncthreads();
    // write transposed: out[r2 = orig col][c2 = orig row], 4 bf16 per lane along c2
#pragma unroll
    for (int i4 = 0; i4 < 4; ++i4) {
      int r2 = gx * 64 + ty + i4 * 16;            // out row (orig col)
      int c2 = gy * 64 + tx * 4;                  // out col (orig row)
      if (r2 < CcPad && c2 + 3 < RrPad) {
        int k = ty + i4 * 16;
        short4v o;
        o.x = f2bfs(tile[tx * 4 + 0][k]);
        o.y = f2bfs(tile[tx * 4 + 1][k]);
        o.z = f2bfs(tile[tx * 4 + 2][k]);
        o.w = f2bfs(tile[tx * 4 + 3][k]);
        *(short4v*)((short*)out + (size_t)r2 * RrPad + c2) = o;
      }
    }
  } else {
    int row = bid - tstart;
    const float* xr = x + (size_t)row * Dn;
    float v0 = xr[t], v1 = xr[t + 256];
    float ss = v0 * v0 + v1 * v1;
#pragma unroll
    for (int o = 32; o > 0; o >>= 1) ss += __shfl_down(ss, o);
    if ((t & 63) == 0) red[t >> 6] = ss;
    __syncthreads();
    float tot = red[0] + red[1] + red[2] + red[3];
    float sc = rsqrtf(tot * (1.f / Dn) + 1e-6f) * mask[row];
    float o0 = v0 * sc * w[t], o1v = v1 * sc * w[t + 256];
    outb[(size_t)row * Dn + t] = f2bf(o0);
    outb[(size_t)row * Dn + t + 256] = f2bf(o1v);
    xs[t] = o0;
    xs[t + 256] = o1v;
    __syncthreads();
    int h = t >> 4, j = t & 15;
    // conflict-free: lane j reads xs[j + kk*16] -> 16 consecutive banks, h-groups broadcast
    float s = 0.f;
#pragma unroll
    for (int kk = 0; kk < 32; ++kk) {
      int k = j + kk * 16;
      s = fmaf(xs[k], Wdt[k * Hn + h], s);
    }
#pragma unroll
    for (int o = 8; o > 0; o >>= 1) s += __shfl_down(s, o, 16);
    if (j == 0) {
      float v = s + dtb[h];
      float sp = (v > 20.f) ? v : log1pf(expf(v));
      float Ah = expf(Alog[h]);
      dt[(size_t)row * Hn + h] = sp;
      la[(size_t)row * Hn + h] = -Ah * sp;
    }
  }
}

// ---------------- rmsnorm (f32 in, no mask) -> bf16 ----------------
__global__ void rmsnorm2_kernel(const float* __restrict__ x,
                                const float* __restrict__ w,
                                __hip_bfloat16* __restrict__ out) {
  int row = blockIdx.x, t = threadIdx.x;
  const float* xr = x + (size_t)row * Dn;
  float v0 = xr[t], v1 = xr[t + 256];
  float ss = v0 * v0 + v1 * v1;
#pragma unroll
  for (int o = 32; o > 0; o >>= 1) ss += __shfl_down(ss, o);
  __shared__ float red[4];
  if ((t & 63) == 0) red[t >> 6] = ss;
  __syncthreads();
  float tot = red[0] + red[1] + red[2] + red[3];
  float sc = rsqrtf(tot * (1.f / Dn) + 1e-6f);
  out[(size_t)row * Dn + t] = f2bf(v0 * sc * w[t]);
  out[(size_t)row * Dn + t + 256] = f2bf(v1 * sc * w[t + 256]);
}

// ---------------- GEMM 128x128, BK=32, TRUE double-buffer, x2-unrolled ----------------
__global__ __launch_bounds__(256) void gemm_kernel(
    const __hip_bfloat16* __restrict__ A, const __hip_bfloat16* __restrict__ BT,
    __hip_bfloat16* __restrict__ C, int M, int N, int K) {
  __shared__ short As[2][128][40];
  __shared__ short Bs[2][128][40];
  int m0 = blockIdx.x * 128, n0 = blockIdx.y * 128;
  int t = threadIdx.x;
  int lane = t & 63, wv = t >> 6;
  int wm = (wv & 1) * 64, wn = (wv >> 1) * 64;
  f32x4 acc[4][4];
#pragma unroll
  for (int i = 0; i < 4; ++i)
#pragma unroll
    for (int j = 0; j < 4; ++j) acc[i][j] = (f32x4){0.f, 0.f, 0.f, 0.f};
  const short* Ag = (const short*)A;
  const short* Bg = (const short*)BT;
  int sr = t >> 2;
  int sc = (t & 3) * 8;
  int rb0 = n0 + sr, rb1 = n0 + sr + 64;
  bool bv0 = rb0 < N, bv1 = rb1 < N;
  const short* Ap0 = Ag + (size_t)(m0 + sr) * K + sc;
  const short* Ap1 = Ag + (size_t)(m0 + sr + 64) * K + sc;
  const short* Bp0 = Bg + (size_t)rb0 * K + sc;
  const short* Bp1 = Bg + (size_t)rb1 * K + sc;
  int kTiles = (K + 31) >> 5;
  int fr = lane & 15, fq = (lane >> 4) * 8;
  short8 a0A = 0, a1A = 0, b0A = 0, b1A = 0;
  short8 a0B = 0, a1B = 0, b0B = 0, b1B = 0;
  auto loadA = [&](int k0) {
    a0A = *(const short8*)(Ap0 + k0);
    a1A = *(const short8*)(Ap1 + k0);
    b0A = bv0 ? *(const short8*)(Bp0 + k0) : (short8)0;
    b1A = bv1 ? *(const short8*)(Bp1 + k0) : (short8)0;
  };
  auto loadB = [&](int k0) {
    a0B = *(const short8*)(Ap0 + k0);
    a1B = *(const short8*)(Ap1 + k0);
    b0B = bv0 ? *(const short8*)(Bp0 + k0) : (short8)0;
    b1B = bv1 ? *(const short8*)(Bp1 + k0) : (short8)0;
  };
  auto storeA = [&](int buf) {
    *(short8*)&As[buf][sr][sc] = a0A;
    *(short8*)&As[buf][sr + 64][sc] = a1A;
    *(short8*)&Bs[buf][sr][sc] = b0A;
    *(short8*)&Bs[buf][sr + 64][sc] = b1A;
  };
  auto storeB = [&](int buf) {
    *(short8*)&As[buf][sr][sc] = a0B;
    *(short8*)&As[buf][sr + 64][sc] = a1B;
    *(short8*)&Bs[buf][sr][sc] = b0B;
    *(short8*)&Bs[buf][sr + 64][sc] = b1B;
  };
  auto mfma = [&](int buf) {
    short8 af[4], bfr[4];
#pragma unroll
    for (int i = 0; i < 4; ++i) af[i] = *(const short8*)&As[buf][wm + i * 16 + fr][fq];
#pragma unroll
    for (int i = 0; i < 4; ++i) bfr[i] = *(const short8*)&Bs[buf][wn + i * 16 + fr][fq];
#pragma unroll
    for (int mi = 0; mi < 4; ++mi)
#pragma unroll
      for (int ni = 0; ni < 4; ++ni)
        acc[mi][ni] = __builtin_amdgcn_mfma_f32_16x16x32_bf16(af[mi], bfr[ni], acc[mi][ni], 0, 0, 0);
  };
  loadA(0);
  storeA(0);
  loadA(32);
  __syncthreads();
  for (int kt = 0; kt < kTiles; kt += 2) {
    storeA(1);
    if (kt + 2 < kTiles) loadB((kt + 2) << 5);
    mfma(0);
    __syncthreads();
    if (kt + 2 < kTiles) storeB(0);
    if (kt + 3 < kTiles) loadA((kt + 3) << 5);
    mfma(1);
    __syncthreads();
  }
  int fq4 = (lane >> 4) * 4;
#pragma unroll
  for (int mi = 0; mi < 4; ++mi)
#pragma unroll
    for (int ni = 0; ni < 4; ++ni) {
      int col = n0 + wn + ni * 16 + fr;
      if (col < N) {
        int rowb = m0 + wm + mi * 16 + fq4;
#pragma unroll
        for (int r = 0; r < 4; ++r)
          C[(size_t)(rowb + r) * N + col] = f2bf(acc[mi][ni][r]);
      }
    }
}

// ---------------- GEMM 64x64, BK=64, double-buffer x2-unrolled, fused f32 epilogue ----------------
template <int MODE>
__global__ __launch_bounds__(256) void gemm64_ep_kernel(
    const __hip_bfloat16* __restrict__ A, const __hip_bfloat16* __restrict__ BT,
    const float* __restrict__ aux, const float* __restrict__ mask,
    float* __restrict__ out, int M, int N, int K) {
  __shared__ short As[2][64][72];
  __shared__ short Bs[2][64][72];
  int m0 = blockIdx.x * 64, n0 = blockIdx.y * 64;
  int t = threadIdx.x;
  int lane = t & 63, wv = t >> 6;
  int wm = (wv & 1) * 32, wn = (wv >> 1) * 32;
  f32x4 acc[2][2];
#pragma unroll
  for (int i = 0; i < 2; ++i)
#pragma unroll
    for (int j = 0; j < 2; ++j) acc[i][j] = (f32x4){0.f, 0.f, 0.f, 0.f};
  const short* Ag = (const short*)A;
  const short* Bg = (const short*)BT;
  int sr = t >> 2;
  int sc = (t & 3) * 16;
  const short* Ap = Ag + (size_t)(m0 + sr) * K + sc;
  const short* Bp = Bg + (size_t)(n0 + sr) * K + sc;
  int fr = lane & 15, fq = (lane >> 4) * 8;
  int kTiles = K >> 6;
  short8 a0A = 0, a1A = 0, b0A = 0, b1A = 0;
  short8 a0B = 0, a1B = 0, b0B = 0, b1B = 0;
  auto loadA = [&](int k0) {
    a0A = *(const short8*)(Ap + k0);
    a1A = *(const short8*)(Ap + k0 + 8);
    b0A = *(const short8*)(Bp + k0);
    b1A = *(const short8*)(Bp + k0 + 8);
  };
  auto loadB = [&](int k0) {
    a0B = *(const short8*)(Ap + k0);
    a1B = *(const short8*)(Ap + k0 + 8);
    b0B = *(const short8*)(Bp + k0);
    b1B = *(const short8*)(Bp + k0 + 8);
  };
  auto storeA = [&](int buf) {
    *(short8*)&As[buf][sr][sc] = a0A;
    *(short8*)&As[buf][sr][sc + 8] = a1A;
    *(short8*)&Bs[buf][sr][sc] = b0A;
    *(short8*)&Bs[buf][sr][sc + 8] = b1A;
  };
  auto storeB = [&](int buf) {
    *(short8*)&As[buf][sr][sc] = a0B;
    *(short8*)&As[buf][sr][sc + 8] = a1B;
    *(short8*)&Bs[buf][sr][sc] = b0B;
    *(short8*)&Bs[buf][sr][sc + 8] = b1B;
  };
  auto mfma = [&](int buf) {
#pragma unroll
    for (int kk = 0; kk < 2; ++kk) {
      short8 af[2], bfr[2];
#pragma unroll
      for (int i = 0; i < 2; ++i) af[i] = *(const short8*)&As[buf][wm + i * 16 + fr][kk * 32 + fq];
#pragma unroll
      for (int i = 0; i < 2; ++i) bfr[i] = *(const short8*)&Bs[buf][wn + i * 16 + fr][kk * 32 + fq];
#pragma unroll
      for (int mi = 0; mi < 2; ++mi)
#pragma unroll
        for (int ni = 0; ni < 2; ++ni)
          acc[mi][ni] = __builtin_amdgcn_mfma_f32_16x16x32_bf16(af[mi], bfr[ni], acc[mi][ni], 0, 0, 0);
    }
  };
  loadA(0);
  storeA(0);
  loadA(64);
  __syncthreads();
  for (int kt = 0; kt < kTiles; kt += 2) {
    storeA(1);
    if (kt + 2 < kTiles) loadB((kt + 2) << 6);
    mfma(0);
    __syncthreads();
    if (kt + 2 < kTiles) storeB(0);
    if (kt + 3 < kTiles) loadA((kt + 3) << 6);
    mfma(1);
    __syncthreads();
  }
  int fq4 = (lane >> 4) * 4;
#pragma unroll
  for (int mi = 0; mi < 2; ++mi)
#pragma unroll
    for (int ni = 0; ni < 2; ++ni) {
      int col = n0 + wn + ni * 16 + fr;
#pragma unroll
      for (int r = 0; r < 4; ++r) {
        int row = m0 + wm + mi * 16 + fq4 + r;
        float m = mask[row];
        size_t a = (size_t)row * N + col;
        float v = acc[mi][ni][r];
        if (MODE == 1) out[a] = aux[a] + v * m;
        else           out[a] = (aux[a] + v) * m;
      }
    }
}

// ---------------- fused FFN GEMM: gated = silu(A@w1) * (A@w3), double-buffer ----------------
__global__ __launch_bounds__(256) void gemm64g_kernel(
    const __hip_bfloat16* __restrict__ A, const __hip_bfloat16* __restrict__ BT,
    __hip_bfloat16* __restrict__ G, int M, int K) {
  __shared__ short As[2][64][72];
  __shared__ short B1s[2][64][72];
  __shared__ short B3s[2][64][72];
  int m0 = blockIdx.x * 64, n0 = blockIdx.y * 64;
  int t = threadIdx.x;
  int lane = t & 63, wv = t >> 6;
  int wm = (wv & 1) * 32, wn = (wv >> 1) * 32;
  f32x4 acc1[2][2], acc3[2][2];
#pragma unroll
  for (int i = 0; i < 2; ++i)
#pragma unroll
    for (int j = 0; j < 2; ++j) {
      acc1[i][j] = (f32x4){0.f, 0.f, 0.f, 0.f};
      acc3[i][j] = (f32x4){0.f, 0.f, 0.f, 0.f};
    }
  const short* Ag = (const short*)A;
  const short* Bg = (const short*)BT;
  int sr = t >> 2;
  int sc = (t & 3) * 16;
  const short* Ap  = Ag + (size_t)(m0 + sr) * K + sc;
  const short* B1p = Bg + (size_t)(n0 + sr) * K + sc;
  const short* B3p = Bg + (size_t)(DFFn + n0 + sr) * K + sc;
  int fr = lane & 15, fq = (lane >> 4) * 8;
  int kTiles = K >> 6;
  short8 a0A = 0, a1A = 0, c0A = 0, c1A = 0, d0A = 0, d1A = 0;
  short8 a0B = 0, a1B = 0, c0B = 0, c1B = 0, d0B = 0, d1B = 0;
  auto loadA = [&](int k0) {
    a0A = *(const short8*)(Ap + k0);
    a1A = *(const short8*)(Ap + k0 + 8);
    c0A = *(const short8*)(B1p + k0);
    c1A = *(const short8*)(B1p + k0 + 8);
    d0A = *(const short8*)(B3p + k0);
    d1A = *(const short8*)(B3p + k0 + 8);
  };
  auto loadB = [&](int k0) {
    a0B = *(const short8*)(Ap + k0);
    a1B = *(const short8*)(Ap + k0 + 8);
    c0B = *(const short8*)(B1p + k0);
    c1B = *(const short8*)(B1p + k0 + 8);
    d0B = *(const short8*)(B3p + k0);
    d1B = *(const short8*)(B3p + k0 + 8);
  };
  auto storeA = [&](int buf) {
    *(short8*)&As[buf][sr][sc] = a0A;
    *(short8*)&As[buf][sr][sc + 8] = a1A;
    *(short8*)&B1s[buf][sr][sc] = c0A;
    *(short8*)&B1s[buf][sr][sc + 8] = c1A;
    *(short8*)&B3s[buf][sr][sc] = d0A;
    *(short8*)&B3s[buf][sr][sc + 8] = d1A;
  };
  auto storeB = [&](int buf) {
    *(short8*)&As[buf][sr][sc] = a0B;
    *(short8*)&As[buf][sr][sc + 8] = a1B;
    *(short8*)&B1s[buf][sr][sc] = c0B;
    *(short8*)&B1s[buf][sr][sc + 8] = c1B;
    *(short8*)&B3s[buf][sr][sc] = d0B;
    *(short8*)&B3s[buf][sr][sc + 8] = d1B;
  };
  auto mfma = [&](int buf) {
#pragma unroll
    for (int kk = 0; kk < 2; ++kk) {
      short8 af[2], b1f[2], b3f[2];
#pragma unroll
      for (int i = 0; i < 2; ++i) af[i]  = *(const short8*)&As[buf][wm + i * 16 + fr][kk * 32 + fq];
#pragma unroll
      for (int i = 0; i < 2; ++i) b1f[i] = *(const short8*)&B1s[buf][wn + i * 16 + fr][kk * 32 + fq];
#pragma unroll
      for (int i = 0; i < 2; ++i) b3f[i] = *(const short8*)&B3s[buf][wn + i * 16 + fr][kk * 32 + fq];
#pragma unroll
      for (int mi = 0; mi < 2; ++mi)
#pragma unroll
        for (int ni = 0; ni < 2; ++ni) {
          acc1[mi][ni] = __builtin_amdgcn_mfma_f32_16x16x32_bf16(af[mi], b1f[ni], acc1[mi][ni], 0, 0, 0);
          acc3[mi][ni] = __builtin_amdgcn_mfma_f32_16x16x32_bf16(af[mi], b3f[ni], acc3[mi][ni], 0, 0, 0);
        }
    }
  };
  loadA(0);
  storeA(0);
  loadA(64);
  __syncthreads();
  for (int kt = 0; kt < kTiles; kt += 2) {
    storeA(1);
    if (kt + 2 < kTiles) loadB((kt + 2) << 6);
    mfma(0);
    __syncthreads();
    if (kt + 2 < kTiles) storeB(0);
    if (kt + 3 < kTiles) loadA((kt + 3) << 6);
    mfma(1);
    __syncthreads();
  }
  int fq4 = (lane >> 4) * 4;
#pragma unroll
  for (int mi = 0; mi < 2; ++mi)
#pragma unroll
    for (int ni = 0; ni < 2; ++ni) {
      int col = n0 + wn + ni * 16 + fr;
      bool valid = col < DFFn;
#pragma unroll
      for (int r = 0; r < 4; ++r) {
        int row = m0 + wm + mi * 16 + fq4 + r;
        float h1v = acc1[mi][ni][r];
        float sil = h1v / (1.f + __expf(-h1v));
        float g = sil * acc3[mi][ni][r];
        G[(size_t)row * KP2 + col] = valid ? f2bf(g) : f2bf(0.f);
      }
    }
}

// ---------------- chunked scan: intra-chunk + chunk-state (bf16 ys/Sbuf outputs) ----------------
__global__ __launch_bounds__(256) void chunk_intra_kernel(
    const __hip_bfloat16* __restrict__ P, const float* __restrict__ dt,
    const float* __restrict__ la, __hip_bfloat16* __restrict__ ysb,
    __hip_bfloat16* __restrict__ Sbuf, float* __restrict__ ecL, float* __restrict__ ec) {
  int id = blockIdx.x;
  int h = id & 15, c = (id >> 4) & 7, b = id >> 7;
  int t = threadIdx.x, lane = t & 63, wv = t >> 6;
  __shared__ __align__(16) char smem[55040];
  short* sCB = (short*)smem;
  short* sB  = (short*)(smem + 18432);
  short* sUD = (short*)(smem + 35840);
  short* sG  = (short*)(smem + 45056);
  float* scum = (float*)(smem + 54272);
  float* sws  = scum + 64;
  float* sdt  = sws + 64;
  int row0 = b * Sn + c * CH;
  const short* Pb = (const short*)P;
#pragma unroll
  for (int i = 0; i < 4; ++i) {
    int idx = t + i * 256;
    int r = idx >> 4, kk = (idx & 15) * 8;
    *(short8*)&sCB[r * 136 + kk] = *(const short8*)(Pb + (size_t)(row0 + r) * PSTR + 4096 + h * 128 + kk);
    *(short8*)&sB [r * 136 + kk] = *(const short8*)(Pb + (size_t)(row0 + r) * PSTR + 2048 + h * 128 + kk);
  }
  if (t < 64) { sdt[t] = dt[(size_t)(row0 + t) * Hn + h]; scum[t] = la[(size_t)(row0 + t) * Hn + h]; }
  __syncthreads();
  if (wv == 0) {
    float v = scum[lane];
#pragma unroll
    for (int o = 1; o < 64; o <<= 1) { float n = __shfl_up(v, o); if (lane >= o) v += n; }
    scum[lane] = v;
    float c63 = __shfl(v, 63);
    sws[lane] = __expf(c63 - v);
    ec[((size_t)((b * NCH + c) * Hn + h)) * 64 + lane] = __expf(v);
    if (lane == 0) ecL[(b * NCH + c) * Hn + h] = __expf(c63);
  }
#pragma unroll
  for (int i = 0; i < 2; ++i) {
    int idx = t + i * 256;
    int s = idx >> 3, pc = (idx & 7) * 8;
    short8 uv = *(const short8*)(Pb + (size_t)(row0 + s) * PSTR + 1024 + h * 64 + pc);
    float dv = sdt[s];
#pragma unroll
    for (int j = 0; j < 8; ++j) sUD[(pc + j) * 72 + s] = f2bfs(bfs2f(uv[j]) * dv);
  }
  __syncthreads();
  int fr = lane & 15, fq = (lane >> 4) * 8, q4 = (lane >> 4) * 4;
  {
    short8 af[4];
#pragma unroll
    for (int k = 0; k < 4; ++k) af[k] = *(short8*)&sCB[(16 * wv + fr) * 136 + k * 32 + fq];
#pragma unroll
    for (int j = 0; j < 4; ++j) {
      f32x4 acc = (f32x4){0.f, 0.f, 0.f, 0.f};
#pragma unroll
      for (int k = 0; k < 4; ++k) {
        short8 bf = *(short8*)&sB[(16 * j + fr) * 136 + k * 32 + fq];
        acc = __builtin_amdgcn_mfma_f32_16x16x32_bf16(af[k], bf, acc, 0, 0, 0);
      }
      int ss = 16 * j + fr;
      float cs = scum[ss];
#pragma unroll
      for (int r = 0; r < 4; ++r) {
        int tt = 16 * wv + q4 + r;
        float w = (ss <= tt) ? __expf(scum[tt] - cs) : 0.f;
        sG[tt * 72 + ss] = f2bfs(acc[r] * w);
      }
    }
  }
  __syncthreads();
#pragma unroll
  for (int i = 0; i < 32; ++i) {
    int idx = t + i * 256;
    int rn = idx >> 6, s = idx & 63;
    sCB[rn * 72 + s] = f2bfs(bfs2f(sB[s * 136 + rn]) * sws[s]);
  }
  __syncthreads();
  {
    short8 ag[2];
#pragma unroll
    for (int k = 0; k < 2; ++k) ag[k] = *(short8*)&sG[(16 * wv + fr) * 72 + k * 32 + fq];
#pragma unroll
    for (int j = 0; j < 4; ++j) {
      f32x4 acc = (f32x4){0.f, 0.f, 0.f, 0.f};
#pragma unroll
      for (int k = 0; k < 2; ++k) {
        short8 bf = *(short8*)&sUD[(16 * j + fr) * 72 + k * 32 + fq];
        acc = __builtin_amdgcn_mfma_f32_16x16x32_bf16(ag[k], bf, acc, 0, 0, 0);
      }
#pragma unroll
      for (int r = 0; r < 4; ++r)
        ysb[(size_t)(row0 + 16 * wv + q4 + r) * DINn + h * 64 + 16 * j + fr] = f2bf(acc[r]);
    }
  }
#pragma unroll
  for (int mt0 = 0; mt0 < 2; ++mt0) {
    int mt = wv * 2 + mt0;
    short8 ab[2];
#pragma unroll
    for (int k = 0; k < 2; ++k) ab[k] = *(short8*)&sCB[(16 * mt + fr) * 72 + k * 32 + fq];
#pragma unroll
    for (int j = 0; j < 4; ++j) {
      f32x4 acc = (f32x4){0.f, 0.f, 0.f, 0.f};
#pragma unroll
      for (int k = 0; k < 2; ++k) {
        short8 bf = *(short8*)&sUD[(16 * j + fr) * 72 + k * 32 + fq];
        acc = __builtin_amdgcn_mfma_f32_16x16x32_bf16(ab[k], bf, acc, 0, 0, 0);
      }
#pragma unroll
      for (int r = 0; r < 4; ++r)
        ((short*)Sbuf)[((size_t)((b * NCH + c) * Hn + h) * RNn + 16 * mt + q4 + r) * 64 + 16 * j + fr] =
            f2bfs(acc[r]);
    }
  }
}

// ---------------- prefix over chunk states (bf16 in/out, f32 accumulate) ----------------
__global__ void chunk_state_kernel(const __hip_bfloat16* __restrict__ Sbuf,
                                   const float* __restrict__ ecL,
                                   __hip_bfloat16* __restrict__ Hp) {
  int bh = blockIdx.x >> 4;
  int j = ((blockIdx.x & 15) * 256 + threadIdx.x) * 2;
  int b = bh >> 4, h = bh & 15;
  const short* Sb = (const short*)Sbuf;
  short* Hs = (short*)Hp;
  float hp0 = 0.f, hp1 = 0.f;
#pragma unroll
  for (int c = 0; c < NCH; ++c) {
    size_t addr = ((size_t)((b * NCH + c) * Hn + h)) * 8192 + j;
    short2 sv = *(const short2*)(Sb + addr);
    *(short2*)(Hs + addr) = make_short2(f2bfs(hp0), f2bfs(hp1));
    float e = ecL[(b * NCH + c) * Hn + h];
    hp0 = e * hp0 + bfs2f(sv.x);
    hp1 = e * hp1 + bfs2f(sv.y);
  }
}

// ---------------- inter-chunk + gate fused (bf16 Hp/ys inputs) ----------------
__global__ __launch_bounds__(256) void inter_gate_kernel(
    const __hip_bfloat16* __restrict__ P, const __hip_bfloat16* __restrict__ Hp,
    const float* __restrict__ ec, const __hip_bfloat16* __restrict__ ysb,
    const float* __restrict__ Dsk, __hip_bfloat16* __restrict__ y2b) {
  int id = blockIdx.x;
  int h = id & 15, c = (id >> 4) & 7, b = id >> 7;
  int t = threadIdx.x, lane = t & 63, wv = t >> 6;
  __shared__ __align__(16) short sC[64 * 136];
  __shared__ __align__(16) short sHt[64 * 136];
  __shared__ __align__(16) short sz[64 * 64];
  __shared__ __align__(16) short su[64 * 64];
  __shared__ float sec[64];
  int row0 = b * Sn + c * CH;
  const short* Pb = (const short*)P;
#pragma unroll
  for (int i = 0; i < 2; ++i) {
    int idx = t + i * 256;
    int r = idx >> 3, pc = (idx & 7) * 8;
    *(short8*)&sz[r * 64 + pc] = *(const short8*)(Pb + (size_t)(row0 + r) * PSTR + h * 64 + pc);
    *(short8*)&su[r * 64 + pc] = *(const short8*)(Pb + (size_t)(row0 + r) * PSTR + 1024 + h * 64 + pc);
  }
  if (c > 0) {
    const short* Hps = (const short*)Hp;
    size_t hbase = ((size_t)((b * NCH + c) * Hn + h)) * 8192;
#pragma unroll
    for (int i = 0; i < 4; ++i) {
      int idx = t + i * 256;
      int r = idx >> 4, kk = (idx & 15) * 8;
      *(short8*)&sC[r * 136 + kk] = *(const short8*)(Pb + (size_t)(row0 + r) * PSTR + 4096 + h * 128 + kk);
    }
#pragma unroll
    for (int i = 0; i < 32; ++i) {
      int idx = t + i * 256;
      int rn = idx >> 6, p = idx & 63;
      sHt[p * 136 + rn] = Hps[hbase + idx];
    }
    if (t < 64) sec[t] = ec[((size_t)((b * NCH + c) * Hn + h)) * 64 + t];
  }
  __syncthreads();
  int fr = lane & 15, fq = (lane >> 4) * 8, q4 = (lane >> 4) * 4;
  f32x4 acc[4];
#pragma unroll
  for (int j = 0; j < 4; ++j) acc[j] = (f32x4){0.f, 0.f, 0.f, 0.f};
  if (c > 0) {
    short8 af[4];
#pragma unroll
    for (int k = 0; k < 4; ++k) af[k] = *(short8*)&sC[(16 * wv + fr) * 136 + k * 32 + fq];
#pragma unroll
    for (int j = 0; j < 4; ++j)
#pragma unroll
      for (int k = 0; k < 4; ++k) {
        short8 bf = *(short8*)&sHt[(16 * j + fr) * 136 + k * 32 + fq];
        acc[j] = __builtin_amdgcn_mfma_f32_16x16x32_bf16(af[k], bf, acc[j], 0, 0, 0);
      }
  }
  float dsk = Dsk[h];
#pragma unroll
  for (int j = 0; j < 4; ++j) {
    int col = 16 * j + fr;
#pragma unroll
    for (int r = 0; r < 4; ++r) {
      int tt = 16 * wv + q4 + r;
      size_t a = (size_t)(row0 + tt) * DINn + h * 64 + col;
      float val = bf2f(ysb[a]);
      if (c > 0) val += sec[tt] * acc[j][r];
      float uu = bfs2f(su[tt * 64 + col]);
      float zz = bfs2f(sz[tt * 64 + col]);
      float sil = zz / (1.f + __expf(-zz));
      y2b[a] = f2bf((val + uu * dsk) * sil);
    }
  }
}

extern "C" void kernel_launch(void* const* d_in, const int* in_sizes, int n_in,
                              void* d_out, int out_size, void* d_ws, size_t ws_size,
                              hipStream_t stream) {
  const float* x    = (const float*)d_in[0];
  const float* mask = (const float*)d_in[1];
  const float* n1w  = (const float*)d_in[2];
  const float* n2w  = (const float*)d_in[3];
  const float* Wz   = (const float*)d_in[4];
  const float* Wx   = (const float*)d_in[5];
  const float* Wb   = (const float*)d_in[6];
  const float* Wc   = (const float*)d_in[7];
  const float* Wdt  = (const float*)d_in[8];
  const float* dtb  = (const float*)d_in[9];
  const float* Alog = (const float*)d_in[10];
  const float* Dsk  = (const float*)d_in[11];
  const float* Wout = (const float*)d_in[12];
  const float* w1   = (const float*)d_in[13];
  const float* w2   = (const float*)d_in[14];
  const float* w3   = (const float*)d_in[15];

  char* ws = (char*)d_ws;
  size_t off = 0;
  auto alloc = [&](size_t bytes) {
    char* p = ws + off;
    off += (bytes + 255) & ~(size_t)255;
    return p;
  };
  __hip_bfloat16* xnb = (__hip_bfloat16*)alloc((size_t)BSn * Dn * 2);
  __hip_bfloat16* P = (__hip_bfloat16*)alloc((size_t)BSn * PSTR * 2);
  float* dt  = (float*)alloc((size_t)BSn * Hn * 4);
  float* la  = (float*)alloc((size_t)BSn * Hn * 4);
  __hip_bfloat16* ysb = (__hip_bfloat16*)alloc((size_t)BSn * DINn * 2);
  float* ecL = (float*)alloc((size_t)Bn * NCH * Hn * 4);
  float* ec  = (float*)alloc((size_t)Bn * NCH * Hn * 64 * 4);
  __hip_bfloat16* WallT = (__hip_bfloat16*)alloc((size_t)PSTR * Dn * 2);   // [z|u|B|C]^T
  __hip_bfloat16* WoutT = (__hip_bfloat16*)alloc((size_t)Dn * DINn * 2);
  __hip_bfloat16* w13T  = (__hip_bfloat16*)alloc((size_t)FPAD * Dn * 2);   // [w1|w3|zeros]^T, 2816 rows
  __hip_bfloat16* w2T   = (__hip_bfloat16*)alloc((size_t)Dn * KP2 * 2);    // K-pad 1408 (BK=64)
  char* arena = alloc(22000000);
  __hip_bfloat16* Sbuf = (__hip_bfloat16*)arena;
  __hip_bfloat16* Hp   = (__hip_bfloat16*)(arena + 8388608);
  __hip_bfloat16* y2b  = (__hip_bfloat16*)(arena + 16777216);
  float* xres          = (float*)arena;
  __hip_bfloat16* gatedb = (__hip_bfloat16*)(arena + 4194304);

  // -------- transpose job table (64x64 tiles) --------
  T8 td;
  td.src[0] = Wz;   td.dst[0] = WallT;                      td.Rr[0] = 512;  td.Cc[0] = 1024; td.RrPad[0] = 512;  td.CcPad[0] = 1024;
  td.src[1] = Wx;   td.dst[1] = WallT + (size_t)1024 * 512; td.Rr[1] = 512;  td.Cc[1] = 1024; td.RrPad[1] = 512;  td.CcPad[1] = 1024;
  td.src[2] = Wb;   td.dst[2] = WallT + (size_t)2048 * 512; td.Rr[2] = 512;  td.Cc[2] = 2048; td.RrPad[2] = 512;  td.CcPad[2] = 2048;
  td.src[3] = Wc;   td.dst[3] = WallT + (size_t)4096 * 512; td.Rr[3] = 512;  td.Cc[3] = 2048; td.RrPad[3] = 512;  td.CcPad[3] = 2048;
  td.src[4] = Wout; td.dst[4] = WoutT;                      td.Rr[4] = 1024; td.Cc[4] = 512;  td.RrPad[4] = 1024; td.CcPad[4] = 512;
  td.src[5] = w1;   td.dst[5] = w13T;                       td.Rr[5] = 512;  td.Cc[5] = 1368; td.RrPad[5] = 512;  td.CcPad[5] = 1368;
  td.src[6] = w3;   td.dst[6] = w13T + (size_t)1368 * 512;  td.Rr[6] = 512;  td.Cc[6] = 1368; td.RrPad[6] = 512;  td.CcPad[6] = 1448; // zero rows -> 2816 total
  td.src[7] = w2;   td.dst[7] = w2T;                        td.Rr[7] = 1368; td.Cc[7] = 512;  td.RrPad[7] = KP2;  td.CcPad[7] = 512;  // zero K-pad
  int tot = 0;
  for (int i = 0; i < 8; ++i) {
    td.gw[i] = (td.CcPad[i] + 63) / 64;
    int gh = (td.RrPad[i] + 63) / 64;
    td.start[i] = tot;
    tot += td.gw[i] * gh;
  }
  td.start[8] = tot;

  prep_kernel<<<tot + BSn, 256, 0, stream>>>(td, x, n1w, mask, Wdt, dtb, Alog, xnb, dt, la, tot);
  gemm_kernel<<<dim3(16, 48), 256, 0, stream>>>(xnb, WallT, P, BSn, PSTR, Dn);
  chunk_intra_kernel<<<Bn * NCH * Hn, 256, 0, stream>>>(P, dt, la, ysb, Sbuf, ecL, ec);
  chunk_state_kernel<<<Bn * Hn * 16, 256, 0, stream>>>(Sbuf, ecL, Hp);
  inter_gate_kernel<<<Bn * NCH * Hn, 256, 0, stream>>>(P, Hp, ec, ysb, Dsk, y2b);
  gemm64_ep_kernel<1><<<dim3(32, 8), 256, 0, stream>>>(y2b, WoutT, x, mask, xres, BSn, Dn, DINn);
  rmsnorm2_kernel<<<BSn, 256, 0, stream>>>(xres, n2w, xnb);
  gemm64g_kernel<<<dim3(32, KP2 / 64), 256, 0, stream>>>(xnb, w13T, gatedb, BSn, Dn);
  gemm64_ep_kernel<2><<<dim3(32, 8), 256, 0, stream>>>(gatedb, w2T, xres, mask, (float*)d_out, BSn, Dn, KP2);
}